// Round 4
// baseline (865.816 us; speedup 1.0000x reference)
//
#include <hip/hip_runtime.h>

#define NN 100000
#define NE 1600000
#define NF 128
#define NH 256
#define NC 47
#define NB 391   // ceil(NN/256) buckets of 256 nodes

typedef __attribute__((ext_vector_type(8))) short bf16x8;
typedef __attribute__((ext_vector_type(4))) float f32x4;

__device__ inline unsigned short f2bf(float f) {
    unsigned u = __builtin_bit_cast(unsigned, f);
    unsigned r = u + 0x7fffu + ((u >> 16) & 1u);
    return (unsigned short)(r >> 16);
}
__device__ inline float bfl(unsigned u) {           // low ushort -> float
    return __builtin_bit_cast(float, u << 16);
}
__device__ inline float bfh(unsigned u) {           // high ushort -> float
    return __builtin_bit_cast(float, u & 0xffff0000u);
}

// ---------------- CSR build: two-level counting sort by dst ----------------

// 1) bucket histogram (LDS-privatized)
__global__ __launch_bounds__(256) void hist_k(const int* __restrict__ dst,
                                              int* __restrict__ bucket_cnt) {
    __shared__ int h[NB];
    int tid = threadIdx.x;
    for (int i = tid; i < NB; i += 256) h[i] = 0;
    __syncthreads();
    for (int e = blockIdx.x * 256 + tid; e < NE; e += gridDim.x * 256)
        atomicAdd(&h[dst[e] >> 8], 1);
    __syncthreads();
    for (int i = tid; i < NB; i += 256)
        if (h[i]) atomicAdd(&bucket_cnt[i], h[i]);
}

// 2) exclusive scan over buckets (one block)
__global__ __launch_bounds__(512) void scan_buckets_k(const int* __restrict__ bucket_cnt,
                                                      int* __restrict__ bucket_base,
                                                      int* __restrict__ bucket_cursor) {
    __shared__ int s[512];
    int tid = threadIdx.x;
    int v = (tid < NB) ? bucket_cnt[tid] : 0;
    s[tid] = v;
    __syncthreads();
    for (int off = 1; off < 512; off <<= 1) {
        int t = (tid >= off) ? s[tid - off] : 0;
        __syncthreads();
        s[tid] += t;
        __syncthreads();
    }
    if (tid < NB) {
        int b = s[tid] - v;
        bucket_base[tid] = b;
        bucket_cursor[tid] = b;
    }
}

// 3) scatter edges into bucket regions, packed: (dst&255)<<24 | src
__global__ __launch_bounds__(256) void scatter_k(const int* __restrict__ src,
                                                 const int* __restrict__ dst,
                                                 int* __restrict__ bucket_cursor,
                                                 unsigned* __restrict__ ebuf) {
    int e = blockIdx.x * 256 + threadIdx.x;
    if (e >= NE) return;
    int d = dst[e];
    int s = src[e];
    int p = atomicAdd(&bucket_cursor[d >> 8], 1);
    ebuf[p] = ((unsigned)(d & 255) << 24) | (unsigned)s;
}

// 4) per-bucket local CSR: histogram + scan + scatter within bucket
__global__ __launch_bounds__(256) void build_csr_k(const unsigned* __restrict__ ebuf,
                                                   const int* __restrict__ bucket_base,
                                                   const int* __restrict__ bucket_cnt,
                                                   int* __restrict__ row_start,
                                                   int* __restrict__ deg,
                                                   float* __restrict__ inv_deg,
                                                   int* __restrict__ csr_src) {
    __shared__ int s[256];
    __shared__ int cursor[256];
    int tid = threadIdx.x;
    int b = blockIdx.x;
    int lo = b << 8;                 // first node of bucket
    int ebase = bucket_base[b];
    int ne = bucket_cnt[b];

    s[tid] = 0;
    __syncthreads();
    for (int e = tid; e < ne; e += 256)
        atomicAdd(&s[ebuf[ebase + e] >> 24], 1);
    __syncthreads();
    int v = s[tid];
    __syncthreads();
    // inclusive scan (Hillis-Steele)
    for (int off = 1; off < 256; off <<= 1) {
        int t = (tid >= off) ? s[tid - off] : 0;
        __syncthreads();
        s[tid] += t;
        __syncthreads();
    }
    int excl = s[tid] - v;
    int node = lo + tid;
    if (node < NN) {
        row_start[node] = ebase + excl;
        deg[node] = v;
        inv_deg[node] = 1.0f / (float)(v > 1 ? v : 1);
    }
    cursor[tid] = ebase + excl;
    __syncthreads();
    for (int e = tid; e < ne; e += 256) {
        unsigned u = ebuf[ebase + e];
        int p = atomicAdd(&cursor[u >> 24], 1);
        csr_src[p] = (int)(u & 0xFFFFFFu);
    }
}

// ---------------- dtype prep ----------------

__global__ void cast_x_k(const float* __restrict__ x, unsigned short* __restrict__ xb) {
    int i = blockIdx.x * 256 + threadIdx.x;        // 4 floats per thread
    if (i >= NN * NF / 4) return;
    float4 v = *reinterpret_cast<const float4*>(x + (size_t)i * 4);
    ushort4 o;
    o.x = f2bf(v.x); o.y = f2bf(v.y); o.z = f2bf(v.z); o.w = f2bf(v.w);
    *reinterpret_cast<ushort4*>(xb + (size_t)i * 4) = o;
}

// Bt1[n][k], n<256, k<256: k<128 -> Wl1[k][n], else Wr1[k-128][n]
__global__ void prep_bt1_k(const float* __restrict__ Wl1, const float* __restrict__ Wr1,
                           unsigned short* __restrict__ Bt1) {
    int idx = blockIdx.x * 256 + threadIdx.x;
    if (idx >= 256 * 256) return;
    int n = idx >> 8, k = idx & 255;
    float v = (k < 128) ? Wl1[(size_t)k * NH + n] : Wr1[(size_t)(k - 128) * NH + n];
    Bt1[idx] = f2bf(v);
}

// Bt2[n][k], n<96, k<256: n<47 -> Wl2[k][n]; 48<=n<95 -> Wr2[k][n-48]; else 0
__global__ void prep_bt2_k(const float* __restrict__ Wl2, const float* __restrict__ Wr2,
                           unsigned short* __restrict__ Bt2) {
    int idx = blockIdx.x * 256 + threadIdx.x;
    if (idx >= 96 * 256) return;
    int n = idx >> 8, k = idx & 255;
    float v = 0.f;
    if (n < 47) v = Wl2[(size_t)k * NC + n];
    else if (n >= 48 && n < 95) v = Wr2[(size_t)k * NC + (n - 48)];
    Bt2[idx] = f2bf(v);
}

// ---------------- aggregation ----------------

// mean1[i,:] = inv_deg * sum_{j->i} xb[j,:]  (bf16 in, f32 acc, bf16 out), unroll 2
__global__ __launch_bounds__(256) void agg_mean_128b_k(const unsigned short* __restrict__ xb,
                                                       const int* __restrict__ csr_src,
                                                       const int* __restrict__ row_start,
                                                       const int* __restrict__ deg,
                                                       const float* __restrict__ inv_deg,
                                                       unsigned short* __restrict__ mean1) {
    int node = (blockIdx.x * 256 + threadIdx.x) >> 6;
    int lane = threadIdx.x & 63;
    if (node >= NN) return;
    int s0 = row_start[node];
    int d  = deg[node];
    float ax = 0.f, ay = 0.f;
    int j = 0;
    for (; j + 1 < d; j += 2) {
        int sA = csr_src[s0 + j];
        int sB = csr_src[s0 + j + 1];
        unsigned uA = *reinterpret_cast<const unsigned*>(xb + (size_t)sA * NF + lane * 2);
        unsigned uB = *reinterpret_cast<const unsigned*>(xb + (size_t)sB * NF + lane * 2);
        ax += bfl(uA); ay += bfh(uA);
        ax += bfl(uB); ay += bfh(uB);
    }
    if (j < d) {
        int s = csr_src[s0 + j];
        unsigned u = *reinterpret_cast<const unsigned*>(xb + (size_t)s * NF + lane * 2);
        ax += bfl(u); ay += bfh(u);
    }
    float inv = inv_deg[node];
    unsigned o = (unsigned)f2bf(ax * inv) | ((unsigned)f2bf(ay * inv) << 16);
    *reinterpret_cast<unsigned*>(mean1 + (size_t)node * NF + lane * 2) = o;
}

// out[i,c] += inv_deg * sum_{j->i} tb[j,c]   (bf16 rows padded to 64 = one 128B line), unroll 4
__global__ __launch_bounds__(256) void agg_mean_47b_add_k(const unsigned short* __restrict__ tb,
                                                          const int* __restrict__ csr_src,
                                                          const int* __restrict__ row_start,
                                                          const int* __restrict__ deg,
                                                          const float* __restrict__ inv_deg,
                                                          float* __restrict__ out) {
    int node = (blockIdx.x * 256 + threadIdx.x) >> 6;
    int lane = threadIdx.x & 63;
    if (node >= NN) return;
    int s0 = row_start[node];
    int d  = deg[node];
    float acc = 0.f;
    int j = 0;
    for (; j + 3 < d; j += 4) {
        int sA = csr_src[s0 + j];
        int sB = csr_src[s0 + j + 1];
        int sC = csr_src[s0 + j + 2];
        int sD = csr_src[s0 + j + 3];
        float a = bfl((unsigned)tb[(size_t)sA * 64 + lane]);
        float b = bfl((unsigned)tb[(size_t)sB * 64 + lane]);
        float c = bfl((unsigned)tb[(size_t)sC * 64 + lane]);
        float e = bfl((unsigned)tb[(size_t)sD * 64 + lane]);
        acc += a + b + c + e;
    }
    for (; j < d; ++j) {
        int s = csr_src[s0 + j];
        acc += bfl((unsigned)tb[(size_t)s * 64 + lane]);
    }
    if (lane < NC) {
        size_t o = (size_t)node * NC + lane;
        out[o] = out[o] + acc * inv_deg[node];
    }
}

// ---------------- GEMM1 (MFMA): h = relu([mean1|x]_bf16 @ Bt1^T + b1) ----------------

__global__ __launch_bounds__(256) void gemm1_mfma_k(const unsigned short* __restrict__ mean1,
                                                    const unsigned short* __restrict__ xb,
                                                    const unsigned short* __restrict__ Bt1,
                                                    const float* __restrict__ b1,
                                                    unsigned short* __restrict__ h) {
    __shared__ short As[2][128 * 32];
    __shared__ short Bs[2][128 * 32];
    const int tid = threadIdx.x;
    const int row0 = blockIdx.x * 128;
    const int col0 = blockIdx.y * 128;
    const int lane = tid & 63;
    const int wid = tid >> 6;
    const int wr = wid >> 1, wc = wid & 1;
    const int r15 = lane & 15;
    const int swz = ((lane >> 4) ^ ((lane >> 1) & 3)) & 3;

    f32x4 acc[4][4];
    #pragma unroll
    for (int i = 0; i < 4; ++i)
        #pragma unroll
        for (int j = 0; j < 4; ++j)
            acc[i][j] = f32x4{0.f, 0.f, 0.f, 0.f};

    bf16x8 ra[2], rb[2];

    auto load_tiles = [&](int kt) {
        #pragma unroll
        for (int i = 0; i < 2; ++i) {
            int c = tid + i * 256;
            int row = c >> 2, g = c & 3;
            int grow = row0 + row;
            const unsigned short* asrc = (kt < 128) ? mean1 : xb;
            int kb = (kt & 127) + g * 8;
            bf16x8 va = {0,0,0,0,0,0,0,0};
            if (grow < NN) va = *reinterpret_cast<const bf16x8*>(asrc + (size_t)grow * NF + kb);
            ra[i] = va;
            int n = col0 + row;
            rb[i] = *reinterpret_cast<const bf16x8*>(Bt1 + (size_t)n * 256 + kt + g * 8);
        }
    };
    auto write_tiles = [&](int buf) {
        #pragma unroll
        for (int i = 0; i < 2; ++i) {
            int c = tid + i * 256;
            int row = c >> 2, g = c & 3;
            int slot = g ^ ((row >> 1) & 3);
            *reinterpret_cast<bf16x8*>(&As[buf][row * 32 + slot * 8]) = ra[i];
            *reinterpret_cast<bf16x8*>(&Bs[buf][row * 32 + slot * 8]) = rb[i];
        }
    };
    auto compute = [&](int buf) {
        bf16x8 a[4], b[4];
        #pragma unroll
        for (int mi = 0; mi < 4; ++mi)
            a[mi] = *reinterpret_cast<const bf16x8*>(&As[buf][(wr * 64 + mi * 16 + r15) * 32 + swz * 8]);
        #pragma unroll
        for (int ni = 0; ni < 4; ++ni)
            b[ni] = *reinterpret_cast<const bf16x8*>(&Bs[buf][(wc * 64 + ni * 16 + r15) * 32 + swz * 8]);
        #pragma unroll
        for (int mi = 0; mi < 4; ++mi)
            #pragma unroll
            for (int ni = 0; ni < 4; ++ni)
                acc[mi][ni] = __builtin_amdgcn_mfma_f32_16x16x32_bf16(a[mi], b[ni], acc[mi][ni], 0, 0, 0);
    };

    load_tiles(0);
    write_tiles(0);
    __syncthreads();
    int cur = 0;
    #pragma unroll 1
    for (int ks = 0; ks < 8; ++ks) {
        if (ks + 1 < 8) load_tiles((ks + 1) * 32);
        compute(cur);
        if (ks + 1 < 8) write_tiles(cur ^ 1);
        __syncthreads();
        cur ^= 1;
    }

    #pragma unroll
    for (int ni = 0; ni < 4; ++ni) {
        int col = col0 + wc * 64 + ni * 16 + r15;
        float bias = b1[col];
        #pragma unroll
        for (int mi = 0; mi < 4; ++mi) {
            int rbase = row0 + wr * 64 + mi * 16 + (lane >> 4) * 4;
            f32x4 c = acc[mi][ni];
            #pragma unroll
            for (int q = 0; q < 4; ++q) {
                int row = rbase + q;
                if (row < NN) {
                    float v = fmaxf(c[q] + bias, 0.f);
                    h[(size_t)row * NH + col] = f2bf(v);
                }
            }
        }
    }
}

// ---------------- GEMM2 (MFMA): tb = bf16(h@Wl2) ; out = h@Wr2 + b2 ----------------

__global__ __launch_bounds__(256) void gemm2_mfma_k(const unsigned short* __restrict__ h,
                                                    const unsigned short* __restrict__ Bt2,
                                                    const float* __restrict__ b2,
                                                    unsigned short* __restrict__ tb,
                                                    float* __restrict__ out) {
    __shared__ short As[2][128 * 32];
    __shared__ short Bs[2][96 * 32];
    const int tid = threadIdx.x;
    const int row0 = blockIdx.x * 128;
    const int lane = tid & 63;
    const int wid = tid >> 6;
    const int wr = wid >> 1, wc = wid & 1;
    const int r15 = lane & 15;
    const int swz = ((lane >> 4) ^ ((lane >> 1) & 3)) & 3;

    f32x4 acc[4][3];
    #pragma unroll
    for (int i = 0; i < 4; ++i)
        #pragma unroll
        for (int j = 0; j < 3; ++j)
            acc[i][j] = f32x4{0.f, 0.f, 0.f, 0.f};

    bf16x8 ra[2], rb[2];

    auto load_tiles = [&](int kt) {
        #pragma unroll
        for (int i = 0; i < 2; ++i) {
            int c = tid + i * 256;
            int row = c >> 2, g = c & 3;
            int grow = row0 + row;
            bf16x8 va = {0,0,0,0,0,0,0,0};
            if (grow < NN) va = *reinterpret_cast<const bf16x8*>(h + (size_t)grow * NH + kt + g * 8);
            ra[i] = va;
            if (c < 96 * 4)
                rb[i] = *reinterpret_cast<const bf16x8*>(Bt2 + (size_t)row * 256 + kt + g * 8);
        }
    };
    auto write_tiles = [&](int buf) {
        #pragma unroll
        for (int i = 0; i < 2; ++i) {
            int c = tid + i * 256;
            int row = c >> 2, g = c & 3;
            int slot = g ^ ((row >> 1) & 3);
            *reinterpret_cast<bf16x8*>(&As[buf][row * 32 + slot * 8]) = ra[i];
            if (c < 96 * 4)
                *reinterpret_cast<bf16x8*>(&Bs[buf][row * 32 + slot * 8]) = rb[i];
        }
    };
    auto compute = [&](int buf) {
        bf16x8 a[4], b[3];
        #pragma unroll
        for (int mi = 0; mi < 4; ++mi)
            a[mi] = *reinterpret_cast<const bf16x8*>(&As[buf][(wr * 64 + mi * 16 + r15) * 32 + swz * 8]);
        #pragma unroll
        for (int ni = 0; ni < 3; ++ni)
            b[ni] = *reinterpret_cast<const bf16x8*>(&Bs[buf][(wc * 48 + ni * 16 + r15) * 32 + swz * 8]);
        #pragma unroll
        for (int mi = 0; mi < 4; ++mi)
            #pragma unroll
            for (int ni = 0; ni < 3; ++ni)
                acc[mi][ni] = __builtin_amdgcn_mfma_f32_16x16x32_bf16(a[mi], b[ni], acc[mi][ni], 0, 0, 0);
    };

    load_tiles(0);
    write_tiles(0);
    __syncthreads();
    int cur = 0;
    #pragma unroll 1
    for (int ks = 0; ks < 8; ++ks) {
        if (ks + 1 < 8) load_tiles((ks + 1) * 32);
        compute(cur);
        if (ks + 1 < 8) write_tiles(cur ^ 1);
        __syncthreads();
        cur ^= 1;
    }

    #pragma unroll
    for (int ni = 0; ni < 3; ++ni) {
        int col = wc * 48 + ni * 16 + r15;       // 0..95
        float bias = (col >= 48 && col < 95) ? b2[col - 48] : 0.f;
        #pragma unroll
        for (int mi = 0; mi < 4; ++mi) {
            int rbase = row0 + wr * 64 + mi * 16 + (lane >> 4) * 4;
            f32x4 c = acc[mi][ni];
            #pragma unroll
            for (int q = 0; q < 4; ++q) {
                int row = rbase + q;
                if (row < NN) {
                    if (col < 47)
                        tb[(size_t)row * 64 + col] = f2bf(c[q]);
                    else if (col >= 48 && col < 95)
                        out[(size_t)row * NC + (col - 48)] = c[q] + bias;
                }
            }
        }
    }
}

// ---------------- launch ----------------

extern "C" void kernel_launch(void* const* d_in, const int* in_sizes, int n_in,
                              void* d_out, int out_size, void* d_ws, size_t ws_size,
                              hipStream_t stream) {
    const float* x    = (const float*)d_in[0];
    const int*   eidx = (const int*)d_in[1];
    const float* Wl1  = (const float*)d_in[2];
    const float* Wr1  = (const float*)d_in[3];
    const float* b1   = (const float*)d_in[4];
    const float* Wl2  = (const float*)d_in[5];
    const float* Wr2  = (const float*)d_in[6];
    const float* b2   = (const float*)d_in[7];
    float* out = (float*)d_out;

    const int* src = eidx;
    const int* dst = eidx + NE;

    size_t off = 0;
    auto alloc = [&](size_t bytes) -> void* {
        void* p = (char*)d_ws + off;
        off += (bytes + 511) & ~(size_t)511;
        return p;
    };
    int*            deg        = (int*)alloc((size_t)NN * 4);
    int*            row_start  = (int*)alloc((size_t)NN * 4);
    float*          inv_deg    = (float*)alloc((size_t)NN * 4);
    int*            csr_src    = (int*)alloc((size_t)NE * 4);
    unsigned*       ebuf       = (unsigned*)alloc((size_t)NE * 4);
    int*            bkt_cnt    = (int*)alloc((size_t)NB * 4);
    int*            bkt_base   = (int*)alloc((size_t)NB * 4);
    int*            bkt_cursor = (int*)alloc((size_t)NB * 4);
    unsigned short* xb         = (unsigned short*)alloc((size_t)NN * NF * 2);
    unsigned short* mean1      = (unsigned short*)alloc((size_t)NN * NF * 2);
    unsigned short* hbuf       = (unsigned short*)alloc((size_t)NN * NH * 2);
    unsigned short* tb         = (unsigned short*)alloc((size_t)NN * 64 * 2);
    unsigned short* Bt1        = (unsigned short*)alloc((size_t)256 * 256 * 2);
    unsigned short* Bt2        = (unsigned short*)alloc((size_t)96 * 256 * 2);
    (void)ws_size; (void)n_in; (void)in_sizes; (void)out_size;

    hipMemsetAsync(bkt_cnt, 0, (size_t)NB * 4, stream);
    hist_k<<<1024, 256, 0, stream>>>(dst, bkt_cnt);
    scan_buckets_k<<<1, 512, 0, stream>>>(bkt_cnt, bkt_base, bkt_cursor);
    scatter_k<<<(NE + 255) / 256, 256, 0, stream>>>(src, dst, bkt_cursor, ebuf);
    build_csr_k<<<NB, 256, 0, stream>>>(ebuf, bkt_base, bkt_cnt,
                                        row_start, deg, inv_deg, csr_src);

    cast_x_k<<<(NN * NF / 4 + 255) / 256, 256, 0, stream>>>(x, xb);
    prep_bt1_k<<<(256 * 256 + 255) / 256, 256, 0, stream>>>(Wl1, Wr1, Bt1);
    prep_bt2_k<<<(96 * 256 + 255) / 256, 256, 0, stream>>>(Wl2, Wr2, Bt2);

    agg_mean_128b_k<<<NN / 4, 256, 0, stream>>>(xb, csr_src, row_start, deg, inv_deg, mean1);

    gemm1_mfma_k<<<dim3((NN + 127) / 128, 2), 256, 0, stream>>>(mean1, xb, Bt1, b1, hbuf);
    gemm2_mfma_k<<<(NN + 127) / 128, 256, 0, stream>>>(hbuf, Bt2, b2, tb, out);

    agg_mean_47b_add_k<<<NN / 4, 256, 0, stream>>>(tb, csr_src, row_start, deg, inv_deg, out);
}

// Round 5
// 322.113 us; speedup vs baseline: 2.6879x; 2.6879x over previous
//
#include <hip/hip_runtime.h>

#define NN 100000
#define NE 1600000
#define NF 128
#define NH 256
#define NC 47
#define NB 391            // ceil(NN/256) buckets of 256 nodes
#define CH 8192           // edges per chunk
#define NCH ((NE + CH - 1) / CH)   // 196

typedef __attribute__((ext_vector_type(8))) short bf16x8;
typedef __attribute__((ext_vector_type(4))) float f32x4;

__device__ inline unsigned short f2bf(float f) {
    unsigned u = __builtin_bit_cast(unsigned, f);
    unsigned r = u + 0x7fffu + ((u >> 16) & 1u);
    return (unsigned short)(r >> 16);
}
__device__ inline float bfl(unsigned u) {           // low ushort -> float
    return __builtin_bit_cast(float, u << 16);
}
__device__ inline float bfh(unsigned u) {           // high ushort -> float
    return __builtin_bit_cast(float, u & 0xffff0000u);
}

// ---------------- CSR build: deterministic 3-pass bucket partition ----------------

// 1) per-chunk histogram + low-contention totals
__global__ __launch_bounds__(256) void chunk_hist_k(const int* __restrict__ dst,
                                                    int* __restrict__ chunk_hist,
                                                    int* __restrict__ total) {
    __shared__ int h[NB];
    int tid = threadIdx.x, ch = blockIdx.x;
    for (int i = tid; i < NB; i += 256) h[i] = 0;
    __syncthreads();
    int e0 = ch * CH;
    int e1 = min(e0 + CH, NE);
    for (int e = e0 + tid; e < e1; e += 256)
        atomicAdd(&h[dst[e] >> 8], 1);
    __syncthreads();
    for (int i = tid; i < NB; i += 256) {
        int v = h[i];
        chunk_hist[(size_t)ch * NB + i] = v;
        if (v) atomicAdd(&total[i], v);          // 196 hits/counter max
    }
}

// 2) exclusive scan over bucket totals (one block)
__global__ __launch_bounds__(512) void scan_buckets_k(const int* __restrict__ total,
                                                      int* __restrict__ bucket_base) {
    __shared__ int s[512];
    int tid = threadIdx.x;
    int v = (tid < NB) ? total[tid] : 0;
    s[tid] = v;
    __syncthreads();
    for (int off = 1; off < 512; off <<= 1) {
        int t = (tid >= off) ? s[tid - off] : 0;
        __syncthreads();
        s[tid] += t;
        __syncthreads();
    }
    if (tid < NB) bucket_base[tid] = s[tid] - v;
}

// 3) per-bucket prefix down the chunk column -> exact per-chunk offsets
__global__ __launch_bounds__(64) void colscan_k(const int* __restrict__ chunk_hist,
                                                const int* __restrict__ bucket_base,
                                                int* __restrict__ chunk_off) {
    int b = blockIdx.x;
    int lane = threadIdx.x;
    int run = bucket_base[b];
    for (int c0 = 0; c0 < NCH; c0 += 64) {
        int c = c0 + lane;
        int v = (c < NCH) ? chunk_hist[(size_t)c * NB + b] : 0;
        int s = v;
        #pragma unroll
        for (int off = 1; off < 64; off <<= 1) {
            int t = __shfl_up(s, off);
            if (lane >= off) s += t;
        }
        if (c < NCH) chunk_off[(size_t)c * NB + b] = run + s - v;
        run += __shfl(s, 63);
    }
}

// 4) scatter via LDS cursors (no global atomics), packed word (dst&255)<<24 | src
__global__ __launch_bounds__(256) void scatter2_k(const int* __restrict__ src,
                                                  const int* __restrict__ dst,
                                                  const int* __restrict__ chunk_off,
                                                  unsigned* __restrict__ ebuf) {
    __shared__ int cur[NB];
    int tid = threadIdx.x, ch = blockIdx.x;
    for (int i = tid; i < NB; i += 256)
        cur[i] = chunk_off[(size_t)ch * NB + i];
    __syncthreads();
    int e0 = ch * CH;
    int e1 = min(e0 + CH, NE);
    for (int e = e0 + tid; e < e1; e += 256) {
        int d = dst[e];
        int b = d >> 8;
        int p = atomicAdd(&cur[b], 1);
        ebuf[p] = ((unsigned)(d & 255) << 24) | (unsigned)src[e];
    }
}

// 5) per-bucket local CSR: histogram + scan + scatter within bucket
__global__ __launch_bounds__(256) void build_csr_k(const unsigned* __restrict__ ebuf,
                                                   const int* __restrict__ bucket_base,
                                                   const int* __restrict__ bucket_cnt,
                                                   int* __restrict__ row_start,
                                                   int* __restrict__ deg,
                                                   float* __restrict__ inv_deg,
                                                   int* __restrict__ csr_src) {
    __shared__ int s[256];
    __shared__ int cursor[256];
    int tid = threadIdx.x;
    int b = blockIdx.x;
    int lo = b << 8;
    int ebase = bucket_base[b];
    int ne = bucket_cnt[b];

    s[tid] = 0;
    __syncthreads();
    for (int e = tid; e < ne; e += 256)
        atomicAdd(&s[ebuf[ebase + e] >> 24], 1);
    __syncthreads();
    int v = s[tid];
    __syncthreads();
    for (int off = 1; off < 256; off <<= 1) {
        int t = (tid >= off) ? s[tid - off] : 0;
        __syncthreads();
        s[tid] += t;
        __syncthreads();
    }
    int excl = s[tid] - v;
    int node = lo + tid;
    if (node < NN) {
        row_start[node] = ebase + excl;
        deg[node] = v;
        inv_deg[node] = 1.0f / (float)(v > 1 ? v : 1);
    }
    cursor[tid] = ebase + excl;
    __syncthreads();
    for (int e = tid; e < ne; e += 256) {
        unsigned u = ebuf[ebase + e];
        int p = atomicAdd(&cursor[u >> 24], 1);
        csr_src[p] = (int)(u & 0xFFFFFFu);
    }
}

// ---------------- dtype prep ----------------

__global__ void cast_x_k(const float* __restrict__ x, unsigned short* __restrict__ xb) {
    int i = blockIdx.x * 256 + threadIdx.x;        // 4 floats per thread
    if (i >= NN * NF / 4) return;
    float4 v = *reinterpret_cast<const float4*>(x + (size_t)i * 4);
    ushort4 o;
    o.x = f2bf(v.x); o.y = f2bf(v.y); o.z = f2bf(v.z); o.w = f2bf(v.w);
    *reinterpret_cast<ushort4*>(xb + (size_t)i * 4) = o;
}

// Bt1[n][k], n<256, k<256: k<128 -> Wl1[k][n], else Wr1[k-128][n]
__global__ void prep_bt1_k(const float* __restrict__ Wl1, const float* __restrict__ Wr1,
                           unsigned short* __restrict__ Bt1) {
    int idx = blockIdx.x * 256 + threadIdx.x;
    if (idx >= 256 * 256) return;
    int n = idx >> 8, k = idx & 255;
    float v = (k < 128) ? Wl1[(size_t)k * NH + n] : Wr1[(size_t)(k - 128) * NH + n];
    Bt1[idx] = f2bf(v);
}

// Bt2[n][k], n<96, k<256: n<47 -> Wl2[k][n]; 48<=n<95 -> Wr2[k][n-48]; else 0
__global__ void prep_bt2_k(const float* __restrict__ Wl2, const float* __restrict__ Wr2,
                           unsigned short* __restrict__ Bt2) {
    int idx = blockIdx.x * 256 + threadIdx.x;
    if (idx >= 96 * 256) return;
    int n = idx >> 8, k = idx & 255;
    float v = 0.f;
    if (n < 47) v = Wl2[(size_t)k * NC + n];
    else if (n >= 48 && n < 95) v = Wr2[(size_t)k * NC + (n - 48)];
    Bt2[idx] = f2bf(v);
}

// ---------------- aggregation ----------------

// mean1[i,:] = inv_deg * sum_{j->i} xb[j,:]  (bf16 in, f32 acc, bf16 out), unroll 2
__global__ __launch_bounds__(256) void agg_mean_128b_k(const unsigned short* __restrict__ xb,
                                                       const int* __restrict__ csr_src,
                                                       const int* __restrict__ row_start,
                                                       const int* __restrict__ deg,
                                                       const float* __restrict__ inv_deg,
                                                       unsigned short* __restrict__ mean1) {
    int node = (blockIdx.x * 256 + threadIdx.x) >> 6;
    int lane = threadIdx.x & 63;
    if (node >= NN) return;
    int s0 = row_start[node];
    int d  = deg[node];
    float ax = 0.f, ay = 0.f;
    int j = 0;
    for (; j + 1 < d; j += 2) {
        int sA = csr_src[s0 + j];
        int sB = csr_src[s0 + j + 1];
        unsigned uA = *reinterpret_cast<const unsigned*>(xb + (size_t)sA * NF + lane * 2);
        unsigned uB = *reinterpret_cast<const unsigned*>(xb + (size_t)sB * NF + lane * 2);
        ax += bfl(uA); ay += bfh(uA);
        ax += bfl(uB); ay += bfh(uB);
    }
    if (j < d) {
        int s = csr_src[s0 + j];
        unsigned u = *reinterpret_cast<const unsigned*>(xb + (size_t)s * NF + lane * 2);
        ax += bfl(u); ay += bfh(u);
    }
    float inv = inv_deg[node];
    unsigned o = (unsigned)f2bf(ax * inv) | ((unsigned)f2bf(ay * inv) << 16);
    *reinterpret_cast<unsigned*>(mean1 + (size_t)node * NF + lane * 2) = o;
}

// out[i,c] += inv_deg * sum_{j->i} tb[j,c]   (bf16 rows padded to 64 = one 128B line), unroll 4
__global__ __launch_bounds__(256) void agg_mean_47b_add_k(const unsigned short* __restrict__ tb,
                                                          const int* __restrict__ csr_src,
                                                          const int* __restrict__ row_start,
                                                          const int* __restrict__ deg,
                                                          const float* __restrict__ inv_deg,
                                                          float* __restrict__ out) {
    int node = (blockIdx.x * 256 + threadIdx.x) >> 6;
    int lane = threadIdx.x & 63;
    if (node >= NN) return;
    int s0 = row_start[node];
    int d  = deg[node];
    float acc = 0.f;
    int j = 0;
    for (; j + 3 < d; j += 4) {
        int sA = csr_src[s0 + j];
        int sB = csr_src[s0 + j + 1];
        int sC = csr_src[s0 + j + 2];
        int sD = csr_src[s0 + j + 3];
        float a = bfl((unsigned)tb[(size_t)sA * 64 + lane]);
        float b = bfl((unsigned)tb[(size_t)sB * 64 + lane]);
        float c = bfl((unsigned)tb[(size_t)sC * 64 + lane]);
        float e = bfl((unsigned)tb[(size_t)sD * 64 + lane]);
        acc += a + b + c + e;
    }
    for (; j < d; ++j) {
        int s = csr_src[s0 + j];
        acc += bfl((unsigned)tb[(size_t)s * 64 + lane]);
    }
    if (lane < NC) {
        size_t o = (size_t)node * NC + lane;
        out[o] = out[o] + acc * inv_deg[node];
    }
}

// ---------------- GEMM1 (MFMA): h = relu([mean1|x]_bf16 @ Bt1^T + b1) ----------------

__global__ __launch_bounds__(256) void gemm1_mfma_k(const unsigned short* __restrict__ mean1,
                                                    const unsigned short* __restrict__ xb,
                                                    const unsigned short* __restrict__ Bt1,
                                                    const float* __restrict__ b1,
                                                    unsigned short* __restrict__ h) {
    __shared__ short As[2][128 * 32];
    __shared__ short Bs[2][128 * 32];
    const int tid = threadIdx.x;
    const int row0 = blockIdx.x * 128;
    const int col0 = blockIdx.y * 128;
    const int lane = tid & 63;
    const int wid = tid >> 6;
    const int wr = wid >> 1, wc = wid & 1;
    const int r15 = lane & 15;
    const int swz = ((lane >> 4) ^ ((lane >> 1) & 3)) & 3;

    f32x4 acc[4][4];
    #pragma unroll
    for (int i = 0; i < 4; ++i)
        #pragma unroll
        for (int j = 0; j < 4; ++j)
            acc[i][j] = f32x4{0.f, 0.f, 0.f, 0.f};

    bf16x8 ra[2], rb[2];

    auto load_tiles = [&](int kt) {
        #pragma unroll
        for (int i = 0; i < 2; ++i) {
            int c = tid + i * 256;
            int row = c >> 2, g = c & 3;
            int grow = row0 + row;
            const unsigned short* asrc = (kt < 128) ? mean1 : xb;
            int kb = (kt & 127) + g * 8;
            bf16x8 va = {0,0,0,0,0,0,0,0};
            if (grow < NN) va = *reinterpret_cast<const bf16x8*>(asrc + (size_t)grow * NF + kb);
            ra[i] = va;
            int n = col0 + row;
            rb[i] = *reinterpret_cast<const bf16x8*>(Bt1 + (size_t)n * 256 + kt + g * 8);
        }
    };
    auto write_tiles = [&](int buf) {
        #pragma unroll
        for (int i = 0; i < 2; ++i) {
            int c = tid + i * 256;
            int row = c >> 2, g = c & 3;
            int slot = g ^ ((row >> 1) & 3);
            *reinterpret_cast<bf16x8*>(&As[buf][row * 32 + slot * 8]) = ra[i];
            *reinterpret_cast<bf16x8*>(&Bs[buf][row * 32 + slot * 8]) = rb[i];
        }
    };
    auto compute = [&](int buf) {
        bf16x8 a[4], b[4];
        #pragma unroll
        for (int mi = 0; mi < 4; ++mi)
            a[mi] = *reinterpret_cast<const bf16x8*>(&As[buf][(wr * 64 + mi * 16 + r15) * 32 + swz * 8]);
        #pragma unroll
        for (int ni = 0; ni < 4; ++ni)
            b[ni] = *reinterpret_cast<const bf16x8*>(&Bs[buf][(wc * 64 + ni * 16 + r15) * 32 + swz * 8]);
        #pragma unroll
        for (int mi = 0; mi < 4; ++mi)
            #pragma unroll
            for (int ni = 0; ni < 4; ++ni)
                acc[mi][ni] = __builtin_amdgcn_mfma_f32_16x16x32_bf16(a[mi], b[ni], acc[mi][ni], 0, 0, 0);
    };

    load_tiles(0);
    write_tiles(0);
    __syncthreads();
    int cur = 0;
    #pragma unroll 1
    for (int ks = 0; ks < 8; ++ks) {
        if (ks + 1 < 8) load_tiles((ks + 1) * 32);
        compute(cur);
        if (ks + 1 < 8) write_tiles(cur ^ 1);
        __syncthreads();
        cur ^= 1;
    }

    #pragma unroll
    for (int ni = 0; ni < 4; ++ni) {
        int col = col0 + wc * 64 + ni * 16 + r15;
        float bias = b1[col];
        #pragma unroll
        for (int mi = 0; mi < 4; ++mi) {
            int rbase = row0 + wr * 64 + mi * 16 + (lane >> 4) * 4;
            f32x4 c = acc[mi][ni];
            #pragma unroll
            for (int q = 0; q < 4; ++q) {
                int row = rbase + q;
                if (row < NN) {
                    float v = fmaxf(c[q] + bias, 0.f);
                    h[(size_t)row * NH + col] = f2bf(v);
                }
            }
        }
    }
}

// ---------------- GEMM2 (MFMA): tb = bf16(h@Wl2) ; out = h@Wr2 + b2 ----------------

__global__ __launch_bounds__(256) void gemm2_mfma_k(const unsigned short* __restrict__ h,
                                                    const unsigned short* __restrict__ Bt2,
                                                    const float* __restrict__ b2,
                                                    unsigned short* __restrict__ tb,
                                                    float* __restrict__ out) {
    __shared__ short As[2][128 * 32];
    __shared__ short Bs[2][96 * 32];
    const int tid = threadIdx.x;
    const int row0 = blockIdx.x * 128;
    const int lane = tid & 63;
    const int wid = tid >> 6;
    const int wr = wid >> 1, wc = wid & 1;
    const int r15 = lane & 15;
    const int swz = ((lane >> 4) ^ ((lane >> 1) & 3)) & 3;

    f32x4 acc[4][3];
    #pragma unroll
    for (int i = 0; i < 4; ++i)
        #pragma unroll
        for (int j = 0; j < 3; ++j)
            acc[i][j] = f32x4{0.f, 0.f, 0.f, 0.f};

    bf16x8 ra[2], rb[2];

    auto load_tiles = [&](int kt) {
        #pragma unroll
        for (int i = 0; i < 2; ++i) {
            int c = tid + i * 256;
            int row = c >> 2, g = c & 3;
            int grow = row0 + row;
            bf16x8 va = {0,0,0,0,0,0,0,0};
            if (grow < NN) va = *reinterpret_cast<const bf16x8*>(h + (size_t)grow * NH + kt + g * 8);
            ra[i] = va;
            if (c < 96 * 4)
                rb[i] = *reinterpret_cast<const bf16x8*>(Bt2 + (size_t)row * 256 + kt + g * 8);
        }
    };
    auto write_tiles = [&](int buf) {
        #pragma unroll
        for (int i = 0; i < 2; ++i) {
            int c = tid + i * 256;
            int row = c >> 2, g = c & 3;
            int slot = g ^ ((row >> 1) & 3);
            *reinterpret_cast<bf16x8*>(&As[buf][row * 32 + slot * 8]) = ra[i];
            if (c < 96 * 4)
                *reinterpret_cast<bf16x8*>(&Bs[buf][row * 32 + slot * 8]) = rb[i];
        }
    };
    auto compute = [&](int buf) {
        bf16x8 a[4], b[3];
        #pragma unroll
        for (int mi = 0; mi < 4; ++mi)
            a[mi] = *reinterpret_cast<const bf16x8*>(&As[buf][(wr * 64 + mi * 16 + r15) * 32 + swz * 8]);
        #pragma unroll
        for (int ni = 0; ni < 3; ++ni)
            b[ni] = *reinterpret_cast<const bf16x8*>(&Bs[buf][(wc * 48 + ni * 16 + r15) * 32 + swz * 8]);
        #pragma unroll
        for (int mi = 0; mi < 4; ++mi)
            #pragma unroll
            for (int ni = 0; ni < 3; ++ni)
                acc[mi][ni] = __builtin_amdgcn_mfma_f32_16x16x32_bf16(a[mi], b[ni], acc[mi][ni], 0, 0, 0);
    };

    load_tiles(0);
    write_tiles(0);
    __syncthreads();
    int cur = 0;
    #pragma unroll 1
    for (int ks = 0; ks < 8; ++ks) {
        if (ks + 1 < 8) load_tiles((ks + 1) * 32);
        compute(cur);
        if (ks + 1 < 8) write_tiles(cur ^ 1);
        __syncthreads();
        cur ^= 1;
    }

    #pragma unroll
    for (int ni = 0; ni < 3; ++ni) {
        int col = wc * 48 + ni * 16 + r15;       // 0..95
        float bias = (col >= 48 && col < 95) ? b2[col - 48] : 0.f;
        #pragma unroll
        for (int mi = 0; mi < 4; ++mi) {
            int rbase = row0 + wr * 64 + mi * 16 + (lane >> 4) * 4;
            f32x4 c = acc[mi][ni];
            #pragma unroll
            for (int q = 0; q < 4; ++q) {
                int row = rbase + q;
                if (row < NN) {
                    if (col < 47)
                        tb[(size_t)row * 64 + col] = f2bf(c[q]);
                    else if (col >= 48 && col < 95)
                        out[(size_t)row * NC + (col - 48)] = c[q] + bias;
                }
            }
        }
    }
}

// ---------------- launch ----------------

extern "C" void kernel_launch(void* const* d_in, const int* in_sizes, int n_in,
                              void* d_out, int out_size, void* d_ws, size_t ws_size,
                              hipStream_t stream) {
    const float* x    = (const float*)d_in[0];
    const int*   eidx = (const int*)d_in[1];
    const float* Wl1  = (const float*)d_in[2];
    const float* Wr1  = (const float*)d_in[3];
    const float* b1   = (const float*)d_in[4];
    const float* Wl2  = (const float*)d_in[5];
    const float* Wr2  = (const float*)d_in[6];
    const float* b2   = (const float*)d_in[7];
    float* out = (float*)d_out;

    const int* src = eidx;
    const int* dst = eidx + NE;

    size_t off = 0;
    auto alloc = [&](size_t bytes) -> void* {
        void* p = (char*)d_ws + off;
        off += (bytes + 511) & ~(size_t)511;
        return p;
    };
    int*            deg        = (int*)alloc((size_t)NN * 4);
    int*            row_start  = (int*)alloc((size_t)NN * 4);
    float*          inv_deg    = (float*)alloc((size_t)NN * 4);
    int*            csr_src    = (int*)alloc((size_t)NE * 4);
    unsigned*       ebuf       = (unsigned*)alloc((size_t)NE * 4);
    int*            chunk_hist = (int*)alloc((size_t)NCH * NB * 4);
    int*            chunk_off  = (int*)alloc((size_t)NCH * NB * 4);
    int*            bkt_cnt    = (int*)alloc((size_t)NB * 4);
    int*            bkt_base   = (int*)alloc((size_t)NB * 4);
    unsigned short* xb         = (unsigned short*)alloc((size_t)NN * NF * 2);
    unsigned short* mean1      = (unsigned short*)alloc((size_t)NN * NF * 2);
    unsigned short* hbuf       = (unsigned short*)alloc((size_t)NN * NH * 2);
    unsigned short* tb         = (unsigned short*)alloc((size_t)NN * 64 * 2);
    unsigned short* Bt1        = (unsigned short*)alloc((size_t)256 * 256 * 2);
    unsigned short* Bt2        = (unsigned short*)alloc((size_t)96 * 256 * 2);
    (void)ws_size; (void)n_in; (void)in_sizes; (void)out_size;

    hipMemsetAsync(bkt_cnt, 0, (size_t)NB * 4, stream);
    chunk_hist_k<<<NCH, 256, 0, stream>>>(dst, chunk_hist, bkt_cnt);
    scan_buckets_k<<<1, 512, 0, stream>>>(bkt_cnt, bkt_base);
    colscan_k<<<NB, 64, 0, stream>>>(chunk_hist, bkt_base, chunk_off);
    scatter2_k<<<NCH, 256, 0, stream>>>(src, dst, chunk_off, ebuf);
    build_csr_k<<<NB, 256, 0, stream>>>(ebuf, bkt_base, bkt_cnt,
                                        row_start, deg, inv_deg, csr_src);

    cast_x_k<<<(NN * NF / 4 + 255) / 256, 256, 0, stream>>>(x, xb);
    prep_bt1_k<<<(256 * 256 + 255) / 256, 256, 0, stream>>>(Wl1, Wr1, Bt1);
    prep_bt2_k<<<(96 * 256 + 255) / 256, 256, 0, stream>>>(Wl2, Wr2, Bt2);

    agg_mean_128b_k<<<NN / 4, 256, 0, stream>>>(xb, csr_src, row_start, deg, inv_deg, mean1);

    gemm1_mfma_k<<<dim3((NN + 127) / 128, 2), 256, 0, stream>>>(mean1, xb, Bt1, b1, hbuf);
    gemm2_mfma_k<<<(NN + 127) / 128, 256, 0, stream>>>(hbuf, Bt2, b2, tb, out);

    agg_mean_47b_add_k<<<NN / 4, 256, 0, stream>>>(tb, csr_src, row_start, deg, inv_deg, out);
}

// Round 6
// 278.762 us; speedup vs baseline: 3.1059x; 1.1555x over previous
//
#include <hip/hip_runtime.h>

#define NN 100000
#define NE 1600000
#define NF 128
#define NH 256
#define NC 47
#define NB 391            // ceil(NN/256) buckets of 256 nodes
#define CH 8192           // edges per chunk
#define NCH ((NE + CH - 1) / CH)   // 196

typedef __attribute__((ext_vector_type(8))) short bf16x8;
typedef __attribute__((ext_vector_type(4))) float f32x4;

__device__ inline unsigned short f2bf(float f) {
    unsigned u = __builtin_bit_cast(unsigned, f);
    unsigned r = u + 0x7fffu + ((u >> 16) & 1u);
    return (unsigned short)(r >> 16);
}
__device__ inline float bfl(unsigned u) {           // low ushort -> float
    return __builtin_bit_cast(float, u << 16);
}
__device__ inline float bfh(unsigned u) {           // high ushort -> float
    return __builtin_bit_cast(float, u & 0xffff0000u);
}

// ---------------- CSR build: deterministic 3-pass bucket partition ----------------

__global__ __launch_bounds__(256) void chunk_hist_k(const int* __restrict__ dst,
                                                    int* __restrict__ chunk_hist,
                                                    int* __restrict__ total) {
    __shared__ int h[NB];
    int tid = threadIdx.x, ch = blockIdx.x;
    for (int i = tid; i < NB; i += 256) h[i] = 0;
    __syncthreads();
    int e0 = ch * CH;
    int e1 = min(e0 + CH, NE);
    for (int e = e0 + tid; e < e1; e += 256)
        atomicAdd(&h[dst[e] >> 8], 1);
    __syncthreads();
    for (int i = tid; i < NB; i += 256) {
        int v = h[i];
        chunk_hist[(size_t)ch * NB + i] = v;
        if (v) atomicAdd(&total[i], v);
    }
}

__global__ __launch_bounds__(512) void scan_buckets_k(const int* __restrict__ total,
                                                      int* __restrict__ bucket_base) {
    __shared__ int s[512];
    int tid = threadIdx.x;
    int v = (tid < NB) ? total[tid] : 0;
    s[tid] = v;
    __syncthreads();
    for (int off = 1; off < 512; off <<= 1) {
        int t = (tid >= off) ? s[tid - off] : 0;
        __syncthreads();
        s[tid] += t;
        __syncthreads();
    }
    if (tid < NB) bucket_base[tid] = s[tid] - v;
}

__global__ __launch_bounds__(64) void colscan_k(const int* __restrict__ chunk_hist,
                                                const int* __restrict__ bucket_base,
                                                int* __restrict__ chunk_off) {
    int b = blockIdx.x;
    int lane = threadIdx.x;
    int run = bucket_base[b];
    for (int c0 = 0; c0 < NCH; c0 += 64) {
        int c = c0 + lane;
        int v = (c < NCH) ? chunk_hist[(size_t)c * NB + b] : 0;
        int s = v;
        #pragma unroll
        for (int off = 1; off < 64; off <<= 1) {
            int t = __shfl_up(s, off);
            if (lane >= off) s += t;
        }
        if (c < NCH) chunk_off[(size_t)c * NB + b] = run + s - v;
        run += __shfl(s, 63);
    }
}

__global__ __launch_bounds__(256) void scatter2_k(const int* __restrict__ src,
                                                  const int* __restrict__ dst,
                                                  const int* __restrict__ chunk_off,
                                                  unsigned* __restrict__ ebuf) {
    __shared__ int cur[NB];
    int tid = threadIdx.x, ch = blockIdx.x;
    for (int i = tid; i < NB; i += 256)
        cur[i] = chunk_off[(size_t)ch * NB + i];
    __syncthreads();
    int e0 = ch * CH;
    int e1 = min(e0 + CH, NE);
    for (int e = e0 + tid; e < e1; e += 256) {
        int d = dst[e];
        int b = d >> 8;
        int p = atomicAdd(&cur[b], 1);
        ebuf[p] = ((unsigned)(d & 255) << 24) | (unsigned)src[e];
    }
}

__global__ __launch_bounds__(256) void build_csr_k(const unsigned* __restrict__ ebuf,
                                                   const int* __restrict__ bucket_base,
                                                   const int* __restrict__ bucket_cnt,
                                                   int* __restrict__ row_start,
                                                   int* __restrict__ deg,
                                                   float* __restrict__ inv_deg,
                                                   int* __restrict__ csr_src) {
    __shared__ int s[256];
    __shared__ int cursor[256];
    int tid = threadIdx.x;
    int b = blockIdx.x;
    int lo = b << 8;
    int ebase = bucket_base[b];
    int ne = bucket_cnt[b];

    s[tid] = 0;
    __syncthreads();
    for (int e = tid; e < ne; e += 256)
        atomicAdd(&s[ebuf[ebase + e] >> 24], 1);
    __syncthreads();
    int v = s[tid];
    __syncthreads();
    for (int off = 1; off < 256; off <<= 1) {
        int t = (tid >= off) ? s[tid - off] : 0;
        __syncthreads();
        s[tid] += t;
        __syncthreads();
    }
    int excl = s[tid] - v;
    int node = lo + tid;
    if (node < NN) {
        row_start[node] = ebase + excl;
        deg[node] = v;
        inv_deg[node] = 1.0f / (float)(v > 1 ? v : 1);
    }
    cursor[tid] = ebase + excl;
    __syncthreads();
    for (int e = tid; e < ne; e += 256) {
        unsigned u = ebuf[ebase + e];
        int p = atomicAdd(&cursor[u >> 24], 1);
        csr_src[p] = (int)(u & 0xFFFFFFu);
    }
}

// ---------------- dtype prep ----------------

__global__ void cast_x_k(const float* __restrict__ x, unsigned short* __restrict__ xb) {
    int i = blockIdx.x * 256 + threadIdx.x;
    if (i >= NN * NF / 4) return;
    float4 v = *reinterpret_cast<const float4*>(x + (size_t)i * 4);
    ushort4 o;
    o.x = f2bf(v.x); o.y = f2bf(v.y); o.z = f2bf(v.z); o.w = f2bf(v.w);
    *reinterpret_cast<ushort4*>(xb + (size_t)i * 4) = o;
}

__global__ void prep_bt1_k(const float* __restrict__ Wl1, const float* __restrict__ Wr1,
                           unsigned short* __restrict__ Bt1) {
    int idx = blockIdx.x * 256 + threadIdx.x;
    if (idx >= 256 * 256) return;
    int n = idx >> 8, k = idx & 255;
    float v = (k < 128) ? Wl1[(size_t)k * NH + n] : Wr1[(size_t)(k - 128) * NH + n];
    Bt1[idx] = f2bf(v);
}

__global__ void prep_bt2_k(const float* __restrict__ Wl2, const float* __restrict__ Wr2,
                           unsigned short* __restrict__ Bt2) {
    int idx = blockIdx.x * 256 + threadIdx.x;
    if (idx >= 96 * 256) return;
    int n = idx >> 8, k = idx & 255;
    float v = 0.f;
    if (n < 47) v = Wl2[(size_t)k * NC + n];
    else if (n >= 48 && n < 95) v = Wr2[(size_t)k * NC + (n - 48)];
    Bt2[idx] = f2bf(v);
}

// ---------------- aggregation ----------------

// 4 rows in flight per step: 16-lane groups each load one 256B row as bf16x8/lane.
__global__ __launch_bounds__(256) void agg_mean_128b_k(const unsigned short* __restrict__ xb,
                                                       const int* __restrict__ csr_src,
                                                       const int* __restrict__ row_start,
                                                       const int* __restrict__ deg,
                                                       const float* __restrict__ inv_deg,
                                                       unsigned short* __restrict__ mean1) {
    int node = (blockIdx.x * 256 + threadIdx.x) >> 6;
    int lane = threadIdx.x & 63;
    if (node >= NN) return;
    int grp = lane >> 4, l16 = lane & 15;
    int s0 = row_start[node];
    int d  = deg[node];
    float acc[8] = {0.f,0.f,0.f,0.f,0.f,0.f,0.f,0.f};
    int j = 0;
    for (; j + 7 < d; j += 8) {                 // 8 rows in flight
        int sA = csr_src[s0 + j + grp];
        int sB = csr_src[s0 + j + 4 + grp];
        bf16x8 vA = *reinterpret_cast<const bf16x8*>(xb + (size_t)sA * NF + l16 * 8);
        bf16x8 vB = *reinterpret_cast<const bf16x8*>(xb + (size_t)sB * NF + l16 * 8);
        #pragma unroll
        for (int k = 0; k < 8; ++k)
            acc[k] += bfl((unsigned)(unsigned short)vA[k]) + bfl((unsigned)(unsigned short)vB[k]);
    }
    for (; j + 3 < d; j += 4) {                 // 4 rows
        int s = csr_src[s0 + j + grp];
        bf16x8 v = *reinterpret_cast<const bf16x8*>(xb + (size_t)s * NF + l16 * 8);
        #pragma unroll
        for (int k = 0; k < 8; ++k)
            acc[k] += bfl((unsigned)(unsigned short)v[k]);
    }
    int rem = d - j;
    if (grp < rem) {                            // tail 0..3 rows
        int s = csr_src[s0 + j + grp];
        bf16x8 v = *reinterpret_cast<const bf16x8*>(xb + (size_t)s * NF + l16 * 8);
        #pragma unroll
        for (int k = 0; k < 8; ++k)
            acc[k] += bfl((unsigned)(unsigned short)v[k]);
    }
    // reduce the 4 groups
    #pragma unroll
    for (int k = 0; k < 8; ++k) {
        acc[k] += __shfl_xor(acc[k], 16);
        acc[k] += __shfl_xor(acc[k], 32);
    }
    if (grp == 0) {
        float inv = inv_deg[node];
        bf16x8 o;
        #pragma unroll
        for (int k = 0; k < 8; ++k)
            o[k] = (short)f2bf(acc[k] * inv);
        *reinterpret_cast<bf16x8*>(mean1 + (size_t)node * NF + l16 * 8) = o;
    }
}

// 2 rows in flight per load: 32-lane groups each load one 128B tb row (dword/lane).
__global__ __launch_bounds__(256) void agg_mean_47b_add_k(const unsigned short* __restrict__ tb,
                                                          const int* __restrict__ csr_src,
                                                          const int* __restrict__ row_start,
                                                          const int* __restrict__ deg,
                                                          const float* __restrict__ inv_deg,
                                                          float* __restrict__ out) {
    int node = (blockIdx.x * 256 + threadIdx.x) >> 6;
    int lane = threadIdx.x & 63;
    if (node >= NN) return;
    int grp = lane >> 5, l32 = lane & 31;
    int s0 = row_start[node];
    int d  = deg[node];
    float a0 = 0.f, a1 = 0.f;
    int j = 0;
    for (; j + 7 < d; j += 8) {                 // 8 rows in flight
        int sA = csr_src[s0 + j + grp];
        int sB = csr_src[s0 + j + 2 + grp];
        int sC = csr_src[s0 + j + 4 + grp];
        int sD = csr_src[s0 + j + 6 + grp];
        unsigned uA = *reinterpret_cast<const unsigned*>(tb + (size_t)sA * 64 + l32 * 2);
        unsigned uB = *reinterpret_cast<const unsigned*>(tb + (size_t)sB * 64 + l32 * 2);
        unsigned uC = *reinterpret_cast<const unsigned*>(tb + (size_t)sC * 64 + l32 * 2);
        unsigned uD = *reinterpret_cast<const unsigned*>(tb + (size_t)sD * 64 + l32 * 2);
        a0 += bfl(uA) + bfl(uB) + bfl(uC) + bfl(uD);
        a1 += bfh(uA) + bfh(uB) + bfh(uC) + bfh(uD);
    }
    for (; j + 1 < d; j += 2) {                 // 2 rows
        int s = csr_src[s0 + j + grp];
        unsigned u = *reinterpret_cast<const unsigned*>(tb + (size_t)s * 64 + l32 * 2);
        a0 += bfl(u); a1 += bfh(u);
    }
    if (j < d && grp == 0) {                    // tail 1 row
        int s = csr_src[s0 + j];
        unsigned u = *reinterpret_cast<const unsigned*>(tb + (size_t)s * 64 + l32 * 2);
        a0 += bfl(u); a1 += bfh(u);
    }
    a0 += __shfl_xor(a0, 32);
    a1 += __shfl_xor(a1, 32);
    if (grp == 0) {
        float inv = inv_deg[node];
        int c = l32 * 2;
        if (c + 1 < NC) {
            size_t o = (size_t)node * NC + c;
            out[o]     += a0 * inv;
            out[o + 1] += a1 * inv;
        } else if (c < NC) {
            out[(size_t)node * NC + c] += a0 * inv;
        }
    }
}

// ---------------- GEMM1 (MFMA): h = relu([mean1|x]_bf16 @ Bt1^T + b1) ----------------

__global__ __launch_bounds__(256) void gemm1_mfma_k(const unsigned short* __restrict__ mean1,
                                                    const unsigned short* __restrict__ xb,
                                                    const unsigned short* __restrict__ Bt1,
                                                    const float* __restrict__ b1,
                                                    unsigned short* __restrict__ h) {
    __shared__ short As[2][128 * 32];
    __shared__ short Bs[2][128 * 32];
    const int tid = threadIdx.x;
    const int row0 = blockIdx.x * 128;
    const int col0 = blockIdx.y * 128;
    const int lane = tid & 63;
    const int wid = tid >> 6;
    const int wr = wid >> 1, wc = wid & 1;
    const int r15 = lane & 15;
    const int swz = ((lane >> 4) ^ ((lane >> 1) & 3)) & 3;

    f32x4 acc[4][4];
    #pragma unroll
    for (int i = 0; i < 4; ++i)
        #pragma unroll
        for (int j = 0; j < 4; ++j)
            acc[i][j] = f32x4{0.f, 0.f, 0.f, 0.f};

    bf16x8 ra[2], rb[2];

    auto load_tiles = [&](int kt) {
        #pragma unroll
        for (int i = 0; i < 2; ++i) {
            int c = tid + i * 256;
            int row = c >> 2, g = c & 3;
            int grow = row0 + row;
            const unsigned short* asrc = (kt < 128) ? mean1 : xb;
            int kb = (kt & 127) + g * 8;
            bf16x8 va = {0,0,0,0,0,0,0,0};
            if (grow < NN) va = *reinterpret_cast<const bf16x8*>(asrc + (size_t)grow * NF + kb);
            ra[i] = va;
            int n = col0 + row;
            rb[i] = *reinterpret_cast<const bf16x8*>(Bt1 + (size_t)n * 256 + kt + g * 8);
        }
    };
    auto write_tiles = [&](int buf) {
        #pragma unroll
        for (int i = 0; i < 2; ++i) {
            int c = tid + i * 256;
            int row = c >> 2, g = c & 3;
            int slot = g ^ ((row >> 1) & 3);
            *reinterpret_cast<bf16x8*>(&As[buf][row * 32 + slot * 8]) = ra[i];
            *reinterpret_cast<bf16x8*>(&Bs[buf][row * 32 + slot * 8]) = rb[i];
        }
    };
    auto compute = [&](int buf) {
        bf16x8 a[4], b[4];
        #pragma unroll
        for (int mi = 0; mi < 4; ++mi)
            a[mi] = *reinterpret_cast<const bf16x8*>(&As[buf][(wr * 64 + mi * 16 + r15) * 32 + swz * 8]);
        #pragma unroll
        for (int ni = 0; ni < 4; ++ni)
            b[ni] = *reinterpret_cast<const bf16x8*>(&Bs[buf][(wc * 64 + ni * 16 + r15) * 32 + swz * 8]);
        #pragma unroll
        for (int mi = 0; mi < 4; ++mi)
            #pragma unroll
            for (int ni = 0; ni < 4; ++ni)
                acc[mi][ni] = __builtin_amdgcn_mfma_f32_16x16x32_bf16(a[mi], b[ni], acc[mi][ni], 0, 0, 0);
    };

    load_tiles(0);
    write_tiles(0);
    __syncthreads();
    int cur = 0;
    #pragma unroll 1
    for (int ks = 0; ks < 8; ++ks) {
        if (ks + 1 < 8) load_tiles((ks + 1) * 32);
        compute(cur);
        if (ks + 1 < 8) write_tiles(cur ^ 1);
        __syncthreads();
        cur ^= 1;
    }

    #pragma unroll
    for (int ni = 0; ni < 4; ++ni) {
        int col = col0 + wc * 64 + ni * 16 + r15;
        float bias = b1[col];
        #pragma unroll
        for (int mi = 0; mi < 4; ++mi) {
            int rbase = row0 + wr * 64 + mi * 16 + (lane >> 4) * 4;
            f32x4 c = acc[mi][ni];
            #pragma unroll
            for (int q = 0; q < 4; ++q) {
                int row = rbase + q;
                if (row < NN) {
                    float v = fmaxf(c[q] + bias, 0.f);
                    h[(size_t)row * NH + col] = f2bf(v);
                }
            }
        }
    }
}

// ---------------- GEMM2 (MFMA): tb = bf16(h@Wl2) ; out = h@Wr2 + b2 ----------------

__global__ __launch_bounds__(256) void gemm2_mfma_k(const unsigned short* __restrict__ h,
                                                    const unsigned short* __restrict__ Bt2,
                                                    const float* __restrict__ b2,
                                                    unsigned short* __restrict__ tb,
                                                    float* __restrict__ out) {
    __shared__ short As[2][128 * 32];
    __shared__ short Bs[2][96 * 32];
    const int tid = threadIdx.x;
    const int row0 = blockIdx.x * 128;
    const int lane = tid & 63;
    const int wid = tid >> 6;
    const int wr = wid >> 1, wc = wid & 1;
    const int r15 = lane & 15;
    const int swz = ((lane >> 4) ^ ((lane >> 1) & 3)) & 3;

    f32x4 acc[4][3];
    #pragma unroll
    for (int i = 0; i < 4; ++i)
        #pragma unroll
        for (int j = 0; j < 3; ++j)
            acc[i][j] = f32x4{0.f, 0.f, 0.f, 0.f};

    bf16x8 ra[2], rb[2];

    auto load_tiles = [&](int kt) {
        #pragma unroll
        for (int i = 0; i < 2; ++i) {
            int c = tid + i * 256;
            int row = c >> 2, g = c & 3;
            int grow = row0 + row;
            bf16x8 va = {0,0,0,0,0,0,0,0};
            if (grow < NN) va = *reinterpret_cast<const bf16x8*>(h + (size_t)grow * NH + kt + g * 8);
            ra[i] = va;
            if (c < 96 * 4)
                rb[i] = *reinterpret_cast<const bf16x8*>(Bt2 + (size_t)row * 256 + kt + g * 8);
        }
    };
    auto write_tiles = [&](int buf) {
        #pragma unroll
        for (int i = 0; i < 2; ++i) {
            int c = tid + i * 256;
            int row = c >> 2, g = c & 3;
            int slot = g ^ ((row >> 1) & 3);
            *reinterpret_cast<bf16x8*>(&As[buf][row * 32 + slot * 8]) = ra[i];
            if (c < 96 * 4)
                *reinterpret_cast<bf16x8*>(&Bs[buf][row * 32 + slot * 8]) = rb[i];
        }
    };
    auto compute = [&](int buf) {
        bf16x8 a[4], b[3];
        #pragma unroll
        for (int mi = 0; mi < 4; ++mi)
            a[mi] = *reinterpret_cast<const bf16x8*>(&As[buf][(wr * 64 + mi * 16 + r15) * 32 + swz * 8]);
        #pragma unroll
        for (int ni = 0; ni < 3; ++ni)
            b[ni] = *reinterpret_cast<const bf16x8*>(&Bs[buf][(wc * 48 + ni * 16 + r15) * 32 + swz * 8]);
        #pragma unroll
        for (int mi = 0; mi < 4; ++mi)
            #pragma unroll
            for (int ni = 0; ni < 3; ++ni)
                acc[mi][ni] = __builtin_amdgcn_mfma_f32_16x16x32_bf16(a[mi], b[ni], acc[mi][ni], 0, 0, 0);
    };

    load_tiles(0);
    write_tiles(0);
    __syncthreads();
    int cur = 0;
    #pragma unroll 1
    for (int ks = 0; ks < 8; ++ks) {
        if (ks + 1 < 8) load_tiles((ks + 1) * 32);
        compute(cur);
        if (ks + 1 < 8) write_tiles(cur ^ 1);
        __syncthreads();
        cur ^= 1;
    }

    #pragma unroll
    for (int ni = 0; ni < 3; ++ni) {
        int col = wc * 48 + ni * 16 + r15;       // 0..95
        float bias = (col >= 48 && col < 95) ? b2[col - 48] : 0.f;
        #pragma unroll
        for (int mi = 0; mi < 4; ++mi) {
            int rbase = row0 + wr * 64 + mi * 16 + (lane >> 4) * 4;
            f32x4 c = acc[mi][ni];
            #pragma unroll
            for (int q = 0; q < 4; ++q) {
                int row = rbase + q;
                if (row < NN) {
                    if (col < 47)
                        tb[(size_t)row * 64 + col] = f2bf(c[q]);
                    else if (col >= 48 && col < 95)
                        out[(size_t)row * NC + (col - 48)] = c[q] + bias;
                }
            }
        }
    }
}

// ---------------- launch ----------------

extern "C" void kernel_launch(void* const* d_in, const int* in_sizes, int n_in,
                              void* d_out, int out_size, void* d_ws, size_t ws_size,
                              hipStream_t stream) {
    const float* x    = (const float*)d_in[0];
    const int*   eidx = (const int*)d_in[1];
    const float* Wl1  = (const float*)d_in[2];
    const float* Wr1  = (const float*)d_in[3];
    const float* b1   = (const float*)d_in[4];
    const float* Wl2  = (const float*)d_in[5];
    const float* Wr2  = (const float*)d_in[6];
    const float* b2   = (const float*)d_in[7];
    float* out = (float*)d_out;

    const int* src = eidx;
    const int* dst = eidx + NE;

    size_t off = 0;
    auto alloc = [&](size_t bytes) -> void* {
        void* p = (char*)d_ws + off;
        off += (bytes + 511) & ~(size_t)511;
        return p;
    };
    int*            deg        = (int*)alloc((size_t)NN * 4);
    int*            row_start  = (int*)alloc((size_t)NN * 4);
    float*          inv_deg    = (float*)alloc((size_t)NN * 4);
    int*            csr_src    = (int*)alloc((size_t)NE * 4);
    unsigned*       ebuf       = (unsigned*)alloc((size_t)NE * 4);
    int*            chunk_hist = (int*)alloc((size_t)NCH * NB * 4);
    int*            chunk_off  = (int*)alloc((size_t)NCH * NB * 4);
    int*            bkt_cnt    = (int*)alloc((size_t)NB * 4);
    int*            bkt_base   = (int*)alloc((size_t)NB * 4);
    unsigned short* xb         = (unsigned short*)alloc((size_t)NN * NF * 2);
    unsigned short* mean1      = (unsigned short*)alloc((size_t)NN * NF * 2);
    unsigned short* hbuf       = (unsigned short*)alloc((size_t)NN * NH * 2);
    unsigned short* tb         = (unsigned short*)alloc((size_t)NN * 64 * 2);
    unsigned short* Bt1        = (unsigned short*)alloc((size_t)256 * 256 * 2);
    unsigned short* Bt2        = (unsigned short*)alloc((size_t)96 * 256 * 2);
    (void)ws_size; (void)n_in; (void)in_sizes; (void)out_size;

    hipMemsetAsync(bkt_cnt, 0, (size_t)NB * 4, stream);
    chunk_hist_k<<<NCH, 256, 0, stream>>>(dst, chunk_hist, bkt_cnt);
    scan_buckets_k<<<1, 512, 0, stream>>>(bkt_cnt, bkt_base);
    colscan_k<<<NB, 64, 0, stream>>>(chunk_hist, bkt_base, chunk_off);
    scatter2_k<<<NCH, 256, 0, stream>>>(src, dst, chunk_off, ebuf);
    build_csr_k<<<NB, 256, 0, stream>>>(ebuf, bkt_base, bkt_cnt,
                                        row_start, deg, inv_deg, csr_src);

    cast_x_k<<<(NN * NF / 4 + 255) / 256, 256, 0, stream>>>(x, xb);
    prep_bt1_k<<<(256 * 256 + 255) / 256, 256, 0, stream>>>(Wl1, Wr1, Bt1);
    prep_bt2_k<<<(96 * 256 + 255) / 256, 256, 0, stream>>>(Wl2, Wr2, Bt2);

    agg_mean_128b_k<<<NN / 4, 256, 0, stream>>>(xb, csr_src, row_start, deg, inv_deg, mean1);

    gemm1_mfma_k<<<dim3((NN + 127) / 128, 2), 256, 0, stream>>>(mean1, xb, Bt1, b1, hbuf);
    gemm2_mfma_k<<<(NN + 127) / 128, 256, 0, stream>>>(hbuf, Bt2, b2, tb, out);

    agg_mean_47b_add_k<<<NN / 4, 256, 0, stream>>>(tb, csr_src, row_start, deg, inv_deg, out);
}

// Round 7
// 255.127 us; speedup vs baseline: 3.3937x; 1.0926x over previous
//
#include <hip/hip_runtime.h>

#define NN 100000
#define NE 1600000
#define NF 128
#define NH 256
#define NC 47
#define NB 391            // ceil(NN/256) buckets of 256 nodes
#define CH 8192           // edges per chunk
#define NCH ((NE + CH - 1) / CH)   // 196

// prep_k block-role offsets
#define PB_HIST 0
#define PB_CAST (PB_HIST + NCH)                  // 196
#define NCAST   (NN * NF / 4 / 256)              // 12500
#define PB_BT1  (PB_CAST + NCAST)                // 12696
#define PB_BT2  (PB_BT1 + 256)                   // 12952
#define PB_END  (PB_BT2 + 96)                    // 13048

typedef __attribute__((ext_vector_type(8))) short bf16x8;
typedef __attribute__((ext_vector_type(4))) float f32x4;

__device__ inline unsigned short f2bf(float f) {
    unsigned u = __builtin_bit_cast(unsigned, f);
    unsigned r = u + 0x7fffu + ((u >> 16) & 1u);
    return (unsigned short)(r >> 16);
}
__device__ inline float bfl(unsigned u) {
    return __builtin_bit_cast(float, u << 16);
}
__device__ inline float bfh(unsigned u) {
    return __builtin_bit_cast(float, u & 0xffff0000u);
}

// ---------------- fused prep: chunk_hist | cast_x | prep_bt1 | prep_bt2 ----------------

__global__ __launch_bounds__(256) void prep_k(const int* __restrict__ dst,
                                              int* __restrict__ chunk_hist,
                                              int* __restrict__ total,
                                              const float* __restrict__ x,
                                              unsigned short* __restrict__ xb,
                                              const float* __restrict__ Wl1,
                                              const float* __restrict__ Wr1,
                                              unsigned short* __restrict__ Bt1,
                                              const float* __restrict__ Wl2,
                                              const float* __restrict__ Wr2,
                                              unsigned short* __restrict__ Bt2) {
    __shared__ int h[NB];
    int tid = threadIdx.x;
    int blk = blockIdx.x;
    if (blk < PB_CAST) {                       // chunk histogram
        int ch = blk;
        for (int i = tid; i < NB; i += 256) h[i] = 0;
        __syncthreads();
        int e0 = ch * CH;
        int e1 = min(e0 + CH, NE);
        for (int e = e0 + tid; e < e1; e += 256)
            atomicAdd(&h[dst[e] >> 8], 1);
        __syncthreads();
        for (int i = tid; i < NB; i += 256) {
            int v = h[i];
            chunk_hist[(size_t)ch * NB + i] = v;
            if (v) atomicAdd(&total[i], v);
        }
    } else if (blk < PB_BT1) {                 // cast x -> bf16
        int i = (blk - PB_CAST) * 256 + tid;
        float4 v = *reinterpret_cast<const float4*>(x + (size_t)i * 4);
        ushort4 o;
        o.x = f2bf(v.x); o.y = f2bf(v.y); o.z = f2bf(v.z); o.w = f2bf(v.w);
        *reinterpret_cast<ushort4*>(xb + (size_t)i * 4) = o;
    } else if (blk < PB_BT2) {                 // Bt1[n][k]
        int idx = (blk - PB_BT1) * 256 + tid;
        int n = idx >> 8, k = idx & 255;
        float v = (k < 128) ? Wl1[(size_t)k * NH + n] : Wr1[(size_t)(k - 128) * NH + n];
        Bt1[idx] = f2bf(v);
    } else {                                   // Bt2[n][k]
        int idx = (blk - PB_BT2) * 256 + tid;
        int n = idx >> 8, k = idx & 255;
        float v = 0.f;
        if (n < 47) v = Wl2[(size_t)k * NC + n];
        else if (n >= 48 && n < 95) v = Wr2[(size_t)k * NC + (n - 48)];
        Bt2[idx] = f2bf(v);
    }
}

// ---------------- fused scan + per-bucket column scan ----------------

__global__ __launch_bounds__(64) void scancol_k(const int* __restrict__ chunk_hist,
                                                const int* __restrict__ total,
                                                int* __restrict__ bucket_base,
                                                int* __restrict__ chunk_off) {
    int b = blockIdx.x;
    int lane = threadIdx.x;
    // base = sum_{i<b} total[i]
    int base = 0;
    for (int i0 = 0; i0 < NB; i0 += 64) {
        int i = i0 + lane;
        base += (i < b) ? total[i] : 0;
    }
    #pragma unroll
    for (int off = 1; off < 64; off <<= 1)
        base += __shfl_xor(base, off);
    if (lane == 0) bucket_base[b] = base;
    int run = base;
    for (int c0 = 0; c0 < NCH; c0 += 64) {
        int c = c0 + lane;
        int v = (c < NCH) ? chunk_hist[(size_t)c * NB + b] : 0;
        int s = v;
        #pragma unroll
        for (int off = 1; off < 64; off <<= 1) {
            int t = __shfl_up(s, off);
            if (lane >= off) s += t;
        }
        if (c < NCH) chunk_off[(size_t)c * NB + b] = run + s - v;
        run += __shfl(s, 63);
    }
}

__global__ __launch_bounds__(256) void scatter2_k(const int* __restrict__ src,
                                                  const int* __restrict__ dst,
                                                  const int* __restrict__ chunk_off,
                                                  unsigned* __restrict__ ebuf) {
    __shared__ int cur[NB];
    int tid = threadIdx.x, ch = blockIdx.x;
    for (int i = tid; i < NB; i += 256)
        cur[i] = chunk_off[(size_t)ch * NB + i];
    __syncthreads();
    int e0 = ch * CH;
    int e1 = min(e0 + CH, NE);
    for (int e = e0 + tid; e < e1; e += 256) {
        int d = dst[e];
        int b = d >> 8;
        int p = atomicAdd(&cur[b], 1);
        ebuf[p] = ((unsigned)(d & 255) << 24) | (unsigned)src[e];
    }
}

__global__ __launch_bounds__(256) void build_csr_k(const unsigned* __restrict__ ebuf,
                                                   const int* __restrict__ bucket_base,
                                                   const int* __restrict__ bucket_cnt,
                                                   int* __restrict__ row_start,
                                                   int* __restrict__ deg,
                                                   float* __restrict__ inv_deg,
                                                   int* __restrict__ csr_src) {
    __shared__ int s[256];
    __shared__ int cursor[256];
    int tid = threadIdx.x;
    int b = blockIdx.x;
    int lo = b << 8;
    int ebase = bucket_base[b];
    int ne = bucket_cnt[b];

    s[tid] = 0;
    __syncthreads();
    for (int e = tid; e < ne; e += 256)
        atomicAdd(&s[ebuf[ebase + e] >> 24], 1);
    __syncthreads();
    int v = s[tid];
    __syncthreads();
    for (int off = 1; off < 256; off <<= 1) {
        int t = (tid >= off) ? s[tid - off] : 0;
        __syncthreads();
        s[tid] += t;
        __syncthreads();
    }
    int excl = s[tid] - v;
    int node = lo + tid;
    if (node < NN) {
        row_start[node] = ebase + excl;
        deg[node] = v;
        inv_deg[node] = 1.0f / (float)(v > 1 ? v : 1);
    }
    cursor[tid] = ebase + excl;
    __syncthreads();
    for (int e = tid; e < ne; e += 256) {
        unsigned u = ebuf[ebase + e];
        int p = atomicAdd(&cursor[u >> 24], 1);
        csr_src[p] = (int)(u & 0xFFFFFFu);
    }
}

// ---------------- aggregation ----------------

__global__ __launch_bounds__(256) void agg_mean_128b_k(const unsigned short* __restrict__ xb,
                                                       const int* __restrict__ csr_src,
                                                       const int* __restrict__ row_start,
                                                       const int* __restrict__ deg,
                                                       const float* __restrict__ inv_deg,
                                                       unsigned short* __restrict__ mean1) {
    int node = (blockIdx.x * 256 + threadIdx.x) >> 6;
    int lane = threadIdx.x & 63;
    if (node >= NN) return;
    int grp = lane >> 4, l16 = lane & 15;
    int s0 = row_start[node];
    int d  = deg[node];
    float acc[8] = {0.f,0.f,0.f,0.f,0.f,0.f,0.f,0.f};
    int j = 0;
    for (; j + 7 < d; j += 8) {
        int sA = csr_src[s0 + j + grp];
        int sB = csr_src[s0 + j + 4 + grp];
        bf16x8 vA = *reinterpret_cast<const bf16x8*>(xb + (size_t)sA * NF + l16 * 8);
        bf16x8 vB = *reinterpret_cast<const bf16x8*>(xb + (size_t)sB * NF + l16 * 8);
        #pragma unroll
        for (int k = 0; k < 8; ++k)
            acc[k] += bfl((unsigned)(unsigned short)vA[k]) + bfl((unsigned)(unsigned short)vB[k]);
    }
    for (; j + 3 < d; j += 4) {
        int s = csr_src[s0 + j + grp];
        bf16x8 v = *reinterpret_cast<const bf16x8*>(xb + (size_t)s * NF + l16 * 8);
        #pragma unroll
        for (int k = 0; k < 8; ++k)
            acc[k] += bfl((unsigned)(unsigned short)v[k]);
    }
    int rem = d - j;
    if (grp < rem) {
        int s = csr_src[s0 + j + grp];
        bf16x8 v = *reinterpret_cast<const bf16x8*>(xb + (size_t)s * NF + l16 * 8);
        #pragma unroll
        for (int k = 0; k < 8; ++k)
            acc[k] += bfl((unsigned)(unsigned short)v[k]);
    }
    #pragma unroll
    for (int k = 0; k < 8; ++k) {
        acc[k] += __shfl_xor(acc[k], 16);
        acc[k] += __shfl_xor(acc[k], 32);
    }
    if (grp == 0) {
        float inv = inv_deg[node];
        bf16x8 o;
        #pragma unroll
        for (int k = 0; k < 8; ++k)
            o[k] = (short)f2bf(acc[k] * inv);
        *reinterpret_cast<bf16x8*>(mean1 + (size_t)node * NF + l16 * 8) = o;
    }
}

__global__ __launch_bounds__(256) void agg_mean_47b_add_k(const unsigned short* __restrict__ tb,
                                                          const int* __restrict__ csr_src,
                                                          const int* __restrict__ row_start,
                                                          const int* __restrict__ deg,
                                                          const float* __restrict__ inv_deg,
                                                          float* __restrict__ out) {
    int node = (blockIdx.x * 256 + threadIdx.x) >> 6;
    int lane = threadIdx.x & 63;
    if (node >= NN) return;
    int grp = lane >> 5, l32 = lane & 31;
    int s0 = row_start[node];
    int d  = deg[node];
    float a0 = 0.f, a1 = 0.f;
    int j = 0;
    for (; j + 7 < d; j += 8) {
        int sA = csr_src[s0 + j + grp];
        int sB = csr_src[s0 + j + 2 + grp];
        int sC = csr_src[s0 + j + 4 + grp];
        int sD = csr_src[s0 + j + 6 + grp];
        unsigned uA = *reinterpret_cast<const unsigned*>(tb + (size_t)sA * 64 + l32 * 2);
        unsigned uB = *reinterpret_cast<const unsigned*>(tb + (size_t)sB * 64 + l32 * 2);
        unsigned uC = *reinterpret_cast<const unsigned*>(tb + (size_t)sC * 64 + l32 * 2);
        unsigned uD = *reinterpret_cast<const unsigned*>(tb + (size_t)sD * 64 + l32 * 2);
        a0 += bfl(uA) + bfl(uB) + bfl(uC) + bfl(uD);
        a1 += bfh(uA) + bfh(uB) + bfh(uC) + bfh(uD);
    }
    for (; j + 1 < d; j += 2) {
        int s = csr_src[s0 + j + grp];
        unsigned u = *reinterpret_cast<const unsigned*>(tb + (size_t)s * 64 + l32 * 2);
        a0 += bfl(u); a1 += bfh(u);
    }
    if (j < d && grp == 0) {
        int s = csr_src[s0 + j];
        unsigned u = *reinterpret_cast<const unsigned*>(tb + (size_t)s * 64 + l32 * 2);
        a0 += bfl(u); a1 += bfh(u);
    }
    a0 += __shfl_xor(a0, 32);
    a1 += __shfl_xor(a1, 32);
    if (grp == 0) {
        float inv = inv_deg[node];
        int c = l32 * 2;
        if (c + 1 < NC) {
            size_t o = (size_t)node * NC + c;
            out[o]     += a0 * inv;
            out[o + 1] += a1 * inv;
        } else if (c < NC) {
            out[(size_t)node * NC + c] += a0 * inv;
        }
    }
}

// ---------------- fused GEMM12: h = relu([mean1|x]@Bt1^T+b1) in LDS; tb/out = h@Bt2^T ----------------
// 512 thr (8 waves). gemm1: waves 2x4 (64x64 each), BM=128, BN=256, BK=32.
// h kept in LDS (bf16, XOR-swizzled). gemm2: waves 4x2 (32x48 each), B-frags from global.

__global__ __launch_bounds__(512) void gemm12_k(const unsigned short* __restrict__ mean1,
                                                const unsigned short* __restrict__ xb,
                                                const unsigned short* __restrict__ Bt1,
                                                const float* __restrict__ b1,
                                                const unsigned short* __restrict__ Bt2,
                                                const float* __restrict__ b2,
                                                unsigned short* __restrict__ tb,
                                                float* __restrict__ out) {
    __shared__ short As[2][128 * 32];
    __shared__ short Bs[2][256 * 32];
    __shared__ unsigned short Hs[128 * 256];     // [row][kslot^(row&31)]
    const int tid = threadIdx.x;
    const int row0 = blockIdx.x * 128;
    const int lane = tid & 63;
    const int wid = tid >> 6;                    // 0..7
    const int r15 = lane & 15;
    const int swz = ((lane >> 4) ^ ((lane >> 1) & 3)) & 3;

    // ---- gemm1 ----
    const int wr = wid >> 2, wc = wid & 3;       // 2x4
    f32x4 acc[4][4];
    #pragma unroll
    for (int i = 0; i < 4; ++i)
        #pragma unroll
        for (int j = 0; j < 4; ++j)
            acc[i][j] = f32x4{0.f, 0.f, 0.f, 0.f};

    bf16x8 ra, rb[2];
    auto load_tiles = [&](int kt) {
        {
            int row = tid >> 2, g = tid & 3;     // A: 128 rows x 4 groups
            int grow = row0 + row;
            const unsigned short* asrc = (kt < 128) ? mean1 : xb;
            int kb = (kt & 127) + g * 8;
            bf16x8 va = {0,0,0,0,0,0,0,0};
            if (grow < NN) va = *reinterpret_cast<const bf16x8*>(asrc + (size_t)grow * NF + kb);
            ra = va;
        }
        #pragma unroll
        for (int i = 0; i < 2; ++i) {            // B: 256 rows x 4 groups
            int c = tid + i * 512;
            int rn = c >> 2, g = c & 3;
            rb[i] = *reinterpret_cast<const bf16x8*>(Bt1 + (size_t)rn * 256 + kt + g * 8);
        }
    };
    auto write_tiles = [&](int buf) {
        {
            int row = tid >> 2, g = tid & 3;
            int slot = g ^ ((row >> 1) & 3);
            *reinterpret_cast<bf16x8*>(&As[buf][row * 32 + slot * 8]) = ra;
        }
        #pragma unroll
        for (int i = 0; i < 2; ++i) {
            int c = tid + i * 512;
            int rn = c >> 2, g = c & 3;
            int slot = g ^ ((rn >> 1) & 3);
            *reinterpret_cast<bf16x8*>(&Bs[buf][rn * 32 + slot * 8]) = rb[i];
        }
    };
    auto compute = [&](int buf) {
        bf16x8 a[4], b[4];
        #pragma unroll
        for (int mi = 0; mi < 4; ++mi)
            a[mi] = *reinterpret_cast<const bf16x8*>(&As[buf][(wr * 64 + mi * 16 + r15) * 32 + swz * 8]);
        #pragma unroll
        for (int ni = 0; ni < 4; ++ni)
            b[ni] = *reinterpret_cast<const bf16x8*>(&Bs[buf][(wc * 64 + ni * 16 + r15) * 32 + swz * 8]);
        #pragma unroll
        for (int mi = 0; mi < 4; ++mi)
            #pragma unroll
            for (int ni = 0; ni < 4; ++ni)
                acc[mi][ni] = __builtin_amdgcn_mfma_f32_16x16x32_bf16(a[mi], b[ni], acc[mi][ni], 0, 0, 0);
    };

    load_tiles(0);
    write_tiles(0);
    __syncthreads();
    int cur = 0;
    #pragma unroll 1
    for (int ks = 0; ks < 8; ++ks) {
        if (ks + 1 < 8) load_tiles((ks + 1) * 32);
        compute(cur);
        if (ks + 1 < 8) write_tiles(cur ^ 1);
        __syncthreads();
        cur ^= 1;
    }

    // h -> LDS (relu+bias, bf16, swizzled)
    #pragma unroll
    for (int ni = 0; ni < 4; ++ni) {
        int col = wc * 64 + ni * 16 + r15;
        float bias = b1[col];
        int kgrp = col >> 3, within = col & 7;
        #pragma unroll
        for (int mi = 0; mi < 4; ++mi) {
            int rbase = wr * 64 + mi * 16 + (lane >> 4) * 4;
            f32x4 c = acc[mi][ni];
            #pragma unroll
            for (int q = 0; q < 4; ++q) {
                int row = rbase + q;
                float v = fmaxf(c[q] + bias, 0.f);
                Hs[row * 256 + (kgrp ^ (row & 31)) * 8 + within] = f2bf(v);
            }
        }
    }
    __syncthreads();

    // ---- gemm2: A from Hs, B from global Bt2 ----
    const int wr2 = wid >> 1, wc2 = wid & 1;     // 4x2
    f32x4 acc2[2][3];
    #pragma unroll
    for (int i = 0; i < 2; ++i)
        #pragma unroll
        for (int j = 0; j < 3; ++j)
            acc2[i][j] = f32x4{0.f, 0.f, 0.f, 0.f};

    #pragma unroll 1
    for (int kt = 0; kt < 256; kt += 32) {
        bf16x8 a2[2], b2f[3];
        #pragma unroll
        for (int mi = 0; mi < 2; ++mi) {
            int row = wr2 * 32 + mi * 16 + r15;
            int kgrp = (kt >> 3) + (lane >> 4);
            a2[mi] = *reinterpret_cast<const bf16x8*>(&Hs[row * 256 + (kgrp ^ (row & 31)) * 8]);
        }
        #pragma unroll
        for (int ni = 0; ni < 3; ++ni) {
            int n = wc2 * 48 + ni * 16 + r15;
            b2f[ni] = *reinterpret_cast<const bf16x8*>(Bt2 + (size_t)n * 256 + kt + (lane >> 4) * 8);
        }
        #pragma unroll
        for (int mi = 0; mi < 2; ++mi)
            #pragma unroll
            for (int ni = 0; ni < 3; ++ni)
                acc2[mi][ni] = __builtin_amdgcn_mfma_f32_16x16x32_bf16(a2[mi], b2f[ni], acc2[mi][ni], 0, 0, 0);
    }

    #pragma unroll
    for (int ni = 0; ni < 3; ++ni) {
        int col = wc2 * 48 + ni * 16 + r15;      // 0..95
        float bias = (col >= 48 && col < 95) ? b2[col - 48] : 0.f;
        #pragma unroll
        for (int mi = 0; mi < 2; ++mi) {
            int rbase = row0 + wr2 * 32 + mi * 16 + (lane >> 4) * 4;
            f32x4 c = acc2[mi][ni];
            #pragma unroll
            for (int q = 0; q < 4; ++q) {
                int row = rbase + q;
                if (row < NN) {
                    if (col < 47)
                        tb[(size_t)row * 64 + col] = f2bf(c[q]);
                    else if (col >= 48 && col < 95)
                        out[(size_t)row * NC + (col - 48)] = c[q] + bias;
                }
            }
        }
    }
}

// ---------------- launch ----------------

extern "C" void kernel_launch(void* const* d_in, const int* in_sizes, int n_in,
                              void* d_out, int out_size, void* d_ws, size_t ws_size,
                              hipStream_t stream) {
    const float* x    = (const float*)d_in[0];
    const int*   eidx = (const int*)d_in[1];
    const float* Wl1  = (const float*)d_in[2];
    const float* Wr1  = (const float*)d_in[3];
    const float* b1   = (const float*)d_in[4];
    const float* Wl2  = (const float*)d_in[5];
    const float* Wr2  = (const float*)d_in[6];
    const float* b2   = (const float*)d_in[7];
    float* out = (float*)d_out;

    const int* src = eidx;
    const int* dst = eidx + NE;

    size_t off = 0;
    auto alloc = [&](size_t bytes) -> void* {
        void* p = (char*)d_ws + off;
        off += (bytes + 511) & ~(size_t)511;
        return p;
    };
    int*            deg        = (int*)alloc((size_t)NN * 4);
    int*            row_start  = (int*)alloc((size_t)NN * 4);
    float*          inv_deg    = (float*)alloc((size_t)NN * 4);
    int*            csr_src    = (int*)alloc((size_t)NE * 4);
    unsigned*       ebuf       = (unsigned*)alloc((size_t)NE * 4);
    int*            chunk_hist = (int*)alloc((size_t)NCH * NB * 4);
    int*            chunk_off  = (int*)alloc((size_t)NCH * NB * 4);
    int*            bkt_cnt    = (int*)alloc((size_t)NB * 4);
    int*            bkt_base   = (int*)alloc((size_t)NB * 4);
    unsigned short* xb         = (unsigned short*)alloc((size_t)NN * NF * 2);
    unsigned short* mean1      = (unsigned short*)alloc((size_t)NN * NF * 2);
    unsigned short* tb         = (unsigned short*)alloc((size_t)NN * 64 * 2);
    unsigned short* Bt1        = (unsigned short*)alloc((size_t)256 * 256 * 2);
    unsigned short* Bt2        = (unsigned short*)alloc((size_t)96 * 256 * 2);
    (void)ws_size; (void)n_in; (void)in_sizes; (void)out_size;

    hipMemsetAsync(bkt_cnt, 0, (size_t)NB * 4, stream);
    prep_k<<<PB_END, 256, 0, stream>>>(dst, chunk_hist, bkt_cnt,
                                       x, xb, Wl1, Wr1, Bt1, Wl2, Wr2, Bt2);
    scancol_k<<<NB, 64, 0, stream>>>(chunk_hist, bkt_cnt, bkt_base, chunk_off);
    scatter2_k<<<NCH, 256, 0, stream>>>(src, dst, chunk_off, ebuf);
    build_csr_k<<<NB, 256, 0, stream>>>(ebuf, bkt_base, bkt_cnt,
                                        row_start, deg, inv_deg, csr_src);

    agg_mean_128b_k<<<NN / 4, 256, 0, stream>>>(xb, csr_src, row_start, deg, inv_deg, mean1);

    gemm12_k<<<(NN + 127) / 128, 512, 0, stream>>>(mean1, xb, Bt1, b1, Bt2, b2, tb, out);

    agg_mean_47b_add_k<<<NN / 4, 256, 0, stream>>>(tb, csr_src, row_start, deg, inv_deg, out);
}

// Round 8
// 241.773 us; speedup vs baseline: 3.5811x; 1.0552x over previous
//
#include <hip/hip_runtime.h>

#define NN 100000
#define NE 1600000
#define NF 128
#define NH 256
#define NC 47
#define NB 391            // ceil(NN/256) buckets of 256 nodes
#define CH 8192           // edges per chunk
#define NCH ((NE + CH - 1) / CH)   // 196

// prep_k block-role offsets
#define PB_HIST 0
#define PB_CAST (PB_HIST + NCH)                  // 196
#define NCAST   (NN * NF / 4 / 256)              // 12500
#define PB_BT1  (PB_CAST + NCAST)                // 12696
#define PB_BT2  (PB_BT1 + 256)                   // 12952
#define PB_END  (PB_BT2 + 96)                    // 13048

typedef __attribute__((ext_vector_type(8))) short bf16x8;
typedef __attribute__((ext_vector_type(4))) float f32x4;

__device__ inline unsigned short f2bf(float f) {
    unsigned u = __builtin_bit_cast(unsigned, f);
    unsigned r = u + 0x7fffu + ((u >> 16) & 1u);
    return (unsigned short)(r >> 16);
}
__device__ inline float bfl(unsigned u) {
    return __builtin_bit_cast(float, u << 16);
}
__device__ inline float bfh(unsigned u) {
    return __builtin_bit_cast(float, u & 0xffff0000u);
}

// ---------------- fused prep: chunk_hist | cast_x | prep_bt1 | prep_bt2 ----------------

__global__ __launch_bounds__(256) void prep_k(const int* __restrict__ dst,
                                              int* __restrict__ chunk_hist,
                                              int* __restrict__ total,
                                              const float* __restrict__ x,
                                              unsigned short* __restrict__ xb,
                                              const float* __restrict__ Wl1,
                                              const float* __restrict__ Wr1,
                                              unsigned short* __restrict__ Bt1,
                                              const float* __restrict__ Wl2,
                                              const float* __restrict__ Wr2,
                                              unsigned short* __restrict__ Bt2) {
    __shared__ int h[NB];
    int tid = threadIdx.x;
    int blk = blockIdx.x;
    if (blk < PB_CAST) {                       // chunk histogram
        int ch = blk;
        for (int i = tid; i < NB; i += 256) h[i] = 0;
        __syncthreads();
        int e0 = ch * CH;
        int e1 = min(e0 + CH, NE);
        for (int e = e0 + tid; e < e1; e += 256)
            atomicAdd(&h[dst[e] >> 8], 1);
        __syncthreads();
        for (int i = tid; i < NB; i += 256) {
            int v = h[i];
            chunk_hist[(size_t)ch * NB + i] = v;
            if (v) atomicAdd(&total[i], v);
        }
    } else if (blk < PB_BT1) {                 // cast x -> bf16
        int i = (blk - PB_CAST) * 256 + tid;
        float4 v = *reinterpret_cast<const float4*>(x + (size_t)i * 4);
        ushort4 o;
        o.x = f2bf(v.x); o.y = f2bf(v.y); o.z = f2bf(v.z); o.w = f2bf(v.w);
        *reinterpret_cast<ushort4*>(xb + (size_t)i * 4) = o;
    } else if (blk < PB_BT2) {                 // Bt1[n][k]
        int idx = (blk - PB_BT1) * 256 + tid;
        int n = idx >> 8, k = idx & 255;
        float v = (k < 128) ? Wl1[(size_t)k * NH + n] : Wr1[(size_t)(k - 128) * NH + n];
        Bt1[idx] = f2bf(v);
    } else {                                   // Bt2[n][k]
        int idx = (blk - PB_BT2) * 256 + tid;
        int n = idx >> 8, k = idx & 255;
        float v = 0.f;
        if (n < 47) v = Wl2[(size_t)k * NC + n];
        else if (n >= 48 && n < 95) v = Wr2[(size_t)k * NC + (n - 48)];
        Bt2[idx] = f2bf(v);
    }
}

// ---------------- fused scan + per-bucket column scan ----------------

__global__ __launch_bounds__(64) void scancol_k(const int* __restrict__ chunk_hist,
                                                const int* __restrict__ total,
                                                int* __restrict__ bucket_base,
                                                int* __restrict__ chunk_off) {
    int b = blockIdx.x;
    int lane = threadIdx.x;
    int base = 0;
    for (int i0 = 0; i0 < NB; i0 += 64) {
        int i = i0 + lane;
        base += (i < b) ? total[i] : 0;
    }
    #pragma unroll
    for (int off = 1; off < 64; off <<= 1)
        base += __shfl_xor(base, off);
    if (lane == 0) bucket_base[b] = base;
    int run = base;
    for (int c0 = 0; c0 < NCH; c0 += 64) {
        int c = c0 + lane;
        int v = (c < NCH) ? chunk_hist[(size_t)c * NB + b] : 0;
        int s = v;
        #pragma unroll
        for (int off = 1; off < 64; off <<= 1) {
            int t = __shfl_up(s, off);
            if (lane >= off) s += t;
        }
        if (c < NCH) chunk_off[(size_t)c * NB + b] = run + s - v;
        run += __shfl(s, 63);
    }
}

__global__ __launch_bounds__(256) void scatter2_k(const int* __restrict__ src,
                                                  const int* __restrict__ dst,
                                                  const int* __restrict__ chunk_off,
                                                  unsigned* __restrict__ ebuf) {
    __shared__ int cur[NB];
    int tid = threadIdx.x, ch = blockIdx.x;
    for (int i = tid; i < NB; i += 256)
        cur[i] = chunk_off[(size_t)ch * NB + i];
    __syncthreads();
    int e0 = ch * CH;
    int e1 = min(e0 + CH, NE);
    for (int e = e0 + tid; e < e1; e += 256) {
        int d = dst[e];
        int b = d >> 8;
        int p = atomicAdd(&cur[b], 1);
        ebuf[p] = ((unsigned)(d & 255) << 24) | (unsigned)src[e];
    }
}

__global__ __launch_bounds__(256) void build_csr_k(const unsigned* __restrict__ ebuf,
                                                   const int* __restrict__ bucket_base,
                                                   const int* __restrict__ bucket_cnt,
                                                   int* __restrict__ row_start,
                                                   int* __restrict__ deg,
                                                   float* __restrict__ inv_deg,
                                                   int* __restrict__ csr_src) {
    __shared__ int s[256];
    __shared__ int cursor[256];
    int tid = threadIdx.x;
    int b = blockIdx.x;
    int lo = b << 8;
    int ebase = bucket_base[b];
    int ne = bucket_cnt[b];

    s[tid] = 0;
    __syncthreads();
    for (int e = tid; e < ne; e += 256)
        atomicAdd(&s[ebuf[ebase + e] >> 24], 1);
    __syncthreads();
    int v = s[tid];
    __syncthreads();
    for (int off = 1; off < 256; off <<= 1) {
        int t = (tid >= off) ? s[tid - off] : 0;
        __syncthreads();
        s[tid] += t;
        __syncthreads();
    }
    int excl = s[tid] - v;
    int node = lo + tid;
    if (node < NN) {
        row_start[node] = ebase + excl;
        deg[node] = v;
        inv_deg[node] = 1.0f / (float)(v > 1 ? v : 1);
    }
    cursor[tid] = ebase + excl;
    __syncthreads();
    for (int e = tid; e < ne; e += 256) {
        unsigned u = ebuf[ebase + e];
        int p = atomicAdd(&cursor[u >> 24], 1);
        csr_src[p] = (int)(u & 0xFFFFFFu);
    }
}

// ---------------- aggregation ----------------

__global__ __launch_bounds__(256) void agg_mean_128b_k(const unsigned short* __restrict__ xb,
                                                       const int* __restrict__ csr_src,
                                                       const int* __restrict__ row_start,
                                                       const int* __restrict__ deg,
                                                       const float* __restrict__ inv_deg,
                                                       unsigned short* __restrict__ mean1) {
    int node = (blockIdx.x * 256 + threadIdx.x) >> 6;
    int lane = threadIdx.x & 63;
    if (node >= NN) return;
    int grp = lane >> 4, l16 = lane & 15;
    int s0 = row_start[node];
    int d  = deg[node];
    float acc[8] = {0.f,0.f,0.f,0.f,0.f,0.f,0.f,0.f};
    int j = 0;
    for (; j + 7 < d; j += 8) {
        int sA = csr_src[s0 + j + grp];
        int sB = csr_src[s0 + j + 4 + grp];
        bf16x8 vA = *reinterpret_cast<const bf16x8*>(xb + (size_t)sA * NF + l16 * 8);
        bf16x8 vB = *reinterpret_cast<const bf16x8*>(xb + (size_t)sB * NF + l16 * 8);
        #pragma unroll
        for (int k = 0; k < 8; ++k)
            acc[k] += bfl((unsigned)(unsigned short)vA[k]) + bfl((unsigned)(unsigned short)vB[k]);
    }
    for (; j + 3 < d; j += 4) {
        int s = csr_src[s0 + j + grp];
        bf16x8 v = *reinterpret_cast<const bf16x8*>(xb + (size_t)s * NF + l16 * 8);
        #pragma unroll
        for (int k = 0; k < 8; ++k)
            acc[k] += bfl((unsigned)(unsigned short)v[k]);
    }
    int rem = d - j;
    if (grp < rem) {
        int s = csr_src[s0 + j + grp];
        bf16x8 v = *reinterpret_cast<const bf16x8*>(xb + (size_t)s * NF + l16 * 8);
        #pragma unroll
        for (int k = 0; k < 8; ++k)
            acc[k] += bfl((unsigned)(unsigned short)v[k]);
    }
    #pragma unroll
    for (int k = 0; k < 8; ++k) {
        acc[k] += __shfl_xor(acc[k], 16);
        acc[k] += __shfl_xor(acc[k], 32);
    }
    if (grp == 0) {
        float inv = inv_deg[node];
        bf16x8 o;
        #pragma unroll
        for (int k = 0; k < 8; ++k)
            o[k] = (short)f2bf(acc[k] * inv);
        *reinterpret_cast<bf16x8*>(mean1 + (size_t)node * NF + l16 * 8) = o;
    }
}

__global__ __launch_bounds__(256) void agg_mean_47b_add_k(const unsigned short* __restrict__ tb,
                                                          const int* __restrict__ csr_src,
                                                          const int* __restrict__ row_start,
                                                          const int* __restrict__ deg,
                                                          const float* __restrict__ inv_deg,
                                                          float* __restrict__ out) {
    int node = (blockIdx.x * 256 + threadIdx.x) >> 6;
    int lane = threadIdx.x & 63;
    if (node >= NN) return;
    int grp = lane >> 5, l32 = lane & 31;
    int s0 = row_start[node];
    int d  = deg[node];
    float a0 = 0.f, a1 = 0.f;
    int j = 0;
    for (; j + 7 < d; j += 8) {
        int sA = csr_src[s0 + j + grp];
        int sB = csr_src[s0 + j + 2 + grp];
        int sC = csr_src[s0 + j + 4 + grp];
        int sD = csr_src[s0 + j + 6 + grp];
        unsigned uA = *reinterpret_cast<const unsigned*>(tb + (size_t)sA * 64 + l32 * 2);
        unsigned uB = *reinterpret_cast<const unsigned*>(tb + (size_t)sB * 64 + l32 * 2);
        unsigned uC = *reinterpret_cast<const unsigned*>(tb + (size_t)sC * 64 + l32 * 2);
        unsigned uD = *reinterpret_cast<const unsigned*>(tb + (size_t)sD * 64 + l32 * 2);
        a0 += bfl(uA) + bfl(uB) + bfl(uC) + bfl(uD);
        a1 += bfh(uA) + bfh(uB) + bfh(uC) + bfh(uD);
    }
    for (; j + 1 < d; j += 2) {
        int s = csr_src[s0 + j + grp];
        unsigned u = *reinterpret_cast<const unsigned*>(tb + (size_t)s * 64 + l32 * 2);
        a0 += bfl(u); a1 += bfh(u);
    }
    if (j < d && grp == 0) {
        int s = csr_src[s0 + j];
        unsigned u = *reinterpret_cast<const unsigned*>(tb + (size_t)s * 64 + l32 * 2);
        a0 += bfl(u); a1 += bfh(u);
    }
    a0 += __shfl_xor(a0, 32);
    a1 += __shfl_xor(a1, 32);
    if (grp == 0) {
        float inv = inv_deg[node];
        int c = l32 * 2;
        if (c + 1 < NC) {
            size_t o = (size_t)node * NC + c;
            out[o]     += a0 * inv;
            out[o + 1] += a1 * inv;
        } else if (c < NC) {
            out[(size_t)node * NC + c] += a0 * inv;
        }
    }
}

// ---------------- fused GEMM12 (LDS union: As/Bs die before Hs is born) ----------------
// 512 thr (8 waves). gemm1: waves 2x4 (64x64 each), BM=128, BN=256, BK=32.
// h kept in LDS (bf16, XOR-swizzled). gemm2: waves 4x2 (32x48 each), B-frags from global.
// LDS = max(As+Bs = 48 KB, Hs = 64 KB) = 64 KB -> 2 blocks/CU.

__global__ __launch_bounds__(512) void gemm12_k(const unsigned short* __restrict__ mean1,
                                                const unsigned short* __restrict__ xb,
                                                const unsigned short* __restrict__ Bt1,
                                                const float* __restrict__ b1,
                                                const unsigned short* __restrict__ Bt2,
                                                const float* __restrict__ b2,
                                                unsigned short* __restrict__ tb,
                                                float* __restrict__ out) {
    __shared__ __align__(16) union SM {
        struct { short As[2][128 * 32]; short Bs[2][256 * 32]; } g;   // 48 KB, gemm1 only
        unsigned short Hs[128 * 256];                                  // 64 KB, after gemm1
    } sm;
    const int tid = threadIdx.x;
    const int row0 = blockIdx.x * 128;
    const int lane = tid & 63;
    const int wid = tid >> 6;                    // 0..7
    const int r15 = lane & 15;
    const int swz = ((lane >> 4) ^ ((lane >> 1) & 3)) & 3;

    // ---- gemm1 ----
    const int wr = wid >> 2, wc = wid & 3;       // 2x4
    f32x4 acc[4][4];
    #pragma unroll
    for (int i = 0; i < 4; ++i)
        #pragma unroll
        for (int j = 0; j < 4; ++j)
            acc[i][j] = f32x4{0.f, 0.f, 0.f, 0.f};

    bf16x8 ra, rb[2];
    auto load_tiles = [&](int kt) {
        {
            int row = tid >> 2, g = tid & 3;     // A: 128 rows x 4 groups
            int grow = row0 + row;
            const unsigned short* asrc = (kt < 128) ? mean1 : xb;
            int kb = (kt & 127) + g * 8;
            bf16x8 va = {0,0,0,0,0,0,0,0};
            if (grow < NN) va = *reinterpret_cast<const bf16x8*>(asrc + (size_t)grow * NF + kb);
            ra = va;
        }
        #pragma unroll
        for (int i = 0; i < 2; ++i) {            // B: 256 rows x 4 groups
            int c = tid + i * 512;
            int rn = c >> 2, g = c & 3;
            rb[i] = *reinterpret_cast<const bf16x8*>(Bt1 + (size_t)rn * 256 + kt + g * 8);
        }
    };
    auto write_tiles = [&](int buf) {
        {
            int row = tid >> 2, g = tid & 3;
            int slot = g ^ ((row >> 1) & 3);
            *reinterpret_cast<bf16x8*>(&sm.g.As[buf][row * 32 + slot * 8]) = ra;
        }
        #pragma unroll
        for (int i = 0; i < 2; ++i) {
            int c = tid + i * 512;
            int rn = c >> 2, g = c & 3;
            int slot = g ^ ((rn >> 1) & 3);
            *reinterpret_cast<bf16x8*>(&sm.g.Bs[buf][rn * 32 + slot * 8]) = rb[i];
        }
    };
    auto compute = [&](int buf) {
        bf16x8 a[4], b[4];
        #pragma unroll
        for (int mi = 0; mi < 4; ++mi)
            a[mi] = *reinterpret_cast<const bf16x8*>(&sm.g.As[buf][(wr * 64 + mi * 16 + r15) * 32 + swz * 8]);
        #pragma unroll
        for (int ni = 0; ni < 4; ++ni)
            b[ni] = *reinterpret_cast<const bf16x8*>(&sm.g.Bs[buf][(wc * 64 + ni * 16 + r15) * 32 + swz * 8]);
        #pragma unroll
        for (int mi = 0; mi < 4; ++mi)
            #pragma unroll
            for (int ni = 0; ni < 4; ++ni)
                acc[mi][ni] = __builtin_amdgcn_mfma_f32_16x16x32_bf16(a[mi], b[ni], acc[mi][ni], 0, 0, 0);
    };

    load_tiles(0);
    write_tiles(0);
    __syncthreads();
    int cur = 0;
    #pragma unroll 1
    for (int ks = 0; ks < 8; ++ks) {
        if (ks + 1 < 8) load_tiles((ks + 1) * 32);
        compute(cur);
        if (ks + 1 < 8) write_tiles(cur ^ 1);
        __syncthreads();
        cur ^= 1;
    }
    // after this barrier all gemm1 LDS reads are done -> safe to overwrite with Hs

    // h -> LDS (relu+bias, bf16, swizzled)
    #pragma unroll
    for (int ni = 0; ni < 4; ++ni) {
        int col = wc * 64 + ni * 16 + r15;
        float bias = b1[col];
        int kgrp = col >> 3, within = col & 7;
        #pragma unroll
        for (int mi = 0; mi < 4; ++mi) {
            int rbase = wr * 64 + mi * 16 + (lane >> 4) * 4;
            f32x4 c = acc[mi][ni];
            #pragma unroll
            for (int q = 0; q < 4; ++q) {
                int row = rbase + q;
                float v = fmaxf(c[q] + bias, 0.f);
                sm.Hs[row * 256 + (kgrp ^ (row & 31)) * 8 + within] = f2bf(v);
            }
        }
    }
    __syncthreads();

    // ---- gemm2: A from Hs, B from global Bt2 ----
    const int wr2 = wid >> 1, wc2 = wid & 1;     // 4x2
    f32x4 acc2[2][3];
    #pragma unroll
    for (int i = 0; i < 2; ++i)
        #pragma unroll
        for (int j = 0; j < 3; ++j)
            acc2[i][j] = f32x4{0.f, 0.f, 0.f, 0.f};

    #pragma unroll 1
    for (int kt = 0; kt < 256; kt += 32) {
        bf16x8 a2[2], b2f[3];
        #pragma unroll
        for (int mi = 0; mi < 2; ++mi) {
            int row = wr2 * 32 + mi * 16 + r15;
            int kgrp = (kt >> 3) + (lane >> 4);
            a2[mi] = *reinterpret_cast<const bf16x8*>(&sm.Hs[row * 256 + (kgrp ^ (row & 31)) * 8]);
        }
        #pragma unroll
        for (int ni = 0; ni < 3; ++ni) {
            int n = wc2 * 48 + ni * 16 + r15;
            b2f[ni] = *reinterpret_cast<const bf16x8*>(Bt2 + (size_t)n * 256 + kt + (lane >> 4) * 8);
        }
        #pragma unroll
        for (int mi = 0; mi < 2; ++mi)
            #pragma unroll
            for (int ni = 0; ni < 3; ++ni)
                acc2[mi][ni] = __builtin_amdgcn_mfma_f32_16x16x32_bf16(a2[mi], b2f[ni], acc2[mi][ni], 0, 0, 0);
    }

    #pragma unroll
    for (int ni = 0; ni < 3; ++ni) {
        int col = wc2 * 48 + ni * 16 + r15;      // 0..95
        float bias = (col >= 48 && col < 95) ? b2[col - 48] : 0.f;
        #pragma unroll
        for (int mi = 0; mi < 2; ++mi) {
            int rbase = row0 + wr2 * 32 + mi * 16 + (lane >> 4) * 4;
            f32x4 c = acc2[mi][ni];
            #pragma unroll
            for (int q = 0; q < 4; ++q) {
                int row = rbase + q;
                if (row < NN) {
                    if (col < 47)
                        tb[(size_t)row * 64 + col] = f2bf(c[q]);
                    else if (col >= 48 && col < 95)
                        out[(size_t)row * NC + (col - 48)] = c[q] + bias;
                }
            }
        }
    }
}

// ---------------- launch ----------------

extern "C" void kernel_launch(void* const* d_in, const int* in_sizes, int n_in,
                              void* d_out, int out_size, void* d_ws, size_t ws_size,
                              hipStream_t stream) {
    const float* x    = (const float*)d_in[0];
    const int*   eidx = (const int*)d_in[1];
    const float* Wl1  = (const float*)d_in[2];
    const float* Wr1  = (const float*)d_in[3];
    const float* b1   = (const float*)d_in[4];
    const float* Wl2  = (const float*)d_in[5];
    const float* Wr2  = (const float*)d_in[6];
    const float* b2   = (const float*)d_in[7];
    float* out = (float*)d_out;

    const int* src = eidx;
    const int* dst = eidx + NE;

    size_t off = 0;
    auto alloc = [&](size_t bytes) -> void* {
        void* p = (char*)d_ws + off;
        off += (bytes + 511) & ~(size_t)511;
        return p;
    };
    int*            deg        = (int*)alloc((size_t)NN * 4);
    int*            row_start  = (int*)alloc((size_t)NN * 4);
    float*          inv_deg    = (float*)alloc((size_t)NN * 4);
    int*            csr_src    = (int*)alloc((size_t)NE * 4);
    unsigned*       ebuf       = (unsigned*)alloc((size_t)NE * 4);
    int*            chunk_hist = (int*)alloc((size_t)NCH * NB * 4);
    int*            chunk_off  = (int*)alloc((size_t)NCH * NB * 4);
    int*            bkt_cnt    = (int*)alloc((size_t)NB * 4);
    int*            bkt_base   = (int*)alloc((size_t)NB * 4);
    unsigned short* xb         = (unsigned short*)alloc((size_t)NN * NF * 2);
    unsigned short* mean1      = (unsigned short*)alloc((size_t)NN * NF * 2);
    unsigned short* tb         = (unsigned short*)alloc((size_t)NN * 64 * 2);
    unsigned short* Bt1        = (unsigned short*)alloc((size_t)256 * 256 * 2);
    unsigned short* Bt2        = (unsigned short*)alloc((size_t)96 * 256 * 2);
    (void)ws_size; (void)n_in; (void)in_sizes; (void)out_size;

    hipMemsetAsync(bkt_cnt, 0, (size_t)NB * 4, stream);
    prep_k<<<PB_END, 256, 0, stream>>>(dst, chunk_hist, bkt_cnt,
                                       x, xb, Wl1, Wr1, Bt1, Wl2, Wr2, Bt2);
    scancol_k<<<NB, 64, 0, stream>>>(chunk_hist, bkt_cnt, bkt_base, chunk_off);
    scatter2_k<<<NCH, 256, 0, stream>>>(src, dst, chunk_off, ebuf);
    build_csr_k<<<NB, 256, 0, stream>>>(ebuf, bkt_base, bkt_cnt,
                                        row_start, deg, inv_deg, csr_src);

    agg_mean_128b_k<<<NN / 4, 256, 0, stream>>>(xb, csr_src, row_start, deg, inv_deg, mean1);

    gemm12_k<<<(NN + 127) / 128, 512, 0, stream>>>(mean1, xb, Bt1, b1, Bt2, b2, tb, out);

    agg_mean_47b_add_k<<<NN / 4, 256, 0, stream>>>(tb, csr_src, row_start, deg, inv_deg, out);
}

// Round 9
// 232.713 us; speedup vs baseline: 3.7205x; 1.0389x over previous
//
#include <hip/hip_runtime.h>

#define NN 100000
#define NE 1600000
#define NF 128
#define NH 256
#define NC 47
#define NB 391            // ceil(NN/256) buckets of 256 nodes
#define CH 8192           // edges per chunk
#define NCH ((NE + CH - 1) / CH)   // 196

// prep_k block-role offsets
#define PB_HIST 0
#define PB_CAST (PB_HIST + NCH)                  // 196
#define NCAST   (NN * NF / 4 / 256)              // 12500
#define PB_BT1  (PB_CAST + NCAST)                // 12696
#define PB_BT2  (PB_BT1 + 256)                   // 12952
#define PB_END  (PB_BT2 + 96)                    // 13048

typedef __attribute__((ext_vector_type(8))) short bf16x8;
typedef __attribute__((ext_vector_type(4))) float f32x4;
typedef __attribute__((ext_vector_type(2))) float f32x2;

__device__ inline unsigned short f2bf(float f) {
    unsigned u = __builtin_bit_cast(unsigned, f);
    unsigned r = u + 0x7fffu + ((u >> 16) & 1u);
    return (unsigned short)(r >> 16);
}
__device__ inline float bfl(unsigned u) {
    return __builtin_bit_cast(float, u << 16);
}
__device__ inline float bfh(unsigned u) {
    return __builtin_bit_cast(float, u & 0xffff0000u);
}

// ---------------- fused prep: chunk_hist | cast_x (bf16 + fp8) | prep_bt1 | prep_bt2 ----------------

__global__ __launch_bounds__(256) void prep_k(const int* __restrict__ dst,
                                              int* __restrict__ chunk_hist,
                                              int* __restrict__ total,
                                              const float* __restrict__ x,
                                              unsigned short* __restrict__ xb,
                                              unsigned* __restrict__ xq,
                                              const float* __restrict__ Wl1,
                                              const float* __restrict__ Wr1,
                                              unsigned short* __restrict__ Bt1,
                                              const float* __restrict__ Wl2,
                                              const float* __restrict__ Wr2,
                                              unsigned short* __restrict__ Bt2) {
    __shared__ int h[NB];
    int tid = threadIdx.x;
    int blk = blockIdx.x;
    if (blk < PB_CAST) {                       // chunk histogram
        int ch = blk;
        for (int i = tid; i < NB; i += 256) h[i] = 0;
        __syncthreads();
        int e0 = ch * CH;
        int e1 = min(e0 + CH, NE);
        for (int e = e0 + tid; e < e1; e += 256)
            atomicAdd(&h[dst[e] >> 8], 1);
        __syncthreads();
        for (int i = tid; i < NB; i += 256) {
            int v = h[i];
            chunk_hist[(size_t)ch * NB + i] = v;
            if (v) atomicAdd(&total[i], v);
        }
    } else if (blk < PB_BT1) {                 // cast x -> bf16 + fp8
        int i = (blk - PB_CAST) * 256 + tid;
        float4 v = *reinterpret_cast<const float4*>(x + (size_t)i * 4);
        ushort4 o;
        o.x = f2bf(v.x); o.y = f2bf(v.y); o.z = f2bf(v.z); o.w = f2bf(v.w);
        *reinterpret_cast<ushort4*>(xb + (size_t)i * 4) = o;
        int r = __builtin_amdgcn_cvt_pk_fp8_f32(v.x, v.y, 0, false);
        r = __builtin_amdgcn_cvt_pk_fp8_f32(v.z, v.w, r, true);
        xq[i] = (unsigned)r;
    } else if (blk < PB_BT2) {                 // Bt1[n][k]
        int idx = (blk - PB_BT1) * 256 + tid;
        int n = idx >> 8, k = idx & 255;
        float v = (k < 128) ? Wl1[(size_t)k * NH + n] : Wr1[(size_t)(k - 128) * NH + n];
        Bt1[idx] = f2bf(v);
    } else {                                   // Bt2[n][k]
        int idx = (blk - PB_BT2) * 256 + tid;
        int n = idx >> 8, k = idx & 255;
        float v = 0.f;
        if (n < 47) v = Wl2[(size_t)k * NC + n];
        else if (n >= 48 && n < 95) v = Wr2[(size_t)k * NC + (n - 48)];
        Bt2[idx] = f2bf(v);
    }
}

// ---------------- fused scan + per-bucket column scan ----------------

__global__ __launch_bounds__(64) void scancol_k(const int* __restrict__ chunk_hist,
                                                const int* __restrict__ total,
                                                int* __restrict__ bucket_base,
                                                int* __restrict__ chunk_off) {
    int b = blockIdx.x;
    int lane = threadIdx.x;
    int base = 0;
    for (int i0 = 0; i0 < NB; i0 += 64) {
        int i = i0 + lane;
        base += (i < b) ? total[i] : 0;
    }
    #pragma unroll
    for (int off = 1; off < 64; off <<= 1)
        base += __shfl_xor(base, off);
    if (lane == 0) bucket_base[b] = base;
    int run = base;
    for (int c0 = 0; c0 < NCH; c0 += 64) {
        int c = c0 + lane;
        int v = (c < NCH) ? chunk_hist[(size_t)c * NB + b] : 0;
        int s = v;
        #pragma unroll
        for (int off = 1; off < 64; off <<= 1) {
            int t = __shfl_up(s, off);
            if (lane >= off) s += t;
        }
        if (c < NCH) chunk_off[(size_t)c * NB + b] = run + s - v;
        run += __shfl(s, 63);
    }
}

__global__ __launch_bounds__(256) void scatter2_k(const int* __restrict__ src,
                                                  const int* __restrict__ dst,
                                                  const int* __restrict__ chunk_off,
                                                  unsigned* __restrict__ ebuf) {
    __shared__ int cur[NB];
    int tid = threadIdx.x, ch = blockIdx.x;
    for (int i = tid; i < NB; i += 256)
        cur[i] = chunk_off[(size_t)ch * NB + i];
    __syncthreads();
    int e0 = ch * CH;
    int e1 = min(e0 + CH, NE);
    for (int e = e0 + tid; e < e1; e += 256) {
        int d = dst[e];
        int b = d >> 8;
        int p = atomicAdd(&cur[b], 1);
        ebuf[p] = ((unsigned)(d & 255) << 24) | (unsigned)src[e];
    }
}

__global__ __launch_bounds__(256) void build_csr_k(const unsigned* __restrict__ ebuf,
                                                   const int* __restrict__ bucket_base,
                                                   const int* __restrict__ bucket_cnt,
                                                   int* __restrict__ row_start,
                                                   int* __restrict__ deg,
                                                   float* __restrict__ inv_deg,
                                                   int* __restrict__ csr_src) {
    __shared__ int s[256];
    __shared__ int cursor[256];
    int tid = threadIdx.x;
    int b = blockIdx.x;
    int lo = b << 8;
    int ebase = bucket_base[b];
    int ne = bucket_cnt[b];

    s[tid] = 0;
    __syncthreads();
    for (int e = tid; e < ne; e += 256)
        atomicAdd(&s[ebuf[ebase + e] >> 24], 1);
    __syncthreads();
    int v = s[tid];
    __syncthreads();
    for (int off = 1; off < 256; off <<= 1) {
        int t = (tid >= off) ? s[tid - off] : 0;
        __syncthreads();
        s[tid] += t;
        __syncthreads();
    }
    int excl = s[tid] - v;
    int node = lo + tid;
    if (node < NN) {
        row_start[node] = ebase + excl;
        deg[node] = v;
        inv_deg[node] = 1.0f / (float)(v > 1 ? v : 1);
    }
    cursor[tid] = ebase + excl;
    __syncthreads();
    for (int e = tid; e < ne; e += 256) {
        unsigned u = ebuf[ebase + e];
        int p = atomicAdd(&cursor[u >> 24], 1);
        csr_src[p] = (int)(u & 0xFFFFFFu);
    }
}

// ---------------- aggregation ----------------

// fp8 gather: row = 128B; 16-lane groups load 8B/lane -> 4 rows/load, unroll 2 -> 8 in flight.
__global__ __launch_bounds__(256) void agg_mean_128q_k(const unsigned* __restrict__ xq,
                                                       const int* __restrict__ csr_src,
                                                       const int* __restrict__ row_start,
                                                       const int* __restrict__ deg,
                                                       const float* __restrict__ inv_deg,
                                                       unsigned short* __restrict__ mean1) {
    int node = (blockIdx.x * 256 + threadIdx.x) >> 6;
    int lane = threadIdx.x & 63;
    if (node >= NN) return;
    int grp = lane >> 4, l16 = lane & 15;
    int s0 = row_start[node];
    int d  = deg[node];
    f32x2 acc[4];
    #pragma unroll
    for (int k = 0; k < 4; ++k) acc[k] = f32x2{0.f, 0.f};
    int j = 0;
    for (; j + 7 < d; j += 8) {
        int sA = csr_src[s0 + j + grp];
        int sB = csr_src[s0 + j + 4 + grp];
        uint2 wA = *reinterpret_cast<const uint2*>(xq + (size_t)sA * 32 + l16 * 2);
        uint2 wB = *reinterpret_cast<const uint2*>(xq + (size_t)sB * 32 + l16 * 2);
        acc[0] += __builtin_amdgcn_cvt_pk_f32_fp8((int)wA.x, false);
        acc[1] += __builtin_amdgcn_cvt_pk_f32_fp8((int)wA.x, true);
        acc[2] += __builtin_amdgcn_cvt_pk_f32_fp8((int)wA.y, false);
        acc[3] += __builtin_amdgcn_cvt_pk_f32_fp8((int)wA.y, true);
        acc[0] += __builtin_amdgcn_cvt_pk_f32_fp8((int)wB.x, false);
        acc[1] += __builtin_amdgcn_cvt_pk_f32_fp8((int)wB.x, true);
        acc[2] += __builtin_amdgcn_cvt_pk_f32_fp8((int)wB.y, false);
        acc[3] += __builtin_amdgcn_cvt_pk_f32_fp8((int)wB.y, true);
    }
    for (; j + 3 < d; j += 4) {
        int s = csr_src[s0 + j + grp];
        uint2 w = *reinterpret_cast<const uint2*>(xq + (size_t)s * 32 + l16 * 2);
        acc[0] += __builtin_amdgcn_cvt_pk_f32_fp8((int)w.x, false);
        acc[1] += __builtin_amdgcn_cvt_pk_f32_fp8((int)w.x, true);
        acc[2] += __builtin_amdgcn_cvt_pk_f32_fp8((int)w.y, false);
        acc[3] += __builtin_amdgcn_cvt_pk_f32_fp8((int)w.y, true);
    }
    int rem = d - j;
    if (grp < rem) {
        int s = csr_src[s0 + j + grp];
        uint2 w = *reinterpret_cast<const uint2*>(xq + (size_t)s * 32 + l16 * 2);
        acc[0] += __builtin_amdgcn_cvt_pk_f32_fp8((int)w.x, false);
        acc[1] += __builtin_amdgcn_cvt_pk_f32_fp8((int)w.x, true);
        acc[2] += __builtin_amdgcn_cvt_pk_f32_fp8((int)w.y, false);
        acc[3] += __builtin_amdgcn_cvt_pk_f32_fp8((int)w.y, true);
    }
    #pragma unroll
    for (int k = 0; k < 4; ++k) {
        acc[k].x += __shfl_xor(acc[k].x, 16);
        acc[k].y += __shfl_xor(acc[k].y, 16);
        acc[k].x += __shfl_xor(acc[k].x, 32);
        acc[k].y += __shfl_xor(acc[k].y, 32);
    }
    if (grp == 0) {
        float inv = inv_deg[node];
        bf16x8 o;
        #pragma unroll
        for (int k = 0; k < 4; ++k) {
            o[k * 2]     = (short)f2bf(acc[k].x * inv);
            o[k * 2 + 1] = (short)f2bf(acc[k].y * inv);
        }
        *reinterpret_cast<bf16x8*>(mean1 + (size_t)node * NF + l16 * 8) = o;
    }
}

__global__ __launch_bounds__(256) void agg_mean_47b_add_k(const unsigned short* __restrict__ tb,
                                                          const int* __restrict__ csr_src,
                                                          const int* __restrict__ row_start,
                                                          const int* __restrict__ deg,
                                                          const float* __restrict__ inv_deg,
                                                          float* __restrict__ out) {
    int node = (blockIdx.x * 256 + threadIdx.x) >> 6;
    int lane = threadIdx.x & 63;
    if (node >= NN) return;
    int grp = lane >> 5, l32 = lane & 31;
    int s0 = row_start[node];
    int d  = deg[node];
    float a0 = 0.f, a1 = 0.f;
    int j = 0;
    for (; j + 7 < d; j += 8) {
        int sA = csr_src[s0 + j + grp];
        int sB = csr_src[s0 + j + 2 + grp];
        int sC = csr_src[s0 + j + 4 + grp];
        int sD = csr_src[s0 + j + 6 + grp];
        unsigned uA = *reinterpret_cast<const unsigned*>(tb + (size_t)sA * 64 + l32 * 2);
        unsigned uB = *reinterpret_cast<const unsigned*>(tb + (size_t)sB * 64 + l32 * 2);
        unsigned uC = *reinterpret_cast<const unsigned*>(tb + (size_t)sC * 64 + l32 * 2);
        unsigned uD = *reinterpret_cast<const unsigned*>(tb + (size_t)sD * 64 + l32 * 2);
        a0 += bfl(uA) + bfl(uB) + bfl(uC) + bfl(uD);
        a1 += bfh(uA) + bfh(uB) + bfh(uC) + bfh(uD);
    }
    for (; j + 1 < d; j += 2) {
        int s = csr_src[s0 + j + grp];
        unsigned u = *reinterpret_cast<const unsigned*>(tb + (size_t)s * 64 + l32 * 2);
        a0 += bfl(u); a1 += bfh(u);
    }
    if (j < d && grp == 0) {
        int s = csr_src[s0 + j];
        unsigned u = *reinterpret_cast<const unsigned*>(tb + (size_t)s * 64 + l32 * 2);
        a0 += bfl(u); a1 += bfh(u);
    }
    a0 += __shfl_xor(a0, 32);
    a1 += __shfl_xor(a1, 32);
    if (grp == 0) {
        float inv = inv_deg[node];
        int c = l32 * 2;
        if (c + 1 < NC) {
            size_t o = (size_t)node * NC + c;
            out[o]     += a0 * inv;
            out[o + 1] += a1 * inv;
        } else if (c < NC) {
            out[(size_t)node * NC + c] += a0 * inv;
        }
    }
}

// ---------------- fused GEMM12 (LDS union: As/Bs die before Hs is born) ----------------
// 512 thr (8 waves). gemm1: waves 2x4 (64x64 each), BM=128, BN=256, BK=32.
// h kept in LDS (bf16, XOR-swizzled). gemm2: waves 4x2 (32x48 each), B-frags from global.
// LDS = max(As+Bs = 48 KB, Hs = 64 KB) = 64 KB -> 2 blocks/CU.

__global__ __launch_bounds__(512) void gemm12_k(const unsigned short* __restrict__ mean1,
                                                const unsigned short* __restrict__ xb,
                                                const unsigned short* __restrict__ Bt1,
                                                const float* __restrict__ b1,
                                                const unsigned short* __restrict__ Bt2,
                                                const float* __restrict__ b2,
                                                unsigned short* __restrict__ tb,
                                                float* __restrict__ out) {
    __shared__ __align__(16) union SM {
        struct { short As[2][128 * 32]; short Bs[2][256 * 32]; } g;   // 48 KB, gemm1 only
        unsigned short Hs[128 * 256];                                  // 64 KB, after gemm1
    } sm;
    const int tid = threadIdx.x;
    const int row0 = blockIdx.x * 128;
    const int lane = tid & 63;
    const int wid = tid >> 6;                    // 0..7
    const int r15 = lane & 15;
    const int swz = ((lane >> 4) ^ ((lane >> 1) & 3)) & 3;

    // ---- gemm1 ----
    const int wr = wid >> 2, wc = wid & 3;       // 2x4
    f32x4 acc[4][4];
    #pragma unroll
    for (int i = 0; i < 4; ++i)
        #pragma unroll
        for (int j = 0; j < 4; ++j)
            acc[i][j] = f32x4{0.f, 0.f, 0.f, 0.f};

    bf16x8 ra, rb[2];
    auto load_tiles = [&](int kt) {
        {
            int row = tid >> 2, g = tid & 3;     // A: 128 rows x 4 groups
            int grow = row0 + row;
            const unsigned short* asrc = (kt < 128) ? mean1 : xb;
            int kb = (kt & 127) + g * 8;
            bf16x8 va = {0,0,0,0,0,0,0,0};
            if (grow < NN) va = *reinterpret_cast<const bf16x8*>(asrc + (size_t)grow * NF + kb);
            ra = va;
        }
        #pragma unroll
        for (int i = 0; i < 2; ++i) {            // B: 256 rows x 4 groups
            int c = tid + i * 512;
            int rn = c >> 2, g = c & 3;
            rb[i] = *reinterpret_cast<const bf16x8*>(Bt1 + (size_t)rn * 256 + kt + g * 8);
        }
    };
    auto write_tiles = [&](int buf) {
        {
            int row = tid >> 2, g = tid & 3;
            int slot = g ^ ((row >> 1) & 3);
            *reinterpret_cast<bf16x8*>(&sm.g.As[buf][row * 32 + slot * 8]) = ra;
        }
        #pragma unroll
        for (int i = 0; i < 2; ++i) {
            int c = tid + i * 512;
            int rn = c >> 2, g = c & 3;
            int slot = g ^ ((rn >> 1) & 3);
            *reinterpret_cast<bf16x8*>(&sm.g.Bs[buf][rn * 32 + slot * 8]) = rb[i];
        }
    };
    auto compute = [&](int buf) {
        bf16x8 a[4], b[4];
        #pragma unroll
        for (int mi = 0; mi < 4; ++mi)
            a[mi] = *reinterpret_cast<const bf16x8*>(&sm.g.As[buf][(wr * 64 + mi * 16 + r15) * 32 + swz * 8]);
        #pragma unroll
        for (int ni = 0; ni < 4; ++ni)
            b[ni] = *reinterpret_cast<const bf16x8*>(&sm.g.Bs[buf][(wc * 64 + ni * 16 + r15) * 32 + swz * 8]);
        #pragma unroll
        for (int mi = 0; mi < 4; ++mi)
            #pragma unroll
            for (int ni = 0; ni < 4; ++ni)
                acc[mi][ni] = __builtin_amdgcn_mfma_f32_16x16x32_bf16(a[mi], b[ni], acc[mi][ni], 0, 0, 0);
    };

    load_tiles(0);
    write_tiles(0);
    __syncthreads();
    int cur = 0;
    #pragma unroll 1
    for (int ks = 0; ks < 8; ++ks) {
        if (ks + 1 < 8) load_tiles((ks + 1) * 32);
        compute(cur);
        if (ks + 1 < 8) write_tiles(cur ^ 1);
        __syncthreads();
        cur ^= 1;
    }
    // after this barrier all gemm1 LDS reads are done -> safe to overwrite with Hs

    // h -> LDS (relu+bias, bf16, swizzled)
    #pragma unroll
    for (int ni = 0; ni < 4; ++ni) {
        int col = wc * 64 + ni * 16 + r15;
        float bias = b1[col];
        int kgrp = col >> 3, within = col & 7;
        #pragma unroll
        for (int mi = 0; mi < 4; ++mi) {
            int rbase = wr * 64 + mi * 16 + (lane >> 4) * 4;
            f32x4 c = acc[mi][ni];
            #pragma unroll
            for (int q = 0; q < 4; ++q) {
                int row = rbase + q;
                float v = fmaxf(c[q] + bias, 0.f);
                sm.Hs[row * 256 + (kgrp ^ (row & 31)) * 8 + within] = f2bf(v);
            }
        }
    }
    __syncthreads();

    // ---- gemm2: A from Hs, B from global Bt2 ----
    const int wr2 = wid >> 1, wc2 = wid & 1;     // 4x2
    f32x4 acc2[2][3];
    #pragma unroll
    for (int i = 0; i < 2; ++i)
        #pragma unroll
        for (int j = 0; j < 3; ++j)
            acc2[i][j] = f32x4{0.f, 0.f, 0.f, 0.f};

    #pragma unroll 1
    for (int kt = 0; kt < 256; kt += 32) {
        bf16x8 a2[2], b2f[3];
        #pragma unroll
        for (int mi = 0; mi < 2; ++mi) {
            int row = wr2 * 32 + mi * 16 + r15;
            int kgrp = (kt >> 3) + (lane >> 4);
            a2[mi] = *reinterpret_cast<const bf16x8*>(&sm.Hs[row * 256 + (kgrp ^ (row & 31)) * 8]);
        }
        #pragma unroll
        for (int ni = 0; ni < 3; ++ni) {
            int n = wc2 * 48 + ni * 16 + r15;
            b2f[ni] = *reinterpret_cast<const bf16x8*>(Bt2 + (size_t)n * 256 + kt + (lane >> 4) * 8);
        }
        #pragma unroll
        for (int mi = 0; mi < 2; ++mi)
            #pragma unroll
            for (int ni = 0; ni < 3; ++ni)
                acc2[mi][ni] = __builtin_amdgcn_mfma_f32_16x16x32_bf16(a2[mi], b2f[ni], acc2[mi][ni], 0, 0, 0);
    }

    #pragma unroll
    for (int ni = 0; ni < 3; ++ni) {
        int col = wc2 * 48 + ni * 16 + r15;      // 0..95
        float bias = (col >= 48 && col < 95) ? b2[col - 48] : 0.f;
        #pragma unroll
        for (int mi = 0; mi < 2; ++mi) {
            int rbase = row0 + wr2 * 32 + mi * 16 + (lane >> 4) * 4;
            f32x4 c = acc2[mi][ni];
            #pragma unroll
            for (int q = 0; q < 4; ++q) {
                int row = rbase + q;
                if (row < NN) {
                    if (col < 47)
                        tb[(size_t)row * 64 + col] = f2bf(c[q]);
                    else if (col >= 48 && col < 95)
                        out[(size_t)row * NC + (col - 48)] = c[q] + bias;
                }
            }
        }
    }
}

// ---------------- launch ----------------

extern "C" void kernel_launch(void* const* d_in, const int* in_sizes, int n_in,
                              void* d_out, int out_size, void* d_ws, size_t ws_size,
                              hipStream_t stream) {
    const float* x    = (const float*)d_in[0];
    const int*   eidx = (const int*)d_in[1];
    const float* Wl1  = (const float*)d_in[2];
    const float* Wr1  = (const float*)d_in[3];
    const float* b1   = (const float*)d_in[4];
    const float* Wl2  = (const float*)d_in[5];
    const float* Wr2  = (const float*)d_in[6];
    const float* b2   = (const float*)d_in[7];
    float* out = (float*)d_out;

    const int* src = eidx;
    const int* dst = eidx + NE;

    size_t off = 0;
    auto alloc = [&](size_t bytes) -> void* {
        void* p = (char*)d_ws + off;
        off += (bytes + 511) & ~(size_t)511;
        return p;
    };
    int*            deg        = (int*)alloc((size_t)NN * 4);
    int*            row_start  = (int*)alloc((size_t)NN * 4);
    float*          inv_deg    = (float*)alloc((size_t)NN * 4);
    int*            csr_src    = (int*)alloc((size_t)NE * 4);
    unsigned*       ebuf       = (unsigned*)alloc((size_t)NE * 4);
    int*            chunk_hist = (int*)alloc((size_t)NCH * NB * 4);
    int*            chunk_off  = (int*)alloc((size_t)NCH * NB * 4);
    int*            bkt_cnt    = (int*)alloc((size_t)NB * 4);
    int*            bkt_base   = (int*)alloc((size_t)NB * 4);
    unsigned short* xb         = (unsigned short*)alloc((size_t)NN * NF * 2);
    unsigned*       xq         = (unsigned*)alloc((size_t)NN * NF);       // fp8, 32 words/row
    unsigned short* mean1      = (unsigned short*)alloc((size_t)NN * NF * 2);
    unsigned short* tb         = (unsigned short*)alloc((size_t)NN * 64 * 2);
    unsigned short* Bt1        = (unsigned short*)alloc((size_t)256 * 256 * 2);
    unsigned short* Bt2        = (unsigned short*)alloc((size_t)96 * 256 * 2);
    (void)ws_size; (void)n_in; (void)in_sizes; (void)out_size;

    hipMemsetAsync(bkt_cnt, 0, (size_t)NB * 4, stream);
    prep_k<<<PB_END, 256, 0, stream>>>(dst, chunk_hist, bkt_cnt,
                                       x, xb, xq, Wl1, Wr1, Bt1, Wl2, Wr2, Bt2);
    scancol_k<<<NB, 64, 0, stream>>>(chunk_hist, bkt_cnt, bkt_base, chunk_off);
    scatter2_k<<<NCH, 256, 0, stream>>>(src, dst, chunk_off, ebuf);
    build_csr_k<<<NB, 256, 0, stream>>>(ebuf, bkt_base, bkt_cnt,
                                        row_start, deg, inv_deg, csr_src);

    agg_mean_128q_k<<<NN / 4, 256, 0, stream>>>(xq, csr_src, row_start, deg, inv_deg, mean1);

    gemm12_k<<<(NN + 127) / 128, 512, 0, stream>>>(mean1, xb, Bt1, b1, Bt2, b2, tb, out);

    agg_mean_47b_add_k<<<NN / 4, 256, 0, stream>>>(tb, csr_src, row_start, deg, inv_deg, out);
}

// Round 10
// 230.668 us; speedup vs baseline: 3.7535x; 1.0089x over previous
//
#include <hip/hip_runtime.h>

#define NN 100000
#define NE 1600000
#define NF 128
#define NH 256
#define NC 47
#define NB 391            // ceil(NN/256) buckets of 256 nodes
#define CH 8192           // edges per chunk
#define NCH ((NE + CH - 1) / CH)   // 196

// prep_k block-role offsets
#define PB_HIST 0
#define PB_CAST (PB_HIST + NCH)                  // 196
#define NCAST   (NN * NF / 4 / 256)              // 12500
#define PB_BT1  (PB_CAST + NCAST)                // 12696
#define PB_BT2  (PB_BT1 + 256)                   // 12952
#define PB_END  (PB_BT2 + 96)                    // 13048

typedef __attribute__((ext_vector_type(8))) short bf16x8;
typedef __attribute__((ext_vector_type(4))) float f32x4;
typedef __attribute__((ext_vector_type(2))) float f32x2;

__device__ inline unsigned short f2bf(float f) {
    unsigned u = __builtin_bit_cast(unsigned, f);
    unsigned r = u + 0x7fffu + ((u >> 16) & 1u);
    return (unsigned short)(r >> 16);
}
__device__ inline float bfl(unsigned u) {
    return __builtin_bit_cast(float, u << 16);
}
__device__ inline float bfh(unsigned u) {
    return __builtin_bit_cast(float, u & 0xffff0000u);
}

// ---------------- fused prep: chunk_hist | cast_x (bf16 + fp8) | prep_bt1 | prep_bt2 ----------------

__global__ __launch_bounds__(256) void prep_k(const int* __restrict__ dst,
                                              int* __restrict__ chunk_hist,
                                              int* __restrict__ total,
                                              const float* __restrict__ x,
                                              unsigned short* __restrict__ xb,
                                              unsigned* __restrict__ xq,
                                              const float* __restrict__ Wl1,
                                              const float* __restrict__ Wr1,
                                              unsigned short* __restrict__ Bt1,
                                              const float* __restrict__ Wl2,
                                              const float* __restrict__ Wr2,
                                              unsigned short* __restrict__ Bt2) {
    __shared__ int h[NB];
    int tid = threadIdx.x;
    int blk = blockIdx.x;
    if (blk < PB_CAST) {                       // chunk histogram
        int ch = blk;
        for (int i = tid; i < NB; i += 256) h[i] = 0;
        __syncthreads();
        int e0 = ch * CH;
        int e1 = min(e0 + CH, NE);
        for (int e = e0 + tid; e < e1; e += 256)
            atomicAdd(&h[dst[e] >> 8], 1);
        __syncthreads();
        for (int i = tid; i < NB; i += 256) {
            int v = h[i];
            chunk_hist[(size_t)ch * NB + i] = v;
            if (v) atomicAdd(&total[i], v);
        }
    } else if (blk < PB_BT1) {                 // cast x -> bf16 + fp8
        int i = (blk - PB_CAST) * 256 + tid;
        float4 v = *reinterpret_cast<const float4*>(x + (size_t)i * 4);
        ushort4 o;
        o.x = f2bf(v.x); o.y = f2bf(v.y); o.z = f2bf(v.z); o.w = f2bf(v.w);
        *reinterpret_cast<ushort4*>(xb + (size_t)i * 4) = o;
        int r = __builtin_amdgcn_cvt_pk_fp8_f32(v.x, v.y, 0, false);
        r = __builtin_amdgcn_cvt_pk_fp8_f32(v.z, v.w, r, true);
        xq[i] = (unsigned)r;
    } else if (blk < PB_BT2) {                 // Bt1[n][k]
        int idx = (blk - PB_BT1) * 256 + tid;
        int n = idx >> 8, k = idx & 255;
        float v = (k < 128) ? Wl1[(size_t)k * NH + n] : Wr1[(size_t)(k - 128) * NH + n];
        Bt1[idx] = f2bf(v);
    } else {                                   // Bt2[n][k]
        int idx = (blk - PB_BT2) * 256 + tid;
        int n = idx >> 8, k = idx & 255;
        float v = 0.f;
        if (n < 47) v = Wl2[(size_t)k * NC + n];
        else if (n >= 48 && n < 95) v = Wr2[(size_t)k * NC + (n - 48)];
        Bt2[idx] = f2bf(v);
    }
}

// ---------------- fused scan + per-bucket column scan ----------------

__global__ __launch_bounds__(64) void scancol_k(const int* __restrict__ chunk_hist,
                                                const int* __restrict__ total,
                                                int* __restrict__ bucket_base,
                                                int* __restrict__ chunk_off) {
    int b = blockIdx.x;
    int lane = threadIdx.x;
    int base = 0;
    for (int i0 = 0; i0 < NB; i0 += 64) {
        int i = i0 + lane;
        base += (i < b) ? total[i] : 0;
    }
    #pragma unroll
    for (int off = 1; off < 64; off <<= 1)
        base += __shfl_xor(base, off);
    if (lane == 0) bucket_base[b] = base;
    int run = base;
    for (int c0 = 0; c0 < NCH; c0 += 64) {
        int c = c0 + lane;
        int v = (c < NCH) ? chunk_hist[(size_t)c * NB + b] : 0;
        int s = v;
        #pragma unroll
        for (int off = 1; off < 64; off <<= 1) {
            int t = __shfl_up(s, off);
            if (lane >= off) s += t;
        }
        if (c < NCH) chunk_off[(size_t)c * NB + b] = run + s - v;
        run += __shfl(s, 63);
    }
}

__global__ __launch_bounds__(256) void scatter2_k(const int* __restrict__ src,
                                                  const int* __restrict__ dst,
                                                  const int* __restrict__ chunk_off,
                                                  unsigned* __restrict__ ebuf) {
    __shared__ int cur[NB];
    int tid = threadIdx.x, ch = blockIdx.x;
    for (int i = tid; i < NB; i += 256)
        cur[i] = chunk_off[(size_t)ch * NB + i];
    __syncthreads();
    int e0 = ch * CH;
    int e1 = min(e0 + CH, NE);
    for (int e = e0 + tid; e < e1; e += 256) {
        int d = dst[e];
        int b = d >> 8;
        int p = atomicAdd(&cur[b], 1);
        ebuf[p] = ((unsigned)(d & 255) << 24) | (unsigned)src[e];
    }
}

__global__ __launch_bounds__(256) void build_csr_k(const unsigned* __restrict__ ebuf,
                                                   const int* __restrict__ bucket_base,
                                                   const int* __restrict__ bucket_cnt,
                                                   int* __restrict__ row_start,
                                                   int* __restrict__ deg,
                                                   float* __restrict__ inv_deg,
                                                   int* __restrict__ csr_src) {
    __shared__ int s[256];
    __shared__ int cursor[256];
    int tid = threadIdx.x;
    int b = blockIdx.x;
    int lo = b << 8;
    int ebase = bucket_base[b];
    int ne = bucket_cnt[b];

    s[tid] = 0;
    __syncthreads();
    for (int e = tid; e < ne; e += 256)
        atomicAdd(&s[ebuf[ebase + e] >> 24], 1);
    __syncthreads();
    int v = s[tid];
    __syncthreads();
    for (int off = 1; off < 256; off <<= 1) {
        int t = (tid >= off) ? s[tid - off] : 0;
        __syncthreads();
        s[tid] += t;
        __syncthreads();
    }
    int excl = s[tid] - v;
    int node = lo + tid;
    if (node < NN) {
        row_start[node] = ebase + excl;
        deg[node] = v;
        inv_deg[node] = 1.0f / (float)(v > 1 ? v : 1);
    }
    cursor[tid] = ebase + excl;
    __syncthreads();
    for (int e = tid; e < ne; e += 256) {
        unsigned u = ebuf[ebase + e];
        int p = atomicAdd(&cursor[u >> 24], 1);
        csr_src[p] = (int)(u & 0xFFFFFFu);
    }
}

// ---------------- aggregation ----------------

// fp8 x-gather: row = 128B; 16-lane groups load 8B/lane -> 4 rows/load, unroll 2 -> 8 in flight.
__global__ __launch_bounds__(256) void agg_mean_128q_k(const unsigned* __restrict__ xq,
                                                       const int* __restrict__ csr_src,
                                                       const int* __restrict__ row_start,
                                                       const int* __restrict__ deg,
                                                       const float* __restrict__ inv_deg,
                                                       unsigned short* __restrict__ mean1) {
    int node = (blockIdx.x * 256 + threadIdx.x) >> 6;
    int lane = threadIdx.x & 63;
    if (node >= NN) return;
    int grp = lane >> 4, l16 = lane & 15;
    int s0 = row_start[node];
    int d  = deg[node];
    f32x2 acc[4];
    #pragma unroll
    for (int k = 0; k < 4; ++k) acc[k] = f32x2{0.f, 0.f};
    int j = 0;
    for (; j + 7 < d; j += 8) {
        int sA = csr_src[s0 + j + grp];
        int sB = csr_src[s0 + j + 4 + grp];
        uint2 wA = *reinterpret_cast<const uint2*>(xq + (size_t)sA * 32 + l16 * 2);
        uint2 wB = *reinterpret_cast<const uint2*>(xq + (size_t)sB * 32 + l16 * 2);
        acc[0] += __builtin_amdgcn_cvt_pk_f32_fp8((int)wA.x, false);
        acc[1] += __builtin_amdgcn_cvt_pk_f32_fp8((int)wA.x, true);
        acc[2] += __builtin_amdgcn_cvt_pk_f32_fp8((int)wA.y, false);
        acc[3] += __builtin_amdgcn_cvt_pk_f32_fp8((int)wA.y, true);
        acc[0] += __builtin_amdgcn_cvt_pk_f32_fp8((int)wB.x, false);
        acc[1] += __builtin_amdgcn_cvt_pk_f32_fp8((int)wB.x, true);
        acc[2] += __builtin_amdgcn_cvt_pk_f32_fp8((int)wB.y, false);
        acc[3] += __builtin_amdgcn_cvt_pk_f32_fp8((int)wB.y, true);
    }
    for (; j + 3 < d; j += 4) {
        int s = csr_src[s0 + j + grp];
        uint2 w = *reinterpret_cast<const uint2*>(xq + (size_t)s * 32 + l16 * 2);
        acc[0] += __builtin_amdgcn_cvt_pk_f32_fp8((int)w.x, false);
        acc[1] += __builtin_amdgcn_cvt_pk_f32_fp8((int)w.x, true);
        acc[2] += __builtin_amdgcn_cvt_pk_f32_fp8((int)w.y, false);
        acc[3] += __builtin_amdgcn_cvt_pk_f32_fp8((int)w.y, true);
    }
    int rem = d - j;
    if (grp < rem) {
        int s = csr_src[s0 + j + grp];
        uint2 w = *reinterpret_cast<const uint2*>(xq + (size_t)s * 32 + l16 * 2);
        acc[0] += __builtin_amdgcn_cvt_pk_f32_fp8((int)w.x, false);
        acc[1] += __builtin_amdgcn_cvt_pk_f32_fp8((int)w.x, true);
        acc[2] += __builtin_amdgcn_cvt_pk_f32_fp8((int)w.y, false);
        acc[3] += __builtin_amdgcn_cvt_pk_f32_fp8((int)w.y, true);
    }
    #pragma unroll
    for (int k = 0; k < 4; ++k) {
        acc[k].x += __shfl_xor(acc[k].x, 16);
        acc[k].y += __shfl_xor(acc[k].y, 16);
        acc[k].x += __shfl_xor(acc[k].x, 32);
        acc[k].y += __shfl_xor(acc[k].y, 32);
    }
    if (grp == 0) {
        float inv = inv_deg[node];
        bf16x8 o;
        #pragma unroll
        for (int k = 0; k < 4; ++k) {
            o[k * 2]     = (short)f2bf(acc[k].x * inv);
            o[k * 2 + 1] = (short)f2bf(acc[k].y * inv);
        }
        *reinterpret_cast<bf16x8*>(mean1 + (size_t)node * NF + l16 * 8) = o;
    }
}

// fp8 t-gather: row = 64B; 16-lane groups load 4B/lane -> 4 rows/load, unroll 2 -> 8 in flight.
__global__ __launch_bounds__(256) void agg_mean_47q_add_k(const unsigned* __restrict__ tq,
                                                          const int* __restrict__ csr_src,
                                                          const int* __restrict__ row_start,
                                                          const int* __restrict__ deg,
                                                          const float* __restrict__ inv_deg,
                                                          float* __restrict__ out) {
    int node = (blockIdx.x * 256 + threadIdx.x) >> 6;
    int lane = threadIdx.x & 63;
    if (node >= NN) return;
    int grp = lane >> 4, l16 = lane & 15;
    int s0 = row_start[node];
    int d  = deg[node];
    f32x2 a01 = {0.f, 0.f}, a23 = {0.f, 0.f};
    int j = 0;
    for (; j + 7 < d; j += 8) {
        int sA = csr_src[s0 + j + grp];
        int sB = csr_src[s0 + j + 4 + grp];
        unsigned wA = tq[(size_t)sA * 16 + l16];
        unsigned wB = tq[(size_t)sB * 16 + l16];
        a01 += __builtin_amdgcn_cvt_pk_f32_fp8((int)wA, false);
        a23 += __builtin_amdgcn_cvt_pk_f32_fp8((int)wA, true);
        a01 += __builtin_amdgcn_cvt_pk_f32_fp8((int)wB, false);
        a23 += __builtin_amdgcn_cvt_pk_f32_fp8((int)wB, true);
    }
    for (; j + 3 < d; j += 4) {
        int s = csr_src[s0 + j + grp];
        unsigned w = tq[(size_t)s * 16 + l16];
        a01 += __builtin_amdgcn_cvt_pk_f32_fp8((int)w, false);
        a23 += __builtin_amdgcn_cvt_pk_f32_fp8((int)w, true);
    }
    int rem = d - j;
    if (grp < rem) {
        int s = csr_src[s0 + j + grp];
        unsigned w = tq[(size_t)s * 16 + l16];
        a01 += __builtin_amdgcn_cvt_pk_f32_fp8((int)w, false);
        a23 += __builtin_amdgcn_cvt_pk_f32_fp8((int)w, true);
    }
    a01.x += __shfl_xor(a01.x, 16); a01.y += __shfl_xor(a01.y, 16);
    a23.x += __shfl_xor(a23.x, 16); a23.y += __shfl_xor(a23.y, 16);
    a01.x += __shfl_xor(a01.x, 32); a01.y += __shfl_xor(a01.y, 32);
    a23.x += __shfl_xor(a23.x, 32); a23.y += __shfl_xor(a23.y, 32);
    if (grp == 0) {
        float inv = inv_deg[node];
        int c0 = l16 * 4;
        float vals[4] = {a01.x, a01.y, a23.x, a23.y};
        #pragma unroll
        for (int m = 0; m < 4; ++m) {
            int col = c0 + m;
            if (col < NC) {
                size_t o = (size_t)node * NC + col;
                out[o] += vals[m] * inv;
            }
        }
    }
}

// ---------------- fused GEMM12 (LDS union: As/Bs die before Hs is born) ----------------
// 512 thr (8 waves). gemm1: waves 2x4 (64x64 each), BM=128, BN=256, BK=32.
// h kept in LDS (bf16, XOR-swizzled). gemm2: waves 4x2 (32x48 each), B-frags from global.
// LDS = max(As+Bs = 48 KB, Hs = 64 KB) = 64 KB -> 2 blocks/CU.

__global__ __launch_bounds__(512) void gemm12_k(const unsigned short* __restrict__ mean1,
                                                const unsigned short* __restrict__ xb,
                                                const unsigned short* __restrict__ Bt1,
                                                const float* __restrict__ b1,
                                                const unsigned short* __restrict__ Bt2,
                                                const float* __restrict__ b2,
                                                unsigned char* __restrict__ tq,
                                                float* __restrict__ out) {
    __shared__ __align__(16) union SM {
        struct { short As[2][128 * 32]; short Bs[2][256 * 32]; } g;   // 48 KB, gemm1 only
        unsigned short Hs[128 * 256];                                  // 64 KB, after gemm1
    } sm;
    const int tid = threadIdx.x;
    const int row0 = blockIdx.x * 128;
    const int lane = tid & 63;
    const int wid = tid >> 6;                    // 0..7
    const int r15 = lane & 15;
    const int swz = ((lane >> 4) ^ ((lane >> 1) & 3)) & 3;

    // ---- gemm1 ----
    const int wr = wid >> 2, wc = wid & 3;       // 2x4
    f32x4 acc[4][4];
    #pragma unroll
    for (int i = 0; i < 4; ++i)
        #pragma unroll
        for (int j = 0; j < 4; ++j)
            acc[i][j] = f32x4{0.f, 0.f, 0.f, 0.f};

    bf16x8 ra, rb[2];
    auto load_tiles = [&](int kt) {
        {
            int row = tid >> 2, g = tid & 3;     // A: 128 rows x 4 groups
            int grow = row0 + row;
            const unsigned short* asrc = (kt < 128) ? mean1 : xb;
            int kb = (kt & 127) + g * 8;
            bf16x8 va = {0,0,0,0,0,0,0,0};
            if (grow < NN) va = *reinterpret_cast<const bf16x8*>(asrc + (size_t)grow * NF + kb);
            ra = va;
        }
        #pragma unroll
        for (int i = 0; i < 2; ++i) {            // B: 256 rows x 4 groups
            int c = tid + i * 512;
            int rn = c >> 2, g = c & 3;
            rb[i] = *reinterpret_cast<const bf16x8*>(Bt1 + (size_t)rn * 256 + kt + g * 8);
        }
    };
    auto write_tiles = [&](int buf) {
        {
            int row = tid >> 2, g = tid & 3;
            int slot = g ^ ((row >> 1) & 3);
            *reinterpret_cast<bf16x8*>(&sm.g.As[buf][row * 32 + slot * 8]) = ra;
        }
        #pragma unroll
        for (int i = 0; i < 2; ++i) {
            int c = tid + i * 512;
            int rn = c >> 2, g = c & 3;
            int slot = g ^ ((rn >> 1) & 3);
            *reinterpret_cast<bf16x8*>(&sm.g.Bs[buf][rn * 32 + slot * 8]) = rb[i];
        }
    };
    auto compute = [&](int buf) {
        bf16x8 a[4], b[4];
        #pragma unroll
        for (int mi = 0; mi < 4; ++mi)
            a[mi] = *reinterpret_cast<const bf16x8*>(&sm.g.As[buf][(wr * 64 + mi * 16 + r15) * 32 + swz * 8]);
        #pragma unroll
        for (int ni = 0; ni < 4; ++ni)
            b[ni] = *reinterpret_cast<const bf16x8*>(&sm.g.Bs[buf][(wc * 64 + ni * 16 + r15) * 32 + swz * 8]);
        #pragma unroll
        for (int mi = 0; mi < 4; ++mi)
            #pragma unroll
            for (int ni = 0; ni < 4; ++ni)
                acc[mi][ni] = __builtin_amdgcn_mfma_f32_16x16x32_bf16(a[mi], b[ni], acc[mi][ni], 0, 0, 0);
    };

    load_tiles(0);
    write_tiles(0);
    __syncthreads();
    int cur = 0;
    #pragma unroll 1
    for (int ks = 0; ks < 8; ++ks) {
        if (ks + 1 < 8) load_tiles((ks + 1) * 32);
        compute(cur);
        if (ks + 1 < 8) write_tiles(cur ^ 1);
        __syncthreads();
        cur ^= 1;
    }
    // after this barrier all gemm1 LDS reads are done -> safe to overwrite with Hs

    // h -> LDS (relu+bias, bf16, swizzled)
    #pragma unroll
    for (int ni = 0; ni < 4; ++ni) {
        int col = wc * 64 + ni * 16 + r15;
        float bias = b1[col];
        int kgrp = col >> 3, within = col & 7;
        #pragma unroll
        for (int mi = 0; mi < 4; ++mi) {
            int rbase = wr * 64 + mi * 16 + (lane >> 4) * 4;
            f32x4 c = acc[mi][ni];
            #pragma unroll
            for (int q = 0; q < 4; ++q) {
                int row = rbase + q;
                float v = fmaxf(c[q] + bias, 0.f);
                sm.Hs[row * 256 + (kgrp ^ (row & 31)) * 8 + within] = f2bf(v);
            }
        }
    }
    __syncthreads();

    // ---- gemm2: A from Hs, B from global Bt2 ----
    const int wr2 = wid >> 1, wc2 = wid & 1;     // 4x2
    f32x4 acc2[2][3];
    #pragma unroll
    for (int i = 0; i < 2; ++i)
        #pragma unroll
        for (int j = 0; j < 3; ++j)
            acc2[i][j] = f32x4{0.f, 0.f, 0.f, 0.f};

    #pragma unroll 1
    for (int kt = 0; kt < 256; kt += 32) {
        bf16x8 a2[2], b2f[3];
        #pragma unroll
        for (int mi = 0; mi < 2; ++mi) {
            int row = wr2 * 32 + mi * 16 + r15;
            int kgrp = (kt >> 3) + (lane >> 4);
            a2[mi] = *reinterpret_cast<const bf16x8*>(&sm.Hs[row * 256 + (kgrp ^ (row & 31)) * 8]);
        }
        #pragma unroll
        for (int ni = 0; ni < 3; ++ni) {
            int n = wc2 * 48 + ni * 16 + r15;
            b2f[ni] = *reinterpret_cast<const bf16x8*>(Bt2 + (size_t)n * 256 + kt + (lane >> 4) * 8);
        }
        #pragma unroll
        for (int mi = 0; mi < 2; ++mi)
            #pragma unroll
            for (int ni = 0; ni < 3; ++ni)
                acc2[mi][ni] = __builtin_amdgcn_mfma_f32_16x16x32_bf16(a2[mi], b2f[ni], acc2[mi][ni], 0, 0, 0);
    }

    #pragma unroll
    for (int ni = 0; ni < 3; ++ni) {
        int col = wc2 * 48 + ni * 16 + r15;      // 0..95
        float bias = (col >= 48 && col < 95) ? b2[col - 48] : 0.f;
        #pragma unroll
        for (int mi = 0; mi < 2; ++mi) {
            int rbase = row0 + wr2 * 32 + mi * 16 + (lane >> 4) * 4;
            f32x4 c = acc2[mi][ni];
            #pragma unroll
            for (int q = 0; q < 4; ++q) {
                int row = rbase + q;
                if (row < NN) {
                    if (col < 47) {
                        int p = __builtin_amdgcn_cvt_pk_fp8_f32(c[q], c[q], 0, false);
                        tq[(size_t)row * 64 + col] = (unsigned char)(p & 0xFF);
                    } else if (col >= 48 && col < 95) {
                        out[(size_t)row * NC + (col - 48)] = c[q] + bias;
                    }
                }
            }
        }
    }
}

// ---------------- launch ----------------

extern "C" void kernel_launch(void* const* d_in, const int* in_sizes, int n_in,
                              void* d_out, int out_size, void* d_ws, size_t ws_size,
                              hipStream_t stream) {
    const float* x    = (const float*)d_in[0];
    const int*   eidx = (const int*)d_in[1];
    const float* Wl1  = (const float*)d_in[2];
    const float* Wr1  = (const float*)d_in[3];
    const float* b1   = (const float*)d_in[4];
    const float* Wl2  = (const float*)d_in[5];
    const float* Wr2  = (const float*)d_in[6];
    const float* b2   = (const float*)d_in[7];
    float* out = (float*)d_out;

    const int* src = eidx;
    const int* dst = eidx + NE;

    size_t off = 0;
    auto alloc = [&](size_t bytes) -> void* {
        void* p = (char*)d_ws + off;
        off += (bytes + 511) & ~(size_t)511;
        return p;
    };
    int*            deg        = (int*)alloc((size_t)NN * 4);
    int*            row_start  = (int*)alloc((size_t)NN * 4);
    float*          inv_deg    = (float*)alloc((size_t)NN * 4);
    int*            csr_src    = (int*)alloc((size_t)NE * 4);
    unsigned*       ebuf       = (unsigned*)alloc((size_t)NE * 4);
    int*            chunk_hist = (int*)alloc((size_t)NCH * NB * 4);
    int*            chunk_off  = (int*)alloc((size_t)NCH * NB * 4);
    int*            bkt_cnt    = (int*)alloc((size_t)NB * 4);
    int*            bkt_base   = (int*)alloc((size_t)NB * 4);
    unsigned short* xb         = (unsigned short*)alloc((size_t)NN * NF * 2);
    unsigned*       xq         = (unsigned*)alloc((size_t)NN * NF);       // fp8 x, 32 words/row
    unsigned short* mean1      = (unsigned short*)alloc((size_t)NN * NF * 2);
    unsigned char*  tq         = (unsigned char*)alloc((size_t)NN * 64);  // fp8 t, 64B rows
    unsigned short* Bt1        = (unsigned short*)alloc((size_t)256 * 256 * 2);
    unsigned short* Bt2        = (unsigned short*)alloc((size_t)96 * 256 * 2);
    (void)ws_size; (void)n_in; (void)in_sizes; (void)out_size;

    hipMemsetAsync(bkt_cnt, 0, (size_t)NB * 4, stream);
    prep_k<<<PB_END, 256, 0, stream>>>(dst, chunk_hist, bkt_cnt,
                                       x, xb, xq, Wl1, Wr1, Bt1, Wl2, Wr2, Bt2);
    scancol_k<<<NB, 64, 0, stream>>>(chunk_hist, bkt_cnt, bkt_base, chunk_off);
    scatter2_k<<<NCH, 256, 0, stream>>>(src, dst, chunk_off, ebuf);
    build_csr_k<<<NB, 256, 0, stream>>>(ebuf, bkt_base, bkt_cnt,
                                        row_start, deg, inv_deg, csr_src);

    agg_mean_128q_k<<<NN / 4, 256, 0, stream>>>(xq, csr_src, row_start, deg, inv_deg, mean1);

    gemm12_k<<<(NN + 127) / 128, 512, 0, stream>>>(mean1, xb, Bt1, b1, Bt2, b2, tq, out);

    agg_mean_47q_add_k<<<NN / 4, 256, 0, stream>>>((const unsigned*)tq, csr_src, row_start, deg, inv_deg, out);
}

// Round 11
// 194.910 us; speedup vs baseline: 4.4421x; 1.1835x over previous
//
#include <hip/hip_runtime.h>

#define NN 100000
#define NE 1600000
#define NF 128
#define NH 256
#define NC 47
#define NB 391            // ceil(NN/256) buckets of 256 nodes
#define CH 8192           // edges per chunk
#define NCH ((NE + CH - 1) / CH)   // 196

// prep_k block-role offsets
#define PB_HIST 0
#define PB_CAST (PB_HIST + NCH)                  // 196
#define NCAST   (NN * NF / 4 / 256)              // 12500
#define PB_BT1  (PB_CAST + NCAST)                // 12696
#define PB_BT2  (PB_BT1 + 256)                   // 12952
#define PB_END  (PB_BT2 + 96)                    // 13048

typedef __attribute__((ext_vector_type(8))) short bf16x8;
typedef __attribute__((ext_vector_type(4))) float f32x4;
typedef __attribute__((ext_vector_type(2))) float f32x2;

typedef __attribute__((address_space(1))) const void as1_void;
typedef __attribute__((address_space(3))) void as3_void;
__device__ __forceinline__ void gload16(const void* g, void* l) {
    __builtin_amdgcn_global_load_lds((as1_void*)g, (as3_void*)l, 16, 0, 0);
}

__device__ inline unsigned short f2bf(float f) {
    unsigned u = __builtin_bit_cast(unsigned, f);
    unsigned r = u + 0x7fffu + ((u >> 16) & 1u);
    return (unsigned short)(r >> 16);
}
__device__ inline float bfl(unsigned u) {
    return __builtin_bit_cast(float, u << 16);
}

// ---------------- fused prep: chunk_hist | cast_x (bf16 + fp8) | prep_bt1 | prep_bt2 ----------------

__global__ __launch_bounds__(256) void prep_k(const int* __restrict__ dst,
                                              int* __restrict__ chunk_hist,
                                              int* __restrict__ total,
                                              const float* __restrict__ x,
                                              unsigned short* __restrict__ xb,
                                              unsigned* __restrict__ xq,
                                              const float* __restrict__ Wl1,
                                              const float* __restrict__ Wr1,
                                              unsigned short* __restrict__ Bt1,
                                              const float* __restrict__ Wl2,
                                              const float* __restrict__ Wr2,
                                              unsigned short* __restrict__ Bt2) {
    __shared__ int h[NB];
    int tid = threadIdx.x;
    int blk = blockIdx.x;
    if (blk < PB_CAST) {                       // chunk histogram
        int ch = blk;
        for (int i = tid; i < NB; i += 256) h[i] = 0;
        __syncthreads();
        int e0 = ch * CH;
        int e1 = min(e0 + CH, NE);
        for (int e = e0 + tid; e < e1; e += 256)
            atomicAdd(&h[dst[e] >> 8], 1);
        __syncthreads();
        for (int i = tid; i < NB; i += 256) {
            int v = h[i];
            chunk_hist[(size_t)ch * NB + i] = v;
            if (v) atomicAdd(&total[i], v);
        }
    } else if (blk < PB_BT1) {                 // cast x -> bf16 + fp8
        int i = (blk - PB_CAST) * 256 + tid;
        float4 v = *reinterpret_cast<const float4*>(x + (size_t)i * 4);
        ushort4 o;
        o.x = f2bf(v.x); o.y = f2bf(v.y); o.z = f2bf(v.z); o.w = f2bf(v.w);
        *reinterpret_cast<ushort4*>(xb + (size_t)i * 4) = o;
        int r = __builtin_amdgcn_cvt_pk_fp8_f32(v.x, v.y, 0, false);
        r = __builtin_amdgcn_cvt_pk_fp8_f32(v.z, v.w, r, true);
        xq[i] = (unsigned)r;
    } else if (blk < PB_BT2) {                 // Bt1[n][k]
        int idx = (blk - PB_BT1) * 256 + tid;
        int n = idx >> 8, k = idx & 255;
        float v = (k < 128) ? Wl1[(size_t)k * NH + n] : Wr1[(size_t)(k - 128) * NH + n];
        Bt1[idx] = f2bf(v);
    } else {                                   // Bt2[n][k]
        int idx = (blk - PB_BT2) * 256 + tid;
        int n = idx >> 8, k = idx & 255;
        float v = 0.f;
        if (n < 47) v = Wl2[(size_t)k * NC + n];
        else if (n >= 48 && n < 95) v = Wr2[(size_t)k * NC + (n - 48)];
        Bt2[idx] = f2bf(v);
    }
}

// ---------------- fused scan + per-bucket column scan ----------------

__global__ __launch_bounds__(64) void scancol_k(const int* __restrict__ chunk_hist,
                                                const int* __restrict__ total,
                                                int* __restrict__ bucket_base,
                                                int* __restrict__ chunk_off) {
    int b = blockIdx.x;
    int lane = threadIdx.x;
    int base = 0;
    for (int i0 = 0; i0 < NB; i0 += 64) {
        int i = i0 + lane;
        base += (i < b) ? total[i] : 0;
    }
    #pragma unroll
    for (int off = 1; off < 64; off <<= 1)
        base += __shfl_xor(base, off);
    if (lane == 0) bucket_base[b] = base;
    int run = base;
    for (int c0 = 0; c0 < NCH; c0 += 64) {
        int c = c0 + lane;
        int v = (c < NCH) ? chunk_hist[(size_t)c * NB + b] : 0;
        int s = v;
        #pragma unroll
        for (int off = 1; off < 64; off <<= 1) {
            int t = __shfl_up(s, off);
            if (lane >= off) s += t;
        }
        if (c < NCH) chunk_off[(size_t)c * NB + b] = run + s - v;
        run += __shfl(s, 63);
    }
}

__global__ __launch_bounds__(256) void scatter2_k(const int* __restrict__ src,
                                                  const int* __restrict__ dst,
                                                  const int* __restrict__ chunk_off,
                                                  unsigned* __restrict__ ebuf) {
    __shared__ int cur[NB];
    int tid = threadIdx.x, ch = blockIdx.x;
    for (int i = tid; i < NB; i += 256)
        cur[i] = chunk_off[(size_t)ch * NB + i];
    __syncthreads();
    int e0 = ch * CH;
    int e1 = min(e0 + CH, NE);
    for (int e = e0 + tid; e < e1; e += 256) {
        int d = dst[e];
        int b = d >> 8;
        int p = atomicAdd(&cur[b], 1);
        ebuf[p] = ((unsigned)(d & 255) << 24) | (unsigned)src[e];
    }
}

__global__ __launch_bounds__(256) void build_csr_k(const unsigned* __restrict__ ebuf,
                                                   const int* __restrict__ bucket_base,
                                                   const int* __restrict__ bucket_cnt,
                                                   int* __restrict__ row_start,
                                                   int* __restrict__ deg,
                                                   float* __restrict__ inv_deg,
                                                   int* __restrict__ csr_src) {
    __shared__ int s[256];
    __shared__ int cursor[256];
    int tid = threadIdx.x;
    int b = blockIdx.x;
    int lo = b << 8;
    int ebase = bucket_base[b];
    int ne = bucket_cnt[b];

    s[tid] = 0;
    __syncthreads();
    for (int e = tid; e < ne; e += 256)
        atomicAdd(&s[ebuf[ebase + e] >> 24], 1);
    __syncthreads();
    int v = s[tid];
    __syncthreads();
    for (int off = 1; off < 256; off <<= 1) {
        int t = (tid >= off) ? s[tid - off] : 0;
        __syncthreads();
        s[tid] += t;
        __syncthreads();
    }
    int excl = s[tid] - v;
    int node = lo + tid;
    if (node < NN) {
        row_start[node] = ebase + excl;
        deg[node] = v;
        inv_deg[node] = 1.0f / (float)(v > 1 ? v : 1);
    }
    cursor[tid] = ebase + excl;
    __syncthreads();
    for (int e = tid; e < ne; e += 256) {
        unsigned u = ebuf[ebase + e];
        int p = atomicAdd(&cursor[u >> 24], 1);
        csr_src[p] = (int)(u & 0xFFFFFFu);
    }
}

// ---------------- aggregation: node per 16-lane group, 4 rows in flight per group ----------------

// fp8 x-gather: row = 128B = 16 lanes x uint2.
__global__ __launch_bounds__(256) void agg_mean_128q_k(const unsigned* __restrict__ xq,
                                                       const int* __restrict__ csr_src,
                                                       const int* __restrict__ row_start,
                                                       const int* __restrict__ deg,
                                                       const float* __restrict__ inv_deg,
                                                       unsigned short* __restrict__ mean1) {
    int node = blockIdx.x * 16 + (threadIdx.x >> 4);
    int l16 = threadIdx.x & 15;
    if (node >= NN) return;
    int s0 = row_start[node];
    int d  = deg[node];
    f32x2 acc[4];
    #pragma unroll
    for (int k = 0; k < 4; ++k) acc[k] = f32x2{0.f, 0.f};
    int j = 0;
    for (; j + 3 < d; j += 4) {
        int sA = csr_src[s0 + j];
        int sB = csr_src[s0 + j + 1];
        int sC = csr_src[s0 + j + 2];
        int sD = csr_src[s0 + j + 3];
        uint2 wA = *reinterpret_cast<const uint2*>(xq + (size_t)sA * 32 + l16 * 2);
        uint2 wB = *reinterpret_cast<const uint2*>(xq + (size_t)sB * 32 + l16 * 2);
        uint2 wC = *reinterpret_cast<const uint2*>(xq + (size_t)sC * 32 + l16 * 2);
        uint2 wD = *reinterpret_cast<const uint2*>(xq + (size_t)sD * 32 + l16 * 2);
        acc[0] += __builtin_amdgcn_cvt_pk_f32_fp8((int)wA.x, false);
        acc[1] += __builtin_amdgcn_cvt_pk_f32_fp8((int)wA.x, true);
        acc[2] += __builtin_amdgcn_cvt_pk_f32_fp8((int)wA.y, false);
        acc[3] += __builtin_amdgcn_cvt_pk_f32_fp8((int)wA.y, true);
        acc[0] += __builtin_amdgcn_cvt_pk_f32_fp8((int)wB.x, false);
        acc[1] += __builtin_amdgcn_cvt_pk_f32_fp8((int)wB.x, true);
        acc[2] += __builtin_amdgcn_cvt_pk_f32_fp8((int)wB.y, false);
        acc[3] += __builtin_amdgcn_cvt_pk_f32_fp8((int)wB.y, true);
        acc[0] += __builtin_amdgcn_cvt_pk_f32_fp8((int)wC.x, false);
        acc[1] += __builtin_amdgcn_cvt_pk_f32_fp8((int)wC.x, true);
        acc[2] += __builtin_amdgcn_cvt_pk_f32_fp8((int)wC.y, false);
        acc[3] += __builtin_amdgcn_cvt_pk_f32_fp8((int)wC.y, true);
        acc[0] += __builtin_amdgcn_cvt_pk_f32_fp8((int)wD.x, false);
        acc[1] += __builtin_amdgcn_cvt_pk_f32_fp8((int)wD.x, true);
        acc[2] += __builtin_amdgcn_cvt_pk_f32_fp8((int)wD.y, false);
        acc[3] += __builtin_amdgcn_cvt_pk_f32_fp8((int)wD.y, true);
    }
    for (; j < d; ++j) {
        int s = csr_src[s0 + j];
        uint2 w = *reinterpret_cast<const uint2*>(xq + (size_t)s * 32 + l16 * 2);
        acc[0] += __builtin_amdgcn_cvt_pk_f32_fp8((int)w.x, false);
        acc[1] += __builtin_amdgcn_cvt_pk_f32_fp8((int)w.x, true);
        acc[2] += __builtin_amdgcn_cvt_pk_f32_fp8((int)w.y, false);
        acc[3] += __builtin_amdgcn_cvt_pk_f32_fp8((int)w.y, true);
    }
    float inv = inv_deg[node];
    bf16x8 o;
    #pragma unroll
    for (int k = 0; k < 4; ++k) {
        o[k * 2]     = (short)f2bf(acc[k].x * inv);
        o[k * 2 + 1] = (short)f2bf(acc[k].y * inv);
    }
    *reinterpret_cast<bf16x8*>(mean1 + (size_t)node * NF + l16 * 8) = o;
}

// fp8 t-gather: row = 64B = 16 lanes x dword.
__global__ __launch_bounds__(256) void agg_mean_47q_add_k(const unsigned* __restrict__ tq,
                                                          const int* __restrict__ csr_src,
                                                          const int* __restrict__ row_start,
                                                          const int* __restrict__ deg,
                                                          const float* __restrict__ inv_deg,
                                                          float* __restrict__ out) {
    int node = blockIdx.x * 16 + (threadIdx.x >> 4);
    int l16 = threadIdx.x & 15;
    if (node >= NN) return;
    int s0 = row_start[node];
    int d  = deg[node];
    f32x2 a01 = {0.f, 0.f}, a23 = {0.f, 0.f};
    int j = 0;
    for (; j + 3 < d; j += 4) {
        int sA = csr_src[s0 + j];
        int sB = csr_src[s0 + j + 1];
        int sC = csr_src[s0 + j + 2];
        int sD = csr_src[s0 + j + 3];
        unsigned wA = tq[(size_t)sA * 16 + l16];
        unsigned wB = tq[(size_t)sB * 16 + l16];
        unsigned wC = tq[(size_t)sC * 16 + l16];
        unsigned wD = tq[(size_t)sD * 16 + l16];
        a01 += __builtin_amdgcn_cvt_pk_f32_fp8((int)wA, false);
        a23 += __builtin_amdgcn_cvt_pk_f32_fp8((int)wA, true);
        a01 += __builtin_amdgcn_cvt_pk_f32_fp8((int)wB, false);
        a23 += __builtin_amdgcn_cvt_pk_f32_fp8((int)wB, true);
        a01 += __builtin_amdgcn_cvt_pk_f32_fp8((int)wC, false);
        a23 += __builtin_amdgcn_cvt_pk_f32_fp8((int)wC, true);
        a01 += __builtin_amdgcn_cvt_pk_f32_fp8((int)wD, false);
        a23 += __builtin_amdgcn_cvt_pk_f32_fp8((int)wD, true);
    }
    for (; j < d; ++j) {
        int s = csr_src[s0 + j];
        unsigned w = tq[(size_t)s * 16 + l16];
        a01 += __builtin_amdgcn_cvt_pk_f32_fp8((int)w, false);
        a23 += __builtin_amdgcn_cvt_pk_f32_fp8((int)w, true);
    }
    float inv = inv_deg[node];
    int c0 = l16 * 4;
    float vals[4] = {a01.x, a01.y, a23.x, a23.y};
    #pragma unroll
    for (int m = 0; m < 4; ++m) {
        int col = c0 + m;
        if (col < NC) {
            size_t o = (size_t)node * NC + col;
            out[o] += vals[m] * inv;
        }
    }
}

// ---------------- fused GEMM12 (LDS union, global_load_lds staging) ----------------
// 512 thr (8 waves). gemm1: waves 2x4 (64x64 each), BM=128, BN=256, BK=32.
// Staging via global_load_lds w16; LDS linear dest, XOR-swizzle applied on the
// per-lane GLOBAL source (m173 pattern); read side unchanged (same involution).
// LDS = max(As+Bs = 48 KB, Hs = 64 KB) = 64 KB -> 2 blocks/CU.

__global__ __launch_bounds__(512) void gemm12_k(const unsigned short* __restrict__ mean1,
                                                const unsigned short* __restrict__ xb,
                                                const unsigned short* __restrict__ Bt1,
                                                const float* __restrict__ b1,
                                                const unsigned short* __restrict__ Bt2,
                                                const float* __restrict__ b2,
                                                unsigned char* __restrict__ tq,
                                                float* __restrict__ out) {
    __shared__ __align__(16) union SM {
        struct { short As[2][128 * 32]; short Bs[2][256 * 32]; } g;   // 48 KB, gemm1 only
        unsigned short Hs[128 * 256];                                  // 64 KB, after gemm1
    } sm;
    const int tid = threadIdx.x;
    const int row0 = blockIdx.x * 128;
    const int lane = tid & 63;
    const int wid = tid >> 6;                    // 0..7
    const int r15 = lane & 15;
    const int swz = ((lane >> 4) ^ ((lane >> 1) & 3)) & 3;

    // ---- gemm1 ----
    const int wr = wid >> 2, wc = wid & 3;       // 2x4
    f32x4 acc[4][4];
    #pragma unroll
    for (int i = 0; i < 4; ++i)
        #pragma unroll
        for (int j = 0; j < 4; ++j)
            acc[i][j] = f32x4{0.f, 0.f, 0.f, 0.f};

    auto stage = [&](int buf, int kt) {
        {   // A: thread -> row=tid>>2, g=tid&3; LDS linear at tid*16B; source group swizzled
            int row = tid >> 2, g = tid & 3;
            int grow = row0 + row;
            int gs = g ^ ((row >> 1) & 3);
            const unsigned short* asrc = (kt < 128) ? mean1 : xb;
            const void* gp = asrc + (size_t)grow * NF + (kt & 127) + gs * 8;
            void* lp = &sm.g.As[buf][tid * 8];
            if (grow < NN) gload16(gp, lp);       // masked rows: stale LDS, outputs guarded
        }
        #pragma unroll
        for (int i = 0; i < 2; ++i) {             // B: 256 rows x 4 groups
            int c = tid + i * 512;
            int rn = c >> 2, g = c & 3;
            int gs = g ^ ((rn >> 1) & 3);
            const void* gp = Bt1 + (size_t)rn * 256 + kt + gs * 8;
            void* lp = &sm.g.Bs[buf][c * 8];
            gload16(gp, lp);
        }
    };
    auto compute = [&](int buf) {
        bf16x8 a[4], b[4];
        #pragma unroll
        for (int mi = 0; mi < 4; ++mi)
            a[mi] = *reinterpret_cast<const bf16x8*>(&sm.g.As[buf][(wr * 64 + mi * 16 + r15) * 32 + swz * 8]);
        #pragma unroll
        for (int ni = 0; ni < 4; ++ni)
            b[ni] = *reinterpret_cast<const bf16x8*>(&sm.g.Bs[buf][(wc * 64 + ni * 16 + r15) * 32 + swz * 8]);
        #pragma unroll
        for (int mi = 0; mi < 4; ++mi)
            #pragma unroll
            for (int ni = 0; ni < 4; ++ni)
                acc[mi][ni] = __builtin_amdgcn_mfma_f32_16x16x32_bf16(a[mi], b[ni], acc[mi][ni], 0, 0, 0);
    };

    stage(0, 0);
    __syncthreads();
    int cur = 0;
    #pragma unroll 1
    for (int ks = 0; ks < 8; ++ks) {
        if (ks + 1 < 8) stage(cur ^ 1, (ks + 1) * 32);
        compute(cur);
        __syncthreads();
        cur ^= 1;
    }
    // after this barrier all gemm1 LDS reads are done -> safe to overwrite with Hs

    // h -> LDS (relu+bias, bf16, swizzled)
    #pragma unroll
    for (int ni = 0; ni < 4; ++ni) {
        int col = wc * 64 + ni * 16 + r15;
        float bias = b1[col];
        int kgrp = col >> 3, within = col & 7;
        #pragma unroll
        for (int mi = 0; mi < 4; ++mi) {
            int rbase = wr * 64 + mi * 16 + (lane >> 4) * 4;
            f32x4 c = acc[mi][ni];
            #pragma unroll
            for (int q = 0; q < 4; ++q) {
                int row = rbase + q;
                float v = fmaxf(c[q] + bias, 0.f);
                sm.Hs[row * 256 + (kgrp ^ (row & 31)) * 8 + within] = f2bf(v);
            }
        }
    }
    __syncthreads();

    // ---- gemm2: A from Hs, B from global Bt2 ----
    const int wr2 = wid >> 1, wc2 = wid & 1;     // 4x2
    f32x4 acc2[2][3];
    #pragma unroll
    for (int i = 0; i < 2; ++i)
        #pragma unroll
        for (int j = 0; j < 3; ++j)
            acc2[i][j] = f32x4{0.f, 0.f, 0.f, 0.f};

    #pragma unroll 1
    for (int kt = 0; kt < 256; kt += 32) {
        bf16x8 a2[2], b2f[3];
        #pragma unroll
        for (int mi = 0; mi < 2; ++mi) {
            int row = wr2 * 32 + mi * 16 + r15;
            int kgrp = (kt >> 3) + (lane >> 4);
            a2[mi] = *reinterpret_cast<const bf16x8*>(&sm.Hs[row * 256 + (kgrp ^ (row & 31)) * 8]);
        }
        #pragma unroll
        for (int ni = 0; ni < 3; ++ni) {
            int n = wc2 * 48 + ni * 16 + r15;
            b2f[ni] = *reinterpret_cast<const bf16x8*>(Bt2 + (size_t)n * 256 + kt + (lane >> 4) * 8);
        }
        #pragma unroll
        for (int mi = 0; mi < 2; ++mi)
            #pragma unroll
            for (int ni = 0; ni < 3; ++ni)
                acc2[mi][ni] = __builtin_amdgcn_mfma_f32_16x16x32_bf16(a2[mi], b2f[ni], acc2[mi][ni], 0, 0, 0);
    }

    #pragma unroll
    for (int ni = 0; ni < 3; ++ni) {
        int col = wc2 * 48 + ni * 16 + r15;      // 0..95
        float bias = (col >= 48 && col < 95) ? b2[col - 48] : 0.f;
        #pragma unroll
        for (int mi = 0; mi < 2; ++mi) {
            int rbase = row0 + wr2 * 32 + mi * 16 + (lane >> 4) * 4;
            f32x4 c = acc2[mi][ni];
            #pragma unroll
            for (int q = 0; q < 4; ++q) {
                int row = rbase + q;
                if (row < NN) {
                    if (col < 47) {
                        int p = __builtin_amdgcn_cvt_pk_fp8_f32(c[q], c[q], 0, false);
                        tq[(size_t)row * 64 + col] = (unsigned char)(p & 0xFF);
                    } else if (col >= 48 && col < 95) {
                        out[(size_t)row * NC + (col - 48)] = c[q] + bias;
                    }
                }
            }
        }
    }
}

// ---------------- launch ----------------

extern "C" void kernel_launch(void* const* d_in, const int* in_sizes, int n_in,
                              void* d_out, int out_size, void* d_ws, size_t ws_size,
                              hipStream_t stream) {
    const float* x    = (const float*)d_in[0];
    const int*   eidx = (const int*)d_in[1];
    const float* Wl1  = (const float*)d_in[2];
    const float* Wr1  = (const float*)d_in[3];
    const float* b1   = (const float*)d_in[4];
    const float* Wl2  = (const float*)d_in[5];
    const float* Wr2  = (const float*)d_in[6];
    const float* b2   = (const float*)d_in[7];
    float* out = (float*)d_out;

    const int* src = eidx;
    const int* dst = eidx + NE;

    size_t off = 0;
    auto alloc = [&](size_t bytes) -> void* {
        void* p = (char*)d_ws + off;
        off += (bytes + 511) & ~(size_t)511;
        return p;
    };
    int*            deg        = (int*)alloc((size_t)NN * 4);
    int*            row_start  = (int*)alloc((size_t)NN * 4);
    float*          inv_deg    = (float*)alloc((size_t)NN * 4);
    int*            csr_src    = (int*)alloc((size_t)NE * 4);
    unsigned*       ebuf       = (unsigned*)alloc((size_t)NE * 4);
    int*            chunk_hist = (int*)alloc((size_t)NCH * NB * 4);
    int*            chunk_off  = (int*)alloc((size_t)NCH * NB * 4);
    int*            bkt_cnt    = (int*)alloc((size_t)NB * 4);
    int*            bkt_base   = (int*)alloc((size_t)NB * 4);
    unsigned short* xb         = (unsigned short*)alloc((size_t)NN * NF * 2);
    unsigned*       xq         = (unsigned*)alloc((size_t)NN * NF);       // fp8 x, 32 words/row
    unsigned short* mean1      = (unsigned short*)alloc((size_t)NN * NF * 2);
    unsigned char*  tq         = (unsigned char*)alloc((size_t)NN * 64);  // fp8 t, 64B rows
    unsigned short* Bt1        = (unsigned short*)alloc((size_t)256 * 256 * 2);
    unsigned short* Bt2        = (unsigned short*)alloc((size_t)96 * 256 * 2);
    (void)ws_size; (void)n_in; (void)in_sizes; (void)out_size;

    hipMemsetAsync(bkt_cnt, 0, (size_t)NB * 4, stream);
    prep_k<<<PB_END, 256, 0, stream>>>(dst, chunk_hist, bkt_cnt,
                                       x, xb, xq, Wl1, Wr1, Bt1, Wl2, Wr2, Bt2);
    scancol_k<<<NB, 64, 0, stream>>>(chunk_hist, bkt_cnt, bkt_base, chunk_off);
    scatter2_k<<<NCH, 256, 0, stream>>>(src, dst, chunk_off, ebuf);
    build_csr_k<<<NB, 256, 0, stream>>>(ebuf, bkt_base, bkt_cnt,
                                        row_start, deg, inv_deg, csr_src);

    agg_mean_128q_k<<<(NN + 15) / 16, 256, 0, stream>>>(xq, csr_src, row_start, deg, inv_deg, mean1);

    gemm12_k<<<(NN + 127) / 128, 512, 0, stream>>>(mean1, xb, Bt1, b1, Bt2, b2, tq, out);

    agg_mean_47q_add_k<<<(NN + 15) / 16, 256, 0, stream>>>((const unsigned*)tq, csr_src, row_start, deg, inv_deg, out);
}

// Round 12
// 192.867 us; speedup vs baseline: 4.4892x; 1.0106x over previous
//
#include <hip/hip_runtime.h>

#define NN 100000
#define NE 1600000
#define NF 128
#define NH 256
#define NC 47
#define NB 391            // ceil(NN/256) buckets of 256 nodes
#define CH 8192           // edges per chunk
#define NCH ((NE + CH - 1) / CH)   // 196

// prep_k block-role offsets
#define PB_HIST 0
#define PB_CAST (PB_HIST + NCH)                  // 196
#define NCAST   (NN * NF / 4 / 256)              // 12500
#define PB_BT1  (PB_CAST + NCAST)                // 12696
#define PB_BT2  (PB_BT1 + 256)                   // 12952
#define PB_END  (PB_BT2 + 96)                    // 13048

typedef __attribute__((ext_vector_type(8))) short bf16x8;
typedef __attribute__((ext_vector_type(4))) float f32x4;
typedef __attribute__((ext_vector_type(2))) float f32x2;

typedef __attribute__((address_space(1))) const void as1_void;
typedef __attribute__((address_space(3))) void as3_void;
__device__ __forceinline__ void gload16(const void* g, void* l) {
    __builtin_amdgcn_global_load_lds((as1_void*)g, (as3_void*)l, 16, 0, 0);
}

__device__ inline unsigned short f2bf(float f) {
    unsigned u = __builtin_bit_cast(unsigned, f);
    unsigned r = u + 0x7fffu + ((u >> 16) & 1u);
    return (unsigned short)(r >> 16);
}
__device__ inline float bfl(unsigned u) {
    return __builtin_bit_cast(float, u << 16);
}

// ---------------- fused prep: chunk_hist | cast_x (bf16 + fp8) | prep_bt1 | prep_bt2 ----------------

__global__ __launch_bounds__(256) void prep_k(const int* __restrict__ dst,
                                              int* __restrict__ chunk_hist,
                                              int* __restrict__ total,
                                              const float* __restrict__ x,
                                              unsigned short* __restrict__ xb,
                                              unsigned* __restrict__ xq,
                                              const float* __restrict__ Wl1,
                                              const float* __restrict__ Wr1,
                                              unsigned short* __restrict__ Bt1,
                                              const float* __restrict__ Wl2,
                                              const float* __restrict__ Wr2,
                                              unsigned short* __restrict__ Bt2) {
    __shared__ int h[NB];
    int tid = threadIdx.x;
    int blk = blockIdx.x;
    if (blk < PB_CAST) {                       // chunk histogram
        int ch = blk;
        for (int i = tid; i < NB; i += 256) h[i] = 0;
        __syncthreads();
        int e0 = ch * CH;
        int e1 = min(e0 + CH, NE);
        for (int e = e0 + tid; e < e1; e += 256)
            atomicAdd(&h[dst[e] >> 8], 1);
        __syncthreads();
        for (int i = tid; i < NB; i += 256) {
            int v = h[i];
            chunk_hist[(size_t)ch * NB + i] = v;
            if (v) atomicAdd(&total[i], v);
        }
    } else if (blk < PB_BT1) {                 // cast x -> bf16 + fp8
        int i = (blk - PB_CAST) * 256 + tid;
        float4 v = *reinterpret_cast<const float4*>(x + (size_t)i * 4);
        ushort4 o;
        o.x = f2bf(v.x); o.y = f2bf(v.y); o.z = f2bf(v.z); o.w = f2bf(v.w);
        *reinterpret_cast<ushort4*>(xb + (size_t)i * 4) = o;
        int r = __builtin_amdgcn_cvt_pk_fp8_f32(v.x, v.y, 0, false);
        r = __builtin_amdgcn_cvt_pk_fp8_f32(v.z, v.w, r, true);
        xq[i] = (unsigned)r;
    } else if (blk < PB_BT2) {                 // Bt1[n][k]
        int idx = (blk - PB_BT1) * 256 + tid;
        int n = idx >> 8, k = idx & 255;
        float v = (k < 128) ? Wl1[(size_t)k * NH + n] : Wr1[(size_t)(k - 128) * NH + n];
        Bt1[idx] = f2bf(v);
    } else {                                   // Bt2[n][k]
        int idx = (blk - PB_BT2) * 256 + tid;
        int n = idx >> 8, k = idx & 255;
        float v = 0.f;
        if (n < 47) v = Wl2[(size_t)k * NC + n];
        else if (n >= 48 && n < 95) v = Wr2[(size_t)k * NC + (n - 48)];
        Bt2[idx] = f2bf(v);
    }
}

// ---------------- fused scan + per-bucket column scan ----------------

__global__ __launch_bounds__(64) void scancol_k(const int* __restrict__ chunk_hist,
                                                const int* __restrict__ total,
                                                int* __restrict__ bucket_base,
                                                int* __restrict__ chunk_off) {
    int b = blockIdx.x;
    int lane = threadIdx.x;
    int base = 0;
    for (int i0 = 0; i0 < NB; i0 += 64) {
        int i = i0 + lane;
        base += (i < b) ? total[i] : 0;
    }
    #pragma unroll
    for (int off = 1; off < 64; off <<= 1)
        base += __shfl_xor(base, off);
    if (lane == 0) bucket_base[b] = base;
    int run = base;
    for (int c0 = 0; c0 < NCH; c0 += 64) {
        int c = c0 + lane;
        int v = (c < NCH) ? chunk_hist[(size_t)c * NB + b] : 0;
        int s = v;
        #pragma unroll
        for (int off = 1; off < 64; off <<= 1) {
            int t = __shfl_up(s, off);
            if (lane >= off) s += t;
        }
        if (c < NCH) chunk_off[(size_t)c * NB + b] = run + s - v;
        run += __shfl(s, 63);
    }
}

__global__ __launch_bounds__(256) void scatter2_k(const int* __restrict__ src,
                                                  const int* __restrict__ dst,
                                                  const int* __restrict__ chunk_off,
                                                  unsigned* __restrict__ ebuf) {
    __shared__ int cur[NB];
    int tid = threadIdx.x, ch = blockIdx.x;
    for (int i = tid; i < NB; i += 256)
        cur[i] = chunk_off[(size_t)ch * NB + i];
    __syncthreads();
    int e0 = ch * CH;
    int e1 = min(e0 + CH, NE);
    for (int e = e0 + tid; e < e1; e += 256) {
        int d = dst[e];
        int b = d >> 8;
        int p = atomicAdd(&cur[b], 1);
        ebuf[p] = ((unsigned)(d & 255) << 24) | (unsigned)src[e];
    }
}

__global__ __launch_bounds__(256) void build_csr_k(const unsigned* __restrict__ ebuf,
                                                   const int* __restrict__ bucket_base,
                                                   const int* __restrict__ bucket_cnt,
                                                   int* __restrict__ row_start,
                                                   int* __restrict__ deg,
                                                   float* __restrict__ inv_deg,
                                                   int* __restrict__ csr_src) {
    __shared__ int s[256];
    __shared__ int cursor[256];
    int tid = threadIdx.x;
    int b = blockIdx.x;
    int lo = b << 8;
    int ebase = bucket_base[b];
    int ne = bucket_cnt[b];

    s[tid] = 0;
    __syncthreads();
    for (int e = tid; e < ne; e += 256)
        atomicAdd(&s[ebuf[ebase + e] >> 24], 1);
    __syncthreads();
    int v = s[tid];
    __syncthreads();
    for (int off = 1; off < 256; off <<= 1) {
        int t = (tid >= off) ? s[tid - off] : 0;
        __syncthreads();
        s[tid] += t;
        __syncthreads();
    }
    int excl = s[tid] - v;
    int node = lo + tid;
    if (node < NN) {
        row_start[node] = ebase + excl;
        deg[node] = v;
        inv_deg[node] = 1.0f / (float)(v > 1 ? v : 1);
    }
    cursor[tid] = ebase + excl;
    __syncthreads();
    for (int e = tid; e < ne; e += 256) {
        unsigned u = ebuf[ebase + e];
        int p = atomicAdd(&cursor[u >> 24], 1);
        csr_src[p] = (int)(u & 0xFFFFFFu);
    }
}

// ---------------- aggregation: node per 16-lane group, 4 rows in flight per group ----------------

// fp8 x-gather: row = 128B = 16 lanes x uint2.
__global__ __launch_bounds__(256) void agg_mean_128q_k(const unsigned* __restrict__ xq,
                                                       const int* __restrict__ csr_src,
                                                       const int* __restrict__ row_start,
                                                       const int* __restrict__ deg,
                                                       const float* __restrict__ inv_deg,
                                                       unsigned short* __restrict__ mean1) {
    int node = blockIdx.x * 16 + (threadIdx.x >> 4);
    int l16 = threadIdx.x & 15;
    if (node >= NN) return;
    int s0 = row_start[node];
    int d  = deg[node];
    f32x2 acc[4];
    #pragma unroll
    for (int k = 0; k < 4; ++k) acc[k] = f32x2{0.f, 0.f};
    int j = 0;
    for (; j + 3 < d; j += 4) {
        int sA = csr_src[s0 + j];
        int sB = csr_src[s0 + j + 1];
        int sC = csr_src[s0 + j + 2];
        int sD = csr_src[s0 + j + 3];
        uint2 wA = *reinterpret_cast<const uint2*>(xq + (size_t)sA * 32 + l16 * 2);
        uint2 wB = *reinterpret_cast<const uint2*>(xq + (size_t)sB * 32 + l16 * 2);
        uint2 wC = *reinterpret_cast<const uint2*>(xq + (size_t)sC * 32 + l16 * 2);
        uint2 wD = *reinterpret_cast<const uint2*>(xq + (size_t)sD * 32 + l16 * 2);
        acc[0] += __builtin_amdgcn_cvt_pk_f32_fp8((int)wA.x, false);
        acc[1] += __builtin_amdgcn_cvt_pk_f32_fp8((int)wA.x, true);
        acc[2] += __builtin_amdgcn_cvt_pk_f32_fp8((int)wA.y, false);
        acc[3] += __builtin_amdgcn_cvt_pk_f32_fp8((int)wA.y, true);
        acc[0] += __builtin_amdgcn_cvt_pk_f32_fp8((int)wB.x, false);
        acc[1] += __builtin_amdgcn_cvt_pk_f32_fp8((int)wB.x, true);
        acc[2] += __builtin_amdgcn_cvt_pk_f32_fp8((int)wB.y, false);
        acc[3] += __builtin_amdgcn_cvt_pk_f32_fp8((int)wB.y, true);
        acc[0] += __builtin_amdgcn_cvt_pk_f32_fp8((int)wC.x, false);
        acc[1] += __builtin_amdgcn_cvt_pk_f32_fp8((int)wC.x, true);
        acc[2] += __builtin_amdgcn_cvt_pk_f32_fp8((int)wC.y, false);
        acc[3] += __builtin_amdgcn_cvt_pk_f32_fp8((int)wC.y, true);
        acc[0] += __builtin_amdgcn_cvt_pk_f32_fp8((int)wD.x, false);
        acc[1] += __builtin_amdgcn_cvt_pk_f32_fp8((int)wD.x, true);
        acc[2] += __builtin_amdgcn_cvt_pk_f32_fp8((int)wD.y, false);
        acc[3] += __builtin_amdgcn_cvt_pk_f32_fp8((int)wD.y, true);
    }
    for (; j < d; ++j) {
        int s = csr_src[s0 + j];
        uint2 w = *reinterpret_cast<const uint2*>(xq + (size_t)s * 32 + l16 * 2);
        acc[0] += __builtin_amdgcn_cvt_pk_f32_fp8((int)w.x, false);
        acc[1] += __builtin_amdgcn_cvt_pk_f32_fp8((int)w.x, true);
        acc[2] += __builtin_amdgcn_cvt_pk_f32_fp8((int)w.y, false);
        acc[3] += __builtin_amdgcn_cvt_pk_f32_fp8((int)w.y, true);
    }
    float inv = inv_deg[node];
    bf16x8 o;
    #pragma unroll
    for (int k = 0; k < 4; ++k) {
        o[k * 2]     = (short)f2bf(acc[k].x * inv);
        o[k * 2 + 1] = (short)f2bf(acc[k].y * inv);
    }
    *reinterpret_cast<bf16x8*>(mean1 + (size_t)node * NF + l16 * 8) = o;
}

// fp8 t-gather: row = 64B = 16 lanes x dword.
__global__ __launch_bounds__(256) void agg_mean_47q_add_k(const unsigned* __restrict__ tq,
                                                          const int* __restrict__ csr_src,
                                                          const int* __restrict__ row_start,
                                                          const int* __restrict__ deg,
                                                          const float* __restrict__ inv_deg,
                                                          float* __restrict__ out) {
    int node = blockIdx.x * 16 + (threadIdx.x >> 4);
    int l16 = threadIdx.x & 15;
    if (node >= NN) return;
    int s0 = row_start[node];
    int d  = deg[node];
    f32x2 a01 = {0.f, 0.f}, a23 = {0.f, 0.f};
    int j = 0;
    for (; j + 3 < d; j += 4) {
        int sA = csr_src[s0 + j];
        int sB = csr_src[s0 + j + 1];
        int sC = csr_src[s0 + j + 2];
        int sD = csr_src[s0 + j + 3];
        unsigned wA = tq[(size_t)sA * 16 + l16];
        unsigned wB = tq[(size_t)sB * 16 + l16];
        unsigned wC = tq[(size_t)sC * 16 + l16];
        unsigned wD = tq[(size_t)sD * 16 + l16];
        a01 += __builtin_amdgcn_cvt_pk_f32_fp8((int)wA, false);
        a23 += __builtin_amdgcn_cvt_pk_f32_fp8((int)wA, true);
        a01 += __builtin_amdgcn_cvt_pk_f32_fp8((int)wB, false);
        a23 += __builtin_amdgcn_cvt_pk_f32_fp8((int)wB, true);
        a01 += __builtin_amdgcn_cvt_pk_f32_fp8((int)wC, false);
        a23 += __builtin_amdgcn_cvt_pk_f32_fp8((int)wC, true);
        a01 += __builtin_amdgcn_cvt_pk_f32_fp8((int)wD, false);
        a23 += __builtin_amdgcn_cvt_pk_f32_fp8((int)wD, true);
    }
    for (; j < d; ++j) {
        int s = csr_src[s0 + j];
        unsigned w = tq[(size_t)s * 16 + l16];
        a01 += __builtin_amdgcn_cvt_pk_f32_fp8((int)w, false);
        a23 += __builtin_amdgcn_cvt_pk_f32_fp8((int)w, true);
    }
    float inv = inv_deg[node];
    int c0 = l16 * 4;
    float vals[4] = {a01.x, a01.y, a23.x, a23.y};
    #pragma unroll
    for (int m = 0; m < 4; ++m) {
        int col = c0 + m;
        if (col < NC) {
            size_t o = (size_t)node * NC + col;
            out[o] += vals[m] * inv;
        }
    }
}

// ---------------- fused GEMM12 (3-buffer counted-vmcnt pipeline) ----------------
// 512 thr (8 waves). gemm1: waves 2x4 (64x64 each), BM=128, BN=256, BK=32.
// Staging via global_load_lds w16 (3 loads/thread/stage, unconditional via clamp).
// K-loop: wait vmcnt(3) -> raw barrier -> stage(k+2) -> compute(k). Never drains
// to 0 mid-loop. LDS = max(As*3+Bs*3 = 72 KB, Hs 64 KB) = 72 KB -> 2 blocks/CU.

__global__ __launch_bounds__(512) void gemm12_k(const unsigned short* __restrict__ mean1,
                                                const unsigned short* __restrict__ xb,
                                                const unsigned short* __restrict__ Bt1,
                                                const float* __restrict__ b1,
                                                const unsigned short* __restrict__ Bt2,
                                                const float* __restrict__ b2,
                                                unsigned char* __restrict__ tq,
                                                float* __restrict__ out) {
    __shared__ __align__(16) union SM {
        struct { short As[3][128 * 32]; short Bs[3][256 * 32]; } g;   // 72 KB, gemm1 only
        unsigned short Hs[128 * 256];                                  // 64 KB, after gemm1
    } sm;
    const int tid = threadIdx.x;
    const int row0 = blockIdx.x * 128;
    const int lane = tid & 63;
    const int wid = tid >> 6;                    // 0..7
    const int r15 = lane & 15;
    const int swz = ((lane >> 4) ^ ((lane >> 1) & 3)) & 3;

    // ---- gemm1 ----
    const int wr = wid >> 2, wc = wid & 3;       // 2x4
    f32x4 acc[4][4];
    #pragma unroll
    for (int i = 0; i < 4; ++i)
        #pragma unroll
        for (int j = 0; j < 4; ++j)
            acc[i][j] = f32x4{0.f, 0.f, 0.f, 0.f};

    auto stage = [&](int buf, int kt) {
        {   // A: row=tid>>2, g=tid&3; LDS linear; source group swizzled; clamped row
            int row = tid >> 2, g = tid & 3;
            int grow = row0 + row;
            if (grow >= NN) grow = NN - 1;       // unconditional load (vmcnt count exact)
            int gs = g ^ ((row >> 1) & 3);
            const unsigned short* asrc = (kt < 128) ? mean1 : xb;
            gload16(asrc + (size_t)grow * NF + (kt & 127) + gs * 8, &sm.g.As[buf][tid * 8]);
        }
        #pragma unroll
        for (int i = 0; i < 2; ++i) {            // B: 256 rows x 4 groups
            int c = tid + i * 512;
            int rn = c >> 2, g = c & 3;
            int gs = g ^ ((rn >> 1) & 3);
            gload16(Bt1 + (size_t)rn * 256 + kt + gs * 8, &sm.g.Bs[buf][c * 8]);
        }
    };
    auto compute = [&](int buf) {
        bf16x8 a[4], b[4];
        #pragma unroll
        for (int mi = 0; mi < 4; ++mi)
            a[mi] = *reinterpret_cast<const bf16x8*>(&sm.g.As[buf][(wr * 64 + mi * 16 + r15) * 32 + swz * 8]);
        #pragma unroll
        for (int ni = 0; ni < 4; ++ni)
            b[ni] = *reinterpret_cast<const bf16x8*>(&sm.g.Bs[buf][(wc * 64 + ni * 16 + r15) * 32 + swz * 8]);
        #pragma unroll
        for (int mi = 0; mi < 4; ++mi)
            #pragma unroll
            for (int ni = 0; ni < 4; ++ni)
                acc[mi][ni] = __builtin_amdgcn_mfma_f32_16x16x32_bf16(a[mi], b[ni], acc[mi][ni], 0, 0, 0);
    };

    stage(0, 0);
    stage(1, 32);                                 // 6 loads in flight
    #pragma unroll 1
    for (int ks = 0; ks < 8; ++ks) {
        if (ks + 1 < 8) asm volatile("s_waitcnt vmcnt(3)" ::: "memory");
        else            asm volatile("s_waitcnt vmcnt(0)" ::: "memory");
        __builtin_amdgcn_s_barrier();             // all waves: buf(ks) ready, done with buf(ks-1)
        if (ks + 2 < 8) stage((ks + 2) % 3, (ks + 2) * 32);
        compute(ks % 3);
    }
    __syncthreads();                              // all gemm1 LDS reads done -> Hs overwrite safe

    // h -> LDS (relu+bias, bf16, swizzled)
    #pragma unroll
    for (int ni = 0; ni < 4; ++ni) {
        int col = wc * 64 + ni * 16 + r15;
        float bias = b1[col];
        int kgrp = col >> 3, within = col & 7;
        #pragma unroll
        for (int mi = 0; mi < 4; ++mi) {
            int rbase = wr * 64 + mi * 16 + (lane >> 4) * 4;
            f32x4 c = acc[mi][ni];
            #pragma unroll
            for (int q = 0; q < 4; ++q) {
                int row = rbase + q;
                float v = fmaxf(c[q] + bias, 0.f);
                sm.Hs[row * 256 + (kgrp ^ (row & 31)) * 8 + within] = f2bf(v);
            }
        }
    }
    __syncthreads();

    // ---- gemm2: A from Hs, B from global Bt2; fully unrolled so loads hoist ----
    const int wr2 = wid >> 1, wc2 = wid & 1;     // 4x2
    f32x4 acc2[2][3];
    #pragma unroll
    for (int i = 0; i < 2; ++i)
        #pragma unroll
        for (int j = 0; j < 3; ++j)
            acc2[i][j] = f32x4{0.f, 0.f, 0.f, 0.f};

    #pragma unroll
    for (int kt = 0; kt < 256; kt += 32) {
        bf16x8 a2[2], b2f[3];
        #pragma unroll
        for (int mi = 0; mi < 2; ++mi) {
            int row = wr2 * 32 + mi * 16 + r15;
            int kgrp = (kt >> 3) + (lane >> 4);
            a2[mi] = *reinterpret_cast<const bf16x8*>(&sm.Hs[row * 256 + (kgrp ^ (row & 31)) * 8]);
        }
        #pragma unroll
        for (int ni = 0; ni < 3; ++ni) {
            int n = wc2 * 48 + ni * 16 + r15;
            b2f[ni] = *reinterpret_cast<const bf16x8*>(Bt2 + (size_t)n * 256 + kt + (lane >> 4) * 8);
        }
        #pragma unroll
        for (int mi = 0; mi < 2; ++mi)
            #pragma unroll
            for (int ni = 0; ni < 3; ++ni)
                acc2[mi][ni] = __builtin_amdgcn_mfma_f32_16x16x32_bf16(a2[mi], b2f[ni], acc2[mi][ni], 0, 0, 0);
    }

    #pragma unroll
    for (int ni = 0; ni < 3; ++ni) {
        int col = wc2 * 48 + ni * 16 + r15;      // 0..95
        float bias = (col >= 48 && col < 95) ? b2[col - 48] : 0.f;
        #pragma unroll
        for (int mi = 0; mi < 2; ++mi) {
            int rbase = row0 + wr2 * 32 + mi * 16 + (lane >> 4) * 4;
            f32x4 c = acc2[mi][ni];
            #pragma unroll
            for (int q = 0; q < 4; ++q) {
                int row = rbase + q;
                if (row < NN) {
                    if (col < 47) {
                        int p = __builtin_amdgcn_cvt_pk_fp8_f32(c[q], c[q], 0, false);
                        tq[(size_t)row * 64 + col] = (unsigned char)(p & 0xFF);
                    } else if (col >= 48 && col < 95) {
                        out[(size_t)row * NC + (col - 48)] = c[q] + bias;
                    }
                }
            }
        }
    }
}

// ---------------- launch ----------------

extern "C" void kernel_launch(void* const* d_in, const int* in_sizes, int n_in,
                              void* d_out, int out_size, void* d_ws, size_t ws_size,
                              hipStream_t stream) {
    const float* x    = (const float*)d_in[0];
    const int*   eidx = (const int*)d_in[1];
    const float* Wl1  = (const float*)d_in[2];
    const float* Wr1  = (const float*)d_in[3];
    const float* b1   = (const float*)d_in[4];
    const float* Wl2  = (const float*)d_in[5];
    const float* Wr2  = (const float*)d_in[6];
    const float* b2   = (const float*)d_in[7];
    float* out = (float*)d_out;

    const int* src = eidx;
    const int* dst = eidx + NE;

    size_t off = 0;
    auto alloc = [&](size_t bytes) -> void* {
        void* p = (char*)d_ws + off;
        off += (bytes + 511) & ~(size_t)511;
        return p;
    };
    int*            deg        = (int*)alloc((size_t)NN * 4);
    int*            row_start  = (int*)alloc((size_t)NN * 4);
    float*          inv_deg    = (float*)alloc((size_t)NN * 4);
    int*            csr_src    = (int*)alloc((size_t)NE * 4);
    unsigned*       ebuf       = (unsigned*)alloc((size_t)NE * 4);
    int*            chunk_hist = (int*)alloc((size_t)NCH * NB * 4);
    int*            chunk_off  = (int*)alloc((size_t)NCH * NB * 4);
    int*            bkt_cnt    = (int*)alloc((size_t)NB * 4);
    int*            bkt_base   = (int*)alloc((size_t)NB * 4);
    unsigned short* xb         = (unsigned short*)alloc((size_t)NN * NF * 2);
    unsigned*       xq         = (unsigned*)alloc((size_t)NN * NF);       // fp8 x, 32 words/row
    unsigned short* mean1      = (unsigned short*)alloc((size_t)NN * NF * 2);
    unsigned char*  tq         = (unsigned char*)alloc((size_t)NN * 64);  // fp8 t, 64B rows
    unsigned short* Bt1        = (unsigned short*)alloc((size_t)256 * 256 * 2);
    unsigned short* Bt2        = (unsigned short*)alloc((size_t)96 * 256 * 2);
    (void)ws_size; (void)n_in; (void)in_sizes; (void)out_size;

    hipMemsetAsync(bkt_cnt, 0, (size_t)NB * 4, stream);
    prep_k<<<PB_END, 256, 0, stream>>>(dst, chunk_hist, bkt_cnt,
                                       x, xb, xq, Wl1, Wr1, Bt1, Wl2, Wr2, Bt2);
    scancol_k<<<NB, 64, 0, stream>>>(chunk_hist, bkt_cnt, bkt_base, chunk_off);
    scatter2_k<<<NCH, 256, 0, stream>>>(src, dst, chunk_off, ebuf);
    build_csr_k<<<NB, 256, 0, stream>>>(ebuf, bkt_base, bkt_cnt,
                                        row_start, deg, inv_deg, csr_src);

    agg_mean_128q_k<<<(NN + 15) / 16, 256, 0, stream>>>(xq, csr_src, row_start, deg, inv_deg, mean1);

    gemm12_k<<<(NN + 127) / 128, 512, 0, stream>>>(mean1, xb, Bt1, b1, Bt2, b2, tq, out);

    agg_mean_47q_add_k<<<(NN + 15) / 16, 256, 0, stream>>>((const unsigned*)tq, csr_src, row_start, deg, inv_deg, out);
}